// Round 1
// baseline (3229.664 us; speedup 1.0000x reference)
//
#include <hip/hip_runtime.h>
#include <cstdint>
#include <cstddef>

#define NN   50000
#define FIN  128
#define HD   128
#define EE   800000
#define C3   384   // 3*H
#define NOUT 40

// ---------- float<->ordered-uint mapping for atomic fmax ----------
static __device__ __forceinline__ unsigned fkey(float f) {
    int i = __float_as_int(f);
    return (i >= 0) ? ((unsigned)i | 0x80000000u) : ~(unsigned)i;
}
static __device__ __forceinline__ float funkey(unsigned u) {
    int i = (u & 0x80000000u) ? (int)(u & 0x7fffffffu) : (int)~u;
    return __int_as_float(i);
}

// ---------- init h_cat rows with [b_gat | b_gcn | 0] ----------
__global__ void k_init_hcat(float* __restrict__ hcat,
                            const float* __restrict__ bg,
                            const float* __restrict__ bc) {
    int gid = blockIdx.x * blockDim.x + threadIdx.x;
    if (gid >= NN * C3) return;
    int j = gid % C3;
    float v = (j < 128) ? bg[j] : (j < 256 ? bc[j - 128] : 0.f);
    hcat[gid] = v;
}

// ---------- generic tiled fp32 GEMM: C = op(A) @ B (+bias) (+addC) ----------
// mode 0: plain; 1: row-scale t1[row]; 2: relu(v*t1[k]+t2[k]); 3: relu(v)
__global__ __launch_bounds__(256) void k_gemm(
    const float* __restrict__ A, int lda,
    const float* __restrict__ B, int ldb,
    const float* __restrict__ bias,
    const float* __restrict__ addC, int ldadd,
    float* __restrict__ C, int ldc,
    int M, int N, int K,
    int mode, const float* __restrict__ t1, const float* __restrict__ t2)
{
    __shared__ float As[32][65];
    __shared__ float Bs[32][65];
    const int t  = threadIdx.x;
    const int tx = t & 15, ty = t >> 4;
    const int row0 = blockIdx.y * 64, col0 = blockIdx.x * 64;
    float acc[4][4] = {};

    for (int k0 = 0; k0 < K; k0 += 32) {
        // A tile: 64 rows x 32 k, stored transposed As[k][r]
        #pragma unroll
        for (int j = 0; j < 8; ++j) {
            int lin = t + j * 256;           // 0..2047
            int r = lin >> 5, kk = lin & 31;
            int row = row0 + r;
            float v = 0.f;
            if (row < M) {
                v = A[(size_t)row * lda + k0 + kk];
                if (mode == 1)      v *= t1[row];
                else if (mode == 2) { v = v * t1[k0 + kk] + t2[k0 + kk]; v = v > 0.f ? v : 0.f; }
                else if (mode == 3) { v = v > 0.f ? v : 0.f; }
            }
            As[kk][r] = v;
        }
        // B tile: 32 k x 64 cols
        #pragma unroll
        for (int j = 0; j < 8; ++j) {
            int lin = t + j * 256;
            int kk = lin >> 6, c = lin & 63;
            int col = col0 + c;
            Bs[kk][c] = (col < N) ? B[(size_t)(k0 + kk) * ldb + col] : 0.f;
        }
        __syncthreads();
        #pragma unroll
        for (int kk = 0; kk < 32; ++kk) {
            float a0 = As[kk][ty * 4 + 0], a1 = As[kk][ty * 4 + 1];
            float a2 = As[kk][ty * 4 + 2], a3 = As[kk][ty * 4 + 3];
            float b0 = Bs[kk][tx * 4 + 0], b1 = Bs[kk][tx * 4 + 1];
            float b2 = Bs[kk][tx * 4 + 2], b3 = Bs[kk][tx * 4 + 3];
            acc[0][0] += a0 * b0; acc[0][1] += a0 * b1; acc[0][2] += a0 * b2; acc[0][3] += a0 * b3;
            acc[1][0] += a1 * b0; acc[1][1] += a1 * b1; acc[1][2] += a1 * b2; acc[1][3] += a1 * b3;
            acc[2][0] += a2 * b0; acc[2][1] += a2 * b1; acc[2][2] += a2 * b2; acc[2][3] += a2 * b3;
            acc[3][0] += a3 * b0; acc[3][1] += a3 * b1; acc[3][2] += a3 * b2; acc[3][3] += a3 * b3;
        }
        __syncthreads();
    }

    #pragma unroll
    for (int i = 0; i < 4; ++i) {
        int rr = row0 + ty * 4 + i;
        if (rr >= M) continue;
        #pragma unroll
        for (int j = 0; j < 4; ++j) {
            int cc = col0 + tx * 4 + j;
            if (cc >= N) continue;
            float v = acc[i][j];
            if (bias) v += bias[cc];
            if (addC) v += addC[(size_t)rr * ldadd + cc];
            C[(size_t)rr * ldc + cc] = v;
        }
    }
}

// ---------- attention dots: a_s = h@att_src, a_d = h@att_dst ----------
__global__ __launch_bounds__(256) void k_att_dots(
    const float* __restrict__ h, const float* __restrict__ ws_,
    const float* __restrict__ wd_, float* __restrict__ a_s,
    float* __restrict__ a_d)
{
    int node = blockIdx.x * 4 + (threadIdx.x >> 6);
    if (node >= NN) return;
    int lane = threadIdx.x & 63;
    float2 v  = *(const float2*)(h + (size_t)node * 128 + lane * 2);
    float2 w1 = *(const float2*)(ws_ + lane * 2);
    float2 w2 = *(const float2*)(wd_ + lane * 2);
    float s1 = v.x * w1.x + v.y * w1.y;
    float s2 = v.x * w2.x + v.y * w2.y;
    #pragma unroll
    for (int off = 32; off; off >>= 1) {
        s1 += __shfl_down(s1, off);
        s2 += __shfl_down(s2, off);
    }
    if (lane == 0) { a_s[node] = s1; a_d[node] = s2; }
}

// ---------- edge pass 1: e=leaky(a_s[s]+a_d[d]); max, deg, cnt ----------
__global__ void k_edge1(const int* __restrict__ src, const int* __restrict__ dst,
                        const float* __restrict__ a_s, const float* __restrict__ a_d,
                        float* __restrict__ ebuf, unsigned* __restrict__ mu,
                        float* __restrict__ deg, float* __restrict__ cnt)
{
    int gid = blockIdx.x * blockDim.x + threadIdx.x;
    if (gid >= EE + NN) return;
    int s, d;
    if (gid < EE) { s = src[gid]; d = dst[gid]; } else { s = d = gid - EE; }
    float e = a_s[s] + a_d[d];
    e = (e > 0.f) ? e : 0.2f * e;
    ebuf[gid] = e;
    atomicMax(&mu[d], fkey(e));
    unsafeAtomicAdd(&deg[d], 1.f);
    if (gid < EE) unsafeAtomicAdd(&cnt[d], 1.f);
}

// ---------- edge pass 2: ex=exp(e-m[d]); denom += ex ----------
__global__ void k_edge2(const int* __restrict__ dst,
                        float* __restrict__ ebuf, const unsigned* __restrict__ mu,
                        float* __restrict__ den)
{
    int gid = blockIdx.x * blockDim.x + threadIdx.x;
    if (gid >= EE + NN) return;
    int d = (gid < EE) ? dst[gid] : (gid - EE);
    float m = funkey(mu[d]);
    float ex = expf(ebuf[gid] - m);
    ebuf[gid] = ex;
    unsafeAtomicAdd(&den[d], ex);
}

// ---------- node finalize: dinv, rdenom, rcnt (in place) ----------
__global__ void k_node_fin(float* __restrict__ deg, float* __restrict__ den,
                           float* __restrict__ cnt)
{
    int i = blockIdx.x * blockDim.x + threadIdx.x;
    if (i >= NN) return;
    deg[i] = rsqrtf(deg[i]);            // deg >= 1 (self-loops)
    den[i] = 1.f / den[i];              // denom > 0 (self-loop term)
    float c = cnt[i];
    cnt[i] = 1.f / (c > 1.f ? c : 1.f); // 1/max(cnt,1)
}

// ---------- edge pass 3: vector scatter for GAT/GCN/SAGE ----------
__global__ __launch_bounds__(256) void k_edge_scatter(
    const int* __restrict__ src, const int* __restrict__ dst,
    const float* __restrict__ ex, const float* __restrict__ rden,
    const float* __restrict__ dinv,
    const float* __restrict__ hgat, const float* __restrict__ hgcn,
    const float* __restrict__ x,
    float* __restrict__ hcat, float* __restrict__ agg)
{
    int eidx = blockIdx.x * 4 + (threadIdx.x >> 6);
    if (eidx >= EE + NN) return;
    int lane = threadIdx.x & 63;
    int s, d;
    if (eidx < EE) { s = src[eidx]; d = dst[eidx]; } else { s = d = eidx - EE; }
    float wg = ex[eidx] * rden[d];
    float wc = dinv[s] * dinv[d];
    int c = lane * 2;
    const float2 hg = *(const float2*)(hgat + (size_t)s * 128 + c);
    const float2 hc = *(const float2*)(hgcn + (size_t)s * 128 + c);
    float* rowp = hcat + (size_t)d * C3 + c;
    unsafeAtomicAdd(rowp,           wg * hg.x);
    unsafeAtomicAdd(rowp + 1,       wg * hg.y);
    unsafeAtomicAdd(rowp + 128,     wc * hc.x);
    unsafeAtomicAdd(rowp + 129,     wc * hc.y);
    if (eidx < EE) {
        const float2 xv = *(const float2*)(x + (size_t)s * 128 + c);
        unsafeAtomicAdd(agg + (size_t)d * 128 + c,     xv.x);
        unsafeAtomicAdd(agg + (size_t)d * 128 + c + 1, xv.y);
    }
}

// ---------- batchnorm stats: per-column sum & sumsq ----------
__global__ __launch_bounds__(128) void k_bn_stats(
    const float* __restrict__ hcat, float* __restrict__ sums,
    float* __restrict__ sumsq)
{
    int t = threadIdx.x; // 128 threads; cols t, t+128, t+256
    float s0 = 0, s1 = 0, s2 = 0, q0 = 0, q1 = 0, q2 = 0;
    for (int i = blockIdx.x; i < NN; i += gridDim.x) {
        const float* r = hcat + (size_t)i * C3;
        float v0 = r[t], v1 = r[t + 128], v2 = r[t + 256];
        s0 += v0; q0 += v0 * v0;
        s1 += v1; q1 += v1 * v1;
        s2 += v2; q2 += v2 * v2;
    }
    unsafeAtomicAdd(&sums[t],        s0);
    unsafeAtomicAdd(&sums[t + 128],  s1);
    unsafeAtomicAdd(&sums[t + 256],  s2);
    unsafeAtomicAdd(&sumsq[t],       q0);
    unsafeAtomicAdd(&sumsq[t + 128], q1);
    unsafeAtomicAdd(&sumsq[t + 256], q2);
}

__global__ void k_bn_final(const float* __restrict__ sums, const float* __restrict__ sumsq,
                           const float* __restrict__ gamma, const float* __restrict__ beta,
                           float* __restrict__ scale, float* __restrict__ shift)
{
    int j = threadIdx.x;
    if (j >= C3) return;
    const float rn = 1.f / (float)NN;
    float mu  = sums[j] * rn;
    float var = sumsq[j] * rn - mu * mu;
    float sc  = gamma[j] * rsqrtf(var + 1e-5f);
    scale[j] = sc;
    shift[j] = beta[j] - mu * sc;
}

extern "C" void kernel_launch(void* const* d_in, const int* in_sizes, int n_in,
                              void* d_out, int out_size, void* d_ws, size_t ws_size,
                              hipStream_t stream) {
    const float* x        = (const float*)d_in[0];
    const int*   ei       = (const int*)d_in[1];
    const float* W_gat    = (const float*)d_in[2];
    const float* att_src  = (const float*)d_in[3];
    const float* att_dst  = (const float*)d_in[4];
    const float* b_gat    = (const float*)d_in[5];
    const float* W_gcn    = (const float*)d_in[6];
    const float* b_gcn    = (const float*)d_in[7];
    const float* W_sage_l = (const float*)d_in[8];
    const float* b_sage_l = (const float*)d_in[9];
    const float* W_sage_r = (const float*)d_in[10];
    const float* W1       = (const float*)d_in[11];
    const float* b1       = (const float*)d_in[12];
    const float* W2       = (const float*)d_in[13];
    const float* b2       = (const float*)d_in[14];
    const float* W3       = (const float*)d_in[15];
    const float* b3       = (const float*)d_in[16];
    const float* gamma    = (const float*)d_in[17];
    const float* beta     = (const float*)d_in[18];

    const int* e_src = ei;
    const int* e_dst = ei + EE;

    // ---- workspace layout (floats) ----
    float* ws    = (float*)d_ws;
    float* h_gat = ws;                            // N*128
    float* h_gcn = h_gat + (size_t)NN * 128;      // N*128
    float* xwr   = h_gcn + (size_t)NN * 128;      // N*128
    float* agg   = xwr   + (size_t)NN * 128;      // N*128
    float* hcat  = agg   + (size_t)NN * 128;      // N*384
    float* a1    = h_gat;                         // reuse: N*256 fits in h_gat+h_gcn
    float* a2    = xwr;                           // reuse: N*128
    float* as_   = hcat + (size_t)NN * C3;        // N
    float* ad_   = as_ + NN;                      // N
    float* ebuf  = ad_ + NN;                      // E+N
    unsigned* mu_ = (unsigned*)(ebuf + EE + NN);  // N
    float* den   = (float*)(mu_ + NN);            // N
    float* deg   = den + NN;                      // N
    float* cnt   = deg + NN;                      // N
    float* sums  = cnt + NN;                      // 384
    float* sumsq = sums + C3;                     // 384
    float* scale = sumsq + C3;                    // 384
    float* shift = scale + C3;                    // 384

    // ---- zero-init scratch that is accumulated into ----
    hipMemsetAsync(agg, 0, (size_t)NN * 128 * sizeof(float), stream);
    hipMemsetAsync(mu_, 0, ((size_t)4 * NN + 2 * C3) * sizeof(float), stream);
    k_init_hcat<<<(NN * C3 + 255) / 256, 256, 0, stream>>>(hcat, b_gat, b_gcn);

    // ---- node-feature GEMMs: h_gat, h_gcn, xWr ----
    dim3 g128(2, (NN + 63) / 64);
    k_gemm<<<g128, 256, 0, stream>>>(x, FIN, W_gat, HD, nullptr, nullptr, 0,
                                     h_gat, HD, NN, HD, FIN, 0, nullptr, nullptr);
    k_gemm<<<g128, 256, 0, stream>>>(x, FIN, W_gcn, HD, nullptr, nullptr, 0,
                                     h_gcn, HD, NN, HD, FIN, 0, nullptr, nullptr);
    k_gemm<<<g128, 256, 0, stream>>>(x, FIN, W_sage_r, HD, nullptr, nullptr, 0,
                                     xwr, HD, NN, HD, FIN, 0, nullptr, nullptr);

    // ---- GAT attention logits ----
    k_att_dots<<<(NN + 3) / 4, 256, 0, stream>>>(h_gat, att_src, att_dst, as_, ad_);

    // ---- edge passes ----
    int eb = (EE + NN + 255) / 256;
    k_edge1<<<eb, 256, 0, stream>>>(e_src, e_dst, as_, ad_, ebuf, mu_, deg, cnt);
    k_edge2<<<eb, 256, 0, stream>>>(e_dst, ebuf, mu_, den);
    k_node_fin<<<(NN + 255) / 256, 256, 0, stream>>>(deg, den, cnt);
    k_edge_scatter<<<(EE + NN + 3) / 4, 256, 0, stream>>>(
        e_src, e_dst, ebuf, den, deg, h_gat, h_gcn, x, hcat, agg);

    // ---- SAGE: mean @ W_l + b_l + xWr -> hcat[:,256:384] ----
    k_gemm<<<g128, 256, 0, stream>>>(agg, HD, W_sage_l, HD, b_sage_l, xwr, HD,
                                     hcat + 256, C3, NN, HD, HD, 1, cnt, nullptr);

    // ---- BatchNorm stats + affine fold ----
    k_bn_stats<<<256, 128, 0, stream>>>(hcat, sums, sumsq);
    k_bn_final<<<1, C3, 0, stream>>>(sums, sumsq, gamma, beta, scale, shift);

    // ---- MLP ----
    dim3 gm1(4, (NN + 63) / 64);
    k_gemm<<<gm1, 256, 0, stream>>>(hcat, C3, W1, 256, b1, nullptr, 0,
                                    a1, 256, NN, 256, C3, 2, scale, shift);
    dim3 gm2(2, (NN + 63) / 64);
    k_gemm<<<gm2, 256, 0, stream>>>(a1, 256, W2, HD, b2, nullptr, 0,
                                    a2, HD, NN, HD, 256, 3, nullptr, nullptr);
    dim3 gm3(1, (NN + 63) / 64);
    k_gemm<<<gm3, 256, 0, stream>>>(a2, HD, W3, NOUT, b3, nullptr, 0,
                                    (float*)d_out, NOUT, NN, NOUT, HD, 3, nullptr, nullptr);
}

// Round 2
// 1493.814 us; speedup vs baseline: 2.1620x; 2.1620x over previous
//
#include <hip/hip_runtime.h>
#include <cstdint>
#include <cstddef>

#define NN   50000
#define FIN  128
#define HD   128
#define EE   800000
#define C3   384   // 3*H
#define NOUT 40

// ---------- float<->ordered-uint mapping for atomic fmax ----------
// For all finite e, fkey(e) > 0, so memset-0 init is a valid identity.
static __device__ __forceinline__ unsigned fkey(float f) {
    int i = __float_as_int(f);
    return (i >= 0) ? ((unsigned)i | 0x80000000u) : ~(unsigned)i;
}
static __device__ __forceinline__ float funkey(unsigned u) {
    int i = (u & 0x80000000u) ? (int)(u & 0x7fffffffu) : (int)~u;
    return __int_as_float(i);
}

// ---------- generic tiled fp32 GEMM: C = op(A) @ B (+bias) (+addC) ----------
// mode 0: plain; 1: row-scale t1[row]; 2: relu(v*t1[k]+t2[k]); 3: relu(v)
__global__ __launch_bounds__(256) void k_gemm(
    const float* __restrict__ A, int lda,
    const float* __restrict__ B, int ldb,
    const float* __restrict__ bias,
    const float* __restrict__ addC, int ldadd,
    float* __restrict__ C, int ldc,
    int M, int N, int K,
    int mode, const float* __restrict__ t1, const float* __restrict__ t2)
{
    __shared__ float As[32][65];
    __shared__ float Bs[32][65];
    const int t  = threadIdx.x;
    const int tx = t & 15, ty = t >> 4;
    const int row0 = blockIdx.y * 64, col0 = blockIdx.x * 64;
    float acc[4][4] = {};

    for (int k0 = 0; k0 < K; k0 += 32) {
        #pragma unroll
        for (int j = 0; j < 8; ++j) {
            int lin = t + j * 256;           // 0..2047
            int r = lin >> 5, kk = lin & 31;
            int row = row0 + r;
            float v = 0.f;
            if (row < M) {
                v = A[(size_t)row * lda + k0 + kk];
                if (mode == 1)      v *= t1[row];
                else if (mode == 2) { v = v * t1[k0 + kk] + t2[k0 + kk]; v = v > 0.f ? v : 0.f; }
                else if (mode == 3) { v = v > 0.f ? v : 0.f; }
            }
            As[kk][r] = v;
        }
        #pragma unroll
        for (int j = 0; j < 8; ++j) {
            int lin = t + j * 256;
            int kk = lin >> 6, c = lin & 63;
            int col = col0 + c;
            Bs[kk][c] = (col < N) ? B[(size_t)(k0 + kk) * ldb + col] : 0.f;
        }
        __syncthreads();
        #pragma unroll
        for (int kk = 0; kk < 32; ++kk) {
            float a0 = As[kk][ty * 4 + 0], a1 = As[kk][ty * 4 + 1];
            float a2 = As[kk][ty * 4 + 2], a3 = As[kk][ty * 4 + 3];
            float b0 = Bs[kk][tx * 4 + 0], b1 = Bs[kk][tx * 4 + 1];
            float b2 = Bs[kk][tx * 4 + 2], b3 = Bs[kk][tx * 4 + 3];
            acc[0][0] += a0 * b0; acc[0][1] += a0 * b1; acc[0][2] += a0 * b2; acc[0][3] += a0 * b3;
            acc[1][0] += a1 * b0; acc[1][1] += a1 * b1; acc[1][2] += a1 * b2; acc[1][3] += a1 * b3;
            acc[2][0] += a2 * b0; acc[2][1] += a2 * b1; acc[2][2] += a2 * b2; acc[2][3] += a2 * b3;
            acc[3][0] += a3 * b0; acc[3][1] += a3 * b1; acc[3][2] += a3 * b2; acc[3][3] += a3 * b3;
        }
        __syncthreads();
    }

    #pragma unroll
    for (int i = 0; i < 4; ++i) {
        int rr = row0 + ty * 4 + i;
        if (rr >= M) continue;
        #pragma unroll
        for (int j = 0; j < 4; ++j) {
            int cc = col0 + tx * 4 + j;
            if (cc >= N) continue;
            float v = acc[i][j];
            if (bias) v += bias[cc];
            if (addC) v += addC[(size_t)rr * ldadd + cc];
            C[(size_t)rr * ldc + cc] = v;
        }
    }
}

// ---------- attention dots: a_s = h@att_src, a_d = h@att_dst ----------
__global__ __launch_bounds__(256) void k_att_dots(
    const float* __restrict__ h, const float* __restrict__ ws_,
    const float* __restrict__ wd_, float* __restrict__ a_s,
    float* __restrict__ a_d)
{
    int node = blockIdx.x * 4 + (threadIdx.x >> 6);
    if (node >= NN) return;
    int lane = threadIdx.x & 63;
    float2 v  = *(const float2*)(h + (size_t)node * 128 + lane * 2);
    float2 w1 = *(const float2*)(ws_ + lane * 2);
    float2 w2 = *(const float2*)(wd_ + lane * 2);
    float s1 = v.x * w1.x + v.y * w1.y;
    float s2 = v.x * w2.x + v.y * w2.y;
    #pragma unroll
    for (int off = 32; off; off >>= 1) {
        s1 += __shfl_down(s1, off);
        s2 += __shfl_down(s2, off);
    }
    if (lane == 0) { a_s[node] = s1; a_d[node] = s2; }
}

// ---------- edge pass 1: e=leaky(a_s[s]+a_d[d]); segment max; dst degree ----------
__global__ void k_edge1(const int* __restrict__ src, const int* __restrict__ dst,
                        const float* __restrict__ a_s, const float* __restrict__ a_d,
                        float* __restrict__ ebuf, unsigned* __restrict__ mu,
                        int* __restrict__ degAll)
{
    int gid = blockIdx.x * blockDim.x + threadIdx.x;
    if (gid >= EE + NN) return;
    int s, d;
    if (gid < EE) { s = src[gid]; d = dst[gid]; } else { s = d = gid - EE; }
    float e = a_s[s] + a_d[d];
    e = (e > 0.f) ? e : 0.2f * e;
    ebuf[gid] = e;
    atomicMax(&mu[d], fkey(e));
    atomicAdd(&degAll[d], 1);
}

// ---------- single-block exclusive scan over degAll -> offs, cursor ----------
#define SCAN_T 256
__global__ __launch_bounds__(SCAN_T) void k_scan(
    const int* __restrict__ degAll, int* __restrict__ offs,
    int* __restrict__ cursor)
{
    __shared__ int part[SCAN_T];
    int t = threadIdx.x;
    const int chunk = (NN + SCAN_T - 1) / SCAN_T;
    int b = t * chunk;
    int e = b + chunk; if (e > NN) e = NN;
    int sum = 0;
    for (int i = b; i < e; ++i) sum += degAll[i];
    part[t] = sum;
    __syncthreads();
    for (int off = 1; off < SCAN_T; off <<= 1) {
        int v = (t >= off) ? part[t - off] : 0;
        __syncthreads();
        part[t] += v;
        __syncthreads();
    }
    int run = (t > 0) ? part[t - 1] : 0;
    for (int i = b; i < e; ++i) {
        offs[i] = run; cursor[i] = run;
        run += degAll[i];
    }
    if (t == SCAN_T - 1) offs[NN] = run;
}

// ---------- CSR fill: bucket edge ids by dst ----------
__global__ void k_csr_fill(const int* __restrict__ dst, int* __restrict__ cursor,
                           int* __restrict__ eids)
{
    int gid = blockIdx.x * blockDim.x + threadIdx.x;
    if (gid >= EE + NN) return;
    int d = (gid < EE) ? dst[gid] : (gid - EE);
    int slot = atomicAdd(&cursor[d], 1);
    eids[slot] = gid;
}

// ---------- edge pass 2: ex=exp(e-m[d]); denom += ex ----------
__global__ void k_edge2(const int* __restrict__ dst,
                        float* __restrict__ ebuf, const unsigned* __restrict__ mu,
                        float* __restrict__ den)
{
    int gid = blockIdx.x * blockDim.x + threadIdx.x;
    if (gid >= EE + NN) return;
    int d = (gid < EE) ? dst[gid] : (gid - EE);
    float m = funkey(mu[d]);
    float ex = expf(ebuf[gid] - m);
    ebuf[gid] = ex;
    unsafeAtomicAdd(&den[d], ex);
}

// ---------- node finalize: dinv, rdenom, rcnt ----------
__global__ void k_node_fin(const int* __restrict__ degAll, float* __restrict__ den,
                           float* __restrict__ dinv, float* __restrict__ rcnt)
{
    int i = blockIdx.x * blockDim.x + threadIdx.x;
    if (i >= NN) return;
    int da = degAll[i];                   // >= 1 (self-loop)
    dinv[i] = rsqrtf((float)da);
    den[i]  = 1.f / den[i];               // denom > 0 (self-loop term)
    int cs = da - 1;                      // SAGE neighbor count (no self-loop)
    rcnt[i] = 1.f / (float)(cs > 1 ? cs : 1);
}

// ---------- CSR gather: one wave per dst node, registers accumulate ----------
__global__ __launch_bounds__(256) void k_gather(
    const int* __restrict__ src,
    const int* __restrict__ eids, const int* __restrict__ offs,
    const float* __restrict__ ex, const float* __restrict__ rden,
    const float* __restrict__ dinv,
    const float* __restrict__ hgat, const float* __restrict__ hgcn,
    const float* __restrict__ x,
    const float* __restrict__ bg, const float* __restrict__ bc,
    float* __restrict__ hcat, float* __restrict__ agg)
{
    int d = blockIdx.x * 4 + (threadIdx.x >> 6);
    if (d >= NN) return;
    int lane = threadIdx.x & 63;
    int beg = offs[d], end = offs[d + 1];
    float rd = rden[d], dd = dinv[d];
    float2 ga = {0.f, 0.f}, gc = {0.f, 0.f}, sg = {0.f, 0.f};
    int c = lane * 2;

    for (int base = beg; base < end; base += 64) {
        int idx = base + lane;
        int s = 0; float wg = 0.f, wc = 0.f, fs = 0.f;
        if (idx < end) {
            int eid = eids[idx];
            if (eid < EE) { s = src[eid]; fs = 1.f; }
            else          { s = eid - EE; }
            wg = ex[eid] * rd;
            wc = dinv[s] * dd;
        }
        int cnt = end - base; if (cnt > 64) cnt = 64;
        for (int j = 0; j < cnt; ++j) {
            int   sj  = __shfl(s,  j);
            float wgj = __shfl(wg, j);
            float wcj = __shfl(wc, j);
            float fsj = __shfl(fs, j);
            const float2 hg = *(const float2*)(hgat + (size_t)sj * 128 + c);
            const float2 hc = *(const float2*)(hgcn + (size_t)sj * 128 + c);
            ga.x += wgj * hg.x; ga.y += wgj * hg.y;
            gc.x += wcj * hc.x; gc.y += wcj * hc.y;
            if (fsj != 0.f) {   // wave-uniform: skip x load on self-loop edges
                const float2 xv = *(const float2*)(x + (size_t)sj * 128 + c);
                sg.x += xv.x; sg.y += xv.y;
            }
        }
    }
    float* row = hcat + (size_t)d * C3;
    ga.x += bg[c]; ga.y += bg[c + 1];
    gc.x += bc[c]; gc.y += bc[c + 1];
    *(float2*)(row + c)        = ga;
    *(float2*)(row + 128 + c)  = gc;
    *(float2*)(agg + (size_t)d * 128 + c) = sg;
}

// ---------- batchnorm stats: per-column sum & sumsq ----------
__global__ __launch_bounds__(128) void k_bn_stats(
    const float* __restrict__ hcat, float* __restrict__ sums,
    float* __restrict__ sumsq)
{
    int t = threadIdx.x; // cols t, t+128, t+256
    float s0 = 0, s1 = 0, s2 = 0, q0 = 0, q1 = 0, q2 = 0;
    for (int i = blockIdx.x; i < NN; i += gridDim.x) {
        const float* r = hcat + (size_t)i * C3;
        float v0 = r[t], v1 = r[t + 128], v2 = r[t + 256];
        s0 += v0; q0 += v0 * v0;
        s1 += v1; q1 += v1 * v1;
        s2 += v2; q2 += v2 * v2;
    }
    unsafeAtomicAdd(&sums[t],        s0);
    unsafeAtomicAdd(&sums[t + 128],  s1);
    unsafeAtomicAdd(&sums[t + 256],  s2);
    unsafeAtomicAdd(&sumsq[t],       q0);
    unsafeAtomicAdd(&sumsq[t + 128], q1);
    unsafeAtomicAdd(&sumsq[t + 256], q2);
}

__global__ void k_bn_final(const float* __restrict__ sums, const float* __restrict__ sumsq,
                           const float* __restrict__ gamma, const float* __restrict__ beta,
                           float* __restrict__ scale, float* __restrict__ shift)
{
    int j = threadIdx.x;
    if (j >= C3) return;
    const float rn = 1.f / (float)NN;
    float mu  = sums[j] * rn;
    float var = sumsq[j] * rn - mu * mu;
    float sc  = gamma[j] * rsqrtf(var + 1e-5f);
    scale[j] = sc;
    shift[j] = beta[j] - mu * sc;
}

extern "C" void kernel_launch(void* const* d_in, const int* in_sizes, int n_in,
                              void* d_out, int out_size, void* d_ws, size_t ws_size,
                              hipStream_t stream) {
    const float* x        = (const float*)d_in[0];
    const int*   ei       = (const int*)d_in[1];
    const float* W_gat    = (const float*)d_in[2];
    const float* att_src  = (const float*)d_in[3];
    const float* att_dst  = (const float*)d_in[4];
    const float* b_gat    = (const float*)d_in[5];
    const float* W_gcn    = (const float*)d_in[6];
    const float* b_gcn    = (const float*)d_in[7];
    const float* W_sage_l = (const float*)d_in[8];
    const float* b_sage_l = (const float*)d_in[9];
    const float* W_sage_r = (const float*)d_in[10];
    const float* W1       = (const float*)d_in[11];
    const float* b1       = (const float*)d_in[12];
    const float* W2       = (const float*)d_in[13];
    const float* b2       = (const float*)d_in[14];
    const float* W3       = (const float*)d_in[15];
    const float* b3       = (const float*)d_in[16];
    const float* gamma    = (const float*)d_in[17];
    const float* beta     = (const float*)d_in[18];

    const int* e_src = ei;
    const int* e_dst = ei + EE;

    // ---- workspace layout ----
    float* ws    = (float*)d_ws;
    float* h_gat = ws;                            // N*128
    float* h_gcn = h_gat + (size_t)NN * 128;      // N*128
    float* xwr   = h_gcn + (size_t)NN * 128;      // N*128
    float* agg   = xwr   + (size_t)NN * 128;      // N*128
    float* hcat  = agg   + (size_t)NN * 128;      // N*384
    float* a1    = h_gat;                         // reuse after gather: N*256
    float* a2    = xwr;                           // reuse after sage gemm: N*128
    float* as_   = hcat + (size_t)NN * C3;        // N
    float* ad_   = as_ + NN;                      // N
    float* ebuf  = ad_ + NN;                      // E+N
    // --- zero-init region starts here (mu_, den, degAll, sums, sumsq) ---
    unsigned* mu_  = (unsigned*)(ebuf + EE + NN); // N
    float*    den  = (float*)(mu_ + NN);          // N
    int*      degA = (int*)(den + NN);            // N
    float*    sums = (float*)(degA + NN);         // 384
    float*    sumsq= sums + C3;                   // 384
    // --- end zero-init region ---
    float* scale = sumsq + C3;                    // 384
    float* shift = scale + C3;                    // 384
    float* dinv  = shift + C3;                    // N
    float* rcnt  = dinv + NN;                     // N
    int*   offs  = (int*)(rcnt + NN);             // N+1
    int*   cursor= offs + NN + 1;                 // N
    int*   eids  = cursor + NN;                   // E+N

    hipMemsetAsync(mu_, 0, ((size_t)3 * NN + 2 * C3) * sizeof(float), stream);

    // ---- node-feature GEMMs: h_gat, h_gcn, xWr ----
    dim3 g128(2, (NN + 63) / 64);
    k_gemm<<<g128, 256, 0, stream>>>(x, FIN, W_gat, HD, nullptr, nullptr, 0,
                                     h_gat, HD, NN, HD, FIN, 0, nullptr, nullptr);
    k_gemm<<<g128, 256, 0, stream>>>(x, FIN, W_gcn, HD, nullptr, nullptr, 0,
                                     h_gcn, HD, NN, HD, FIN, 0, nullptr, nullptr);
    k_gemm<<<g128, 256, 0, stream>>>(x, FIN, W_sage_r, HD, nullptr, nullptr, 0,
                                     xwr, HD, NN, HD, FIN, 0, nullptr, nullptr);

    // ---- GAT attention logits ----
    k_att_dots<<<(NN + 3) / 4, 256, 0, stream>>>(h_gat, att_src, att_dst, as_, ad_);

    // ---- edge passes + CSR build ----
    int eb = (EE + NN + 255) / 256;
    k_edge1<<<eb, 256, 0, stream>>>(e_src, e_dst, as_, ad_, ebuf, mu_, degA);
    k_scan<<<1, SCAN_T, 0, stream>>>(degA, offs, cursor);
    k_csr_fill<<<eb, 256, 0, stream>>>(e_dst, cursor, eids);
    k_edge2<<<eb, 256, 0, stream>>>(e_dst, ebuf, mu_, den);
    k_node_fin<<<(NN + 255) / 256, 256, 0, stream>>>(degA, den, dinv, rcnt);

    // ---- gather: GAT + GCN (+biases) into hcat, SAGE sum into agg ----
    k_gather<<<(NN + 3) / 4, 256, 0, stream>>>(
        e_src, eids, offs, ebuf, den, dinv, h_gat, h_gcn, x, b_gat, b_gcn,
        hcat, agg);

    // ---- SAGE: (agg * rcnt[row]) @ W_l + b_l + xWr -> hcat[:,256:384] ----
    k_gemm<<<g128, 256, 0, stream>>>(agg, HD, W_sage_l, HD, b_sage_l, xwr, HD,
                                     hcat + 256, C3, NN, HD, HD, 1, rcnt, nullptr);

    // ---- BatchNorm stats + affine fold ----
    k_bn_stats<<<256, 128, 0, stream>>>(hcat, sums, sumsq);
    k_bn_final<<<1, C3, 0, stream>>>(sums, sumsq, gamma, beta, scale, shift);

    // ---- MLP ----
    dim3 gm1(4, (NN + 63) / 64);
    k_gemm<<<gm1, 256, 0, stream>>>(hcat, C3, W1, 256, b1, nullptr, 0,
                                    a1, 256, NN, 256, C3, 2, scale, shift);
    dim3 gm2(2, (NN + 63) / 64);
    k_gemm<<<gm2, 256, 0, stream>>>(a1, 256, W2, HD, b2, nullptr, 0,
                                    a2, HD, NN, HD, 256, 3, nullptr, nullptr);
    dim3 gm3(1, (NN + 63) / 64);
    k_gemm<<<gm3, 256, 0, stream>>>(a2, HD, W3, NOUT, b3, nullptr, 0,
                                    (float*)d_out, NOUT, NN, NOUT, HD, 3, nullptr, nullptr);
}

// Round 3
// 1062.015 us; speedup vs baseline: 3.0411x; 1.4066x over previous
//
#include <hip/hip_runtime.h>
#include <cstdint>
#include <cstddef>

#define NN   50000
#define FIN  128
#define HD   128
#define EE   800000
#define C3   384   // 3*H
#define NOUT 40

typedef __attribute__((ext_vector_type(8))) short s8v;   // 8 x bf16 (4 VGPR)
typedef __attribute__((ext_vector_type(4))) float f4v;   // MFMA acc

// ---------- bf16 helpers ----------
static __device__ __forceinline__ float b2f(ushort u) {
    return __uint_as_float((unsigned)u << 16);
}
// round-to-nearest-even fp32 -> bf16, split v = hi + lo (+eps ~2^-17|v|)
static __device__ __forceinline__ ushort f2b(float v) {
    unsigned u = __float_as_uint(v);
    unsigned r = u + 0x7fffu + ((u >> 16) & 1u);
    return (ushort)(r >> 16);
}
static __device__ __forceinline__ void bsplit(float v, ushort& h, ushort& l) {
    h = f2b(v);
    float hf = b2f(h);
    l = f2b(v - hf);
}

// ---------- float<->ordered-uint mapping for atomic fmax ----------
static __device__ __forceinline__ unsigned fkey(float f) {
    int i = __float_as_int(f);
    return (i >= 0) ? ((unsigned)i | 0x80000000u) : ~(unsigned)i;
}
static __device__ __forceinline__ float funkey(unsigned u) {
    int i = (u & 0x80000000u) ? (int)(u & 0x7fffffffu) : (int)~u;
    return __int_as_float(i);
}

// ---------- split x (fp32) -> xhi/xlo bf16, 2 elems/thread ----------
__global__ void k_split_x(const float* __restrict__ x,
                          ushort* __restrict__ xh, ushort* __restrict__ xl) {
    int gid = blockIdx.x * blockDim.x + threadIdx.x;
    if (gid >= NN * FIN / 2) return;
    float2 v = *(const float2*)(x + (size_t)gid * 2);
    ushort hx, lx, hy, ly;
    bsplit(v.x, hx, lx); bsplit(v.y, hy, ly);
    ushort2 h; h.x = hx; h.y = hy;
    ushort2 l; l.x = lx; l.y = ly;
    *(ushort2*)(xh + (size_t)gid * 2) = h;
    *(ushort2*)(xl + (size_t)gid * 2) = l;
}

// ---------- split+transpose weight: W[K][Nw] -> Bt[n][k] hi/lo, n<Npad ----------
__global__ void k_splitw(const float* __restrict__ W, int K, int Nw,
                         ushort* __restrict__ bh, ushort* __restrict__ bl) {
    int k = blockIdx.x * blockDim.x + threadIdx.x;
    int n = blockIdx.y;
    if (k >= K) return;
    float v = (n < Nw) ? W[(size_t)k * Nw + n] : 0.f;
    ushort h, l; bsplit(v, h, l);
    bh[(size_t)n * K + k] = h;
    bl[(size_t)n * K + k] = l;
}

// ---------- MFMA split-bf16 GEMM ----------
// wave computes 32 rows x NT*16 cols; block = 4 waves = 128 rows. No LDS.
// A = Ahi+Alo [M][K] bf16 (rows clamped to M-1 for OOB); B = Bt[n][K] bf16.
// mode 0: Cf = acc                       (fp32, ldc)
// mode 1: Chi/Clo = split(acc*t1[r] + bias[c] + addC[r][c])   (ldch)
// mode 2: Chi/Clo = split(relu(acc + bias[c]))                (ldch)
// mode 3: Cf = acc + bias[c], store only c < colmax           (fp32, ldc)
template<int NT>
__global__ __launch_bounds__(256) void k_mfma_gemm(
    const ushort* __restrict__ Ahi, const ushort* __restrict__ Alo,
    const ushort* __restrict__ Bthi, const ushort* __restrict__ Btlo,
    int M, int K, int mode,
    const float* __restrict__ bias, const float* __restrict__ t1,
    const float* __restrict__ addC, int ldadd,
    float* __restrict__ Cf, int ldc,
    ushort* __restrict__ Chi, ushort* __restrict__ Clo, int ldch,
    int colmax)
{
    const int lane = threadIdx.x & 63;
    const int wave = threadIdx.x >> 6;
    const int quad = lane >> 4;
    const int ln15 = lane & 15;
    const int row0 = (blockIdx.x * 4 + wave) * 32;
    const int col0 = blockIdx.y * (NT * 16);
    if (row0 >= M) return;

    f4v acc[2][NT] = {};

    int r0 = row0 + ln15;        if (r0 > M - 1) r0 = M - 1;
    int r1 = row0 + 16 + ln15;   if (r1 > M - 1) r1 = M - 1;
    const size_t a0 = (size_t)r0 * K;
    const size_t a1 = (size_t)r1 * K;
    size_t bb[NT];
    #pragma unroll
    for (int t = 0; t < NT; ++t) bb[t] = (size_t)(col0 + t * 16 + ln15) * K;

    for (int k0 = 0; k0 < K; k0 += 32) {
        const int ko = k0 + quad * 8;
        s8v ah0 = *(const s8v*)(Ahi + a0 + ko);
        s8v al0 = *(const s8v*)(Alo + a0 + ko);
        s8v ah1 = *(const s8v*)(Ahi + a1 + ko);
        s8v al1 = *(const s8v*)(Alo + a1 + ko);
        s8v bh[NT], bl[NT];
        #pragma unroll
        for (int t = 0; t < NT; ++t) {
            bh[t] = *(const s8v*)(Bthi + bb[t] + ko);
            bl[t] = *(const s8v*)(Btlo + bb[t] + ko);
        }
        #pragma unroll
        for (int t = 0; t < NT; ++t) {
            acc[0][t] = __builtin_amdgcn_mfma_f32_16x16x32_bf16(ah0, bh[t], acc[0][t], 0, 0, 0);
            acc[1][t] = __builtin_amdgcn_mfma_f32_16x16x32_bf16(ah1, bh[t], acc[1][t], 0, 0, 0);
            acc[0][t] = __builtin_amdgcn_mfma_f32_16x16x32_bf16(ah0, bl[t], acc[0][t], 0, 0, 0);
            acc[1][t] = __builtin_amdgcn_mfma_f32_16x16x32_bf16(ah1, bl[t], acc[1][t], 0, 0, 0);
            acc[0][t] = __builtin_amdgcn_mfma_f32_16x16x32_bf16(al0, bh[t], acc[0][t], 0, 0, 0);
            acc[1][t] = __builtin_amdgcn_mfma_f32_16x16x32_bf16(al1, bh[t], acc[1][t], 0, 0, 0);
        }
    }

    #pragma unroll
    for (int mt = 0; mt < 2; ++mt) {
        #pragma unroll
        for (int t = 0; t < NT; ++t) {
            #pragma unroll
            for (int r = 0; r < 4; ++r) {
                int rr = row0 + mt * 16 + quad * 4 + r;
                if (rr >= M) continue;
                int cc = col0 + t * 16 + ln15;
                float v = acc[mt][t][r];
                if (mode == 0) {
                    Cf[(size_t)rr * ldc + cc] = v;
                } else if (mode == 1) {
                    v = v * t1[rr] + bias[cc] + addC[(size_t)rr * ldadd + cc];
                    ushort h, l; bsplit(v, h, l);
                    Chi[(size_t)rr * ldch + cc] = h;
                    Clo[(size_t)rr * ldch + cc] = l;
                } else if (mode == 2) {
                    v += bias[cc];
                    v = v > 0.f ? v : 0.f;
                    ushort h, l; bsplit(v, h, l);
                    Chi[(size_t)rr * ldch + cc] = h;
                    Clo[(size_t)rr * ldch + cc] = l;
                } else {
                    if (cc < colmax) Cf[(size_t)rr * ldc + cc] = v + bias[cc];
                }
            }
        }
    }
}

// ---------- attention dots ----------
__global__ __launch_bounds__(256) void k_att_dots(
    const float* __restrict__ h, const float* __restrict__ ws_,
    const float* __restrict__ wd_, float* __restrict__ a_s,
    float* __restrict__ a_d)
{
    int node = blockIdx.x * 4 + (threadIdx.x >> 6);
    if (node >= NN) return;
    int lane = threadIdx.x & 63;
    float2 v  = *(const float2*)(h + (size_t)node * 128 + lane * 2);
    float2 w1 = *(const float2*)(ws_ + lane * 2);
    float2 w2 = *(const float2*)(wd_ + lane * 2);
    float s1 = v.x * w1.x + v.y * w1.y;
    float s2 = v.x * w2.x + v.y * w2.y;
    #pragma unroll
    for (int off = 32; off; off >>= 1) {
        s1 += __shfl_down(s1, off);
        s2 += __shfl_down(s2, off);
    }
    if (lane == 0) { a_s[node] = s1; a_d[node] = s2; }
}

// ---------- edge pass 1 ----------
__global__ void k_edge1(const int* __restrict__ src, const int* __restrict__ dst,
                        const float* __restrict__ a_s, const float* __restrict__ a_d,
                        float* __restrict__ ebuf, unsigned* __restrict__ mu,
                        int* __restrict__ degAll)
{
    int gid = blockIdx.x * blockDim.x + threadIdx.x;
    if (gid >= EE + NN) return;
    int s, d;
    if (gid < EE) { s = src[gid]; d = dst[gid]; } else { s = d = gid - EE; }
    float e = a_s[s] + a_d[d];
    e = (e > 0.f) ? e : 0.2f * e;
    ebuf[gid] = e;
    atomicMax(&mu[d], fkey(e));
    atomicAdd(&degAll[d], 1);
}

#define SCAN_T 256
__global__ __launch_bounds__(SCAN_T) void k_scan(
    const int* __restrict__ degAll, int* __restrict__ offs,
    int* __restrict__ cursor)
{
    __shared__ int part[SCAN_T];
    int t = threadIdx.x;
    const int chunk = (NN + SCAN_T - 1) / SCAN_T;
    int b = t * chunk;
    int e = b + chunk; if (e > NN) e = NN;
    int sum = 0;
    for (int i = b; i < e; ++i) sum += degAll[i];
    part[t] = sum;
    __syncthreads();
    for (int off = 1; off < SCAN_T; off <<= 1) {
        int v = (t >= off) ? part[t - off] : 0;
        __syncthreads();
        part[t] += v;
        __syncthreads();
    }
    int run = (t > 0) ? part[t - 1] : 0;
    for (int i = b; i < e; ++i) {
        offs[i] = run; cursor[i] = run;
        run += degAll[i];
    }
    if (t == SCAN_T - 1) offs[NN] = run;
}

__global__ void k_csr_fill(const int* __restrict__ dst, int* __restrict__ cursor,
                           int* __restrict__ eids)
{
    int gid = blockIdx.x * blockDim.x + threadIdx.x;
    if (gid >= EE + NN) return;
    int d = (gid < EE) ? dst[gid] : (gid - EE);
    int slot = atomicAdd(&cursor[d], 1);
    eids[slot] = gid;
}

__global__ void k_edge2(const int* __restrict__ dst,
                        float* __restrict__ ebuf, const unsigned* __restrict__ mu,
                        float* __restrict__ den)
{
    int gid = blockIdx.x * blockDim.x + threadIdx.x;
    if (gid >= EE + NN) return;
    int d = (gid < EE) ? dst[gid] : (gid - EE);
    float m = funkey(mu[d]);
    float ex = expf(ebuf[gid] - m);
    ebuf[gid] = ex;
    unsafeAtomicAdd(&den[d], ex);
}

__global__ void k_node_fin(const int* __restrict__ degAll, float* __restrict__ den,
                           float* __restrict__ dinv, float* __restrict__ rcnt)
{
    int i = blockIdx.x * blockDim.x + threadIdx.x;
    if (i >= NN) return;
    int da = degAll[i];
    dinv[i] = rsqrtf((float)da);
    den[i]  = 1.f / den[i];
    int cs = da - 1;
    rcnt[i] = 1.f / (float)(cs > 1 ? cs : 1);
}

// ---------- CSR gather: GAT+GCN (+bias) -> hch/hcl cols[0,256); SAGE sum -> agg hi/lo ----------
__global__ __launch_bounds__(256) void k_gather(
    const int* __restrict__ src,
    const int* __restrict__ eids, const int* __restrict__ offs,
    const float* __restrict__ ex, const float* __restrict__ rden,
    const float* __restrict__ dinv,
    const float* __restrict__ hgat, const float* __restrict__ hgcn,
    const float* __restrict__ x,
    const float* __restrict__ bg, const float* __restrict__ bc,
    ushort* __restrict__ hch, ushort* __restrict__ hcl,
    ushort* __restrict__ aggh, ushort* __restrict__ aggl)
{
    int d = blockIdx.x * 4 + (threadIdx.x >> 6);
    if (d >= NN) return;
    int lane = threadIdx.x & 63;
    int beg = offs[d], end = offs[d + 1];
    float rd = rden[d], dd = dinv[d];
    float2 ga = {0.f, 0.f}, gc = {0.f, 0.f}, sg = {0.f, 0.f};
    int c = lane * 2;

    for (int base = beg; base < end; base += 64) {
        int idx = base + lane;
        int s = 0; float wg = 0.f, wc = 0.f, fs = 0.f;
        if (idx < end) {
            int eid = eids[idx];
            if (eid < EE) { s = src[eid]; fs = 1.f; }
            else          { s = eid - EE; }
            wg = ex[eid] * rd;
            wc = dinv[s] * dd;
        }
        int cnt = end - base; if (cnt > 64) cnt = 64;
        for (int j = 0; j < cnt; ++j) {
            int   sj  = __shfl(s,  j);
            float wgj = __shfl(wg, j);
            float wcj = __shfl(wc, j);
            float fsj = __shfl(fs, j);
            const float2 hg = *(const float2*)(hgat + (size_t)sj * 128 + c);
            const float2 hc = *(const float2*)(hgcn + (size_t)sj * 128 + c);
            ga.x += wgj * hg.x; ga.y += wgj * hg.y;
            gc.x += wcj * hc.x; gc.y += wcj * hc.y;
            if (fsj != 0.f) {
                const float2 xv = *(const float2*)(x + (size_t)sj * 128 + c);
                sg.x += xv.x; sg.y += xv.y;
            }
        }
    }
    ga.x += bg[c]; ga.y += bg[c + 1];
    gc.x += bc[c]; gc.y += bc[c + 1];
    ushort h0, l0, h1, l1;
    size_t row = (size_t)d * C3;
    bsplit(ga.x, h0, l0); bsplit(ga.y, h1, l1);
    { ushort2 u; u.x = h0; u.y = h1; *(ushort2*)(hch + row + c) = u; }
    { ushort2 u; u.x = l0; u.y = l1; *(ushort2*)(hcl + row + c) = u; }
    bsplit(gc.x, h0, l0); bsplit(gc.y, h1, l1);
    { ushort2 u; u.x = h0; u.y = h1; *(ushort2*)(hch + row + 128 + c) = u; }
    { ushort2 u; u.x = l0; u.y = l1; *(ushort2*)(hcl + row + 128 + c) = u; }
    bsplit(sg.x, h0, l0); bsplit(sg.y, h1, l1);
    { ushort2 u; u.x = h0; u.y = h1; *(ushort2*)(aggh + (size_t)d * 128 + c) = u; }
    { ushort2 u; u.x = l0; u.y = l1; *(ushort2*)(aggl + (size_t)d * 128 + c) = u; }
}

// ---------- batchnorm stats over split hcat ----------
__global__ __launch_bounds__(128) void k_bn_stats(
    const ushort* __restrict__ hch, const ushort* __restrict__ hcl,
    float* __restrict__ sums, float* __restrict__ sumsq)
{
    int t = threadIdx.x; // cols t, t+128, t+256
    float s0 = 0, s1 = 0, s2 = 0, q0 = 0, q1 = 0, q2 = 0;
    for (int i = blockIdx.x; i < NN; i += gridDim.x) {
        const ushort* rh = hch + (size_t)i * C3;
        const ushort* rl = hcl + (size_t)i * C3;
        float v0 = b2f(rh[t])       + b2f(rl[t]);
        float v1 = b2f(rh[t + 128]) + b2f(rl[t + 128]);
        float v2 = b2f(rh[t + 256]) + b2f(rl[t + 256]);
        s0 += v0; q0 += v0 * v0;
        s1 += v1; q1 += v1 * v1;
        s2 += v2; q2 += v2 * v2;
    }
    unsafeAtomicAdd(&sums[t],        s0);
    unsafeAtomicAdd(&sums[t + 128],  s1);
    unsafeAtomicAdd(&sums[t + 256],  s2);
    unsafeAtomicAdd(&sumsq[t],       q0);
    unsafeAtomicAdd(&sumsq[t + 128], q1);
    unsafeAtomicAdd(&sumsq[t + 256], q2);
}

__global__ void k_bn_final(const float* __restrict__ sums, const float* __restrict__ sumsq,
                           const float* __restrict__ gamma, const float* __restrict__ beta,
                           float* __restrict__ scale, float* __restrict__ shift)
{
    int j = threadIdx.x;
    if (j >= C3) return;
    const float rn = 1.f / (float)NN;
    float mu  = sums[j] * rn;
    float var = sumsq[j] * rn - mu * mu;
    float sc  = gamma[j] * rsqrtf(var + 1e-5f);
    scale[j] = sc;
    shift[j] = beta[j] - mu * sc;
}

// ---------- in-place BN+relu transform of split hcat ----------
__global__ __launch_bounds__(192) void k_bnrelu(
    ushort* __restrict__ hch, ushort* __restrict__ hcl,
    const float* __restrict__ scale, const float* __restrict__ shift)
{
    int r = blockIdx.x;
    int c = threadIdx.x * 2;
    size_t o = (size_t)r * C3 + c;
    ushort2 h = *(ushort2*)(hch + o);
    ushort2 l = *(ushort2*)(hcl + o);
    float v0 = b2f(h.x) + b2f(l.x);
    float v1 = b2f(h.y) + b2f(l.y);
    v0 = v0 * scale[c] + shift[c];         v0 = v0 > 0.f ? v0 : 0.f;
    v1 = v1 * scale[c + 1] + shift[c + 1]; v1 = v1 > 0.f ? v1 : 0.f;
    ushort h0, l0, h1, l1;
    bsplit(v0, h0, l0); bsplit(v1, h1, l1);
    { ushort2 u; u.x = h0; u.y = h1; *(ushort2*)(hch + o) = u; }
    { ushort2 u; u.x = l0; u.y = l1; *(ushort2*)(hcl + o) = u; }
}

extern "C" void kernel_launch(void* const* d_in, const int* in_sizes, int n_in,
                              void* d_out, int out_size, void* d_ws, size_t ws_size,
                              hipStream_t stream) {
    const float* x        = (const float*)d_in[0];
    const int*   ei       = (const int*)d_in[1];
    const float* W_gat    = (const float*)d_in[2];
    const float* att_src  = (const float*)d_in[3];
    const float* att_dst  = (const float*)d_in[4];
    const float* b_gat    = (const float*)d_in[5];
    const float* W_gcn    = (const float*)d_in[6];
    const float* b_gcn    = (const float*)d_in[7];
    const float* W_sage_l = (const float*)d_in[8];
    const float* b_sage_l = (const float*)d_in[9];
    const float* W_sage_r = (const float*)d_in[10];
    const float* W1       = (const float*)d_in[11];
    const float* b1       = (const float*)d_in[12];
    const float* W2       = (const float*)d_in[13];
    const float* b2       = (const float*)d_in[14];
    const float* W3       = (const float*)d_in[15];
    const float* b3       = (const float*)d_in[16];
    const float* gamma    = (const float*)d_in[17];
    const float* beta     = (const float*)d_in[18];

    const int* e_src = ei;
    const int* e_dst = ei + EE;

    // ---- workspace layout (byte offsets; overlays noted) ----
    char* base = (char*)d_ws;
    size_t o = 0;
    ushort* hch  = (ushort*)(base + o); o += (size_t)NN * C3 * 2;        // 38.4MB
    ushort* hcl  = (ushort*)(base + o); o += (size_t)NN * C3 * 2;        // 38.4MB
    float*  hgat = (float*)(base + o);  o += (size_t)NN * 128 * 4;       // 25.6MB (reuse: a1h)
    float*  hgcn = (float*)(base + o);  o += (size_t)NN * 128 * 4;       // 25.6MB (reuse: a1l)
    float*  xwr  = (float*)(base + o);  o += (size_t)NN * 128 * 4;       // 25.6MB (reuse: a2h+a2l)
    char*   X    = base + o;            o += (size_t)NN * 128 * 4;       // 25.6MB multi-use
    float*  ebuf = (float*)(base + o);  o += (size_t)(EE + NN) * 4;
    int*    eids = (int*)(base + o);    o += (size_t)(EE + NN) * 4;
    float*  dinv = (float*)(base + o);  o += (size_t)NN * 4;
    float*  rcnt = (float*)(base + o);  o += (size_t)NN * 4;
    int*    offs = (int*)(base + o);    o += (size_t)(NN + 16) * 4;
    unsigned* mu_ = (unsigned*)(base + o); o += (size_t)NN * 4;          // zeroed (memset#1)
    float*  den  = (float*)(base + o);  o += (size_t)NN * 4;             // zeroed (memset#1)
    float*  sums = (float*)(base + o);  o += C3 * 4;                     // zeroed (memset#1)
    float*  sumsq= (float*)(base + o);  o += C3 * 4;                     // zeroed (memset#1)
    float*  scale= (float*)(base + o);  o += C3 * 4;
    float*  shift= (float*)(base + o);  o += C3 * 4;
    // split-transposed weights (hi/lo)
    ushort* btg_h = (ushort*)(base + o); o += 128 * 128 * 2;
    ushort* btg_l = (ushort*)(base + o); o += 128 * 128 * 2;
    ushort* btc_h = (ushort*)(base + o); o += 128 * 128 * 2;
    ushort* btc_l = (ushort*)(base + o); o += 128 * 128 * 2;
    ushort* btr_h = (ushort*)(base + o); o += 128 * 128 * 2;
    ushort* btr_l = (ushort*)(base + o); o += 128 * 128 * 2;
    ushort* btl_h = (ushort*)(base + o); o += 128 * 128 * 2;
    ushort* btl_l = (ushort*)(base + o); o += 128 * 128 * 2;
    ushort* bt1_h = (ushort*)(base + o); o += 256 * 384 * 2;
    ushort* bt1_l = (ushort*)(base + o); o += 256 * 384 * 2;
    ushort* bt2_h = (ushort*)(base + o); o += 128 * 256 * 2;
    ushort* bt2_l = (ushort*)(base + o); o += 128 * 256 * 2;
    ushort* bt3_h = (ushort*)(base + o); o += 48 * 128 * 2;
    ushort* bt3_l = (ushort*)(base + o); o += 48 * 128 * 2;
    // X-region overlays (temporally disjoint):
    ushort* xhi = (ushort*)X;                                  // until gemm3
    ushort* xlo = (ushort*)(X + (size_t)NN * 128 * 2);
    float*  as_ = (float*)X;                                   // att_dots -> edge1
    float*  ad_ = (float*)(X + 200000);
    int*    degA = (int*)(X + 400000);                         // edge1 -> node_fin (memset#2)
    int*    cursor = (int*)(X + 600000);                       // scan -> csr_fill
    ushort* aggh = (ushort*)X;                                 // gather -> sage gemm
    ushort* aggl = (ushort*)(X + (size_t)NN * 128 * 2);
    // post-gather reuses:
    ushort* a1h = (ushort*)hgat;   // NN*256 bf16 == NN*128 fp32 bytes
    ushort* a1l = (ushort*)hgcn;
    ushort* a2h = (ushort*)xwr;
    ushort* a2l = (ushort*)xwr + (size_t)NN * 128;

    // ---- memset #1: mu_, den, sums, sumsq (contiguous) ----
    hipMemsetAsync(mu_, 0, (size_t)2 * NN * 4 + 2 * C3 * 4, stream);

    // ---- splits ----
    k_split_x<<<(NN * FIN / 2 + 255) / 256, 256, 0, stream>>>(x, xhi, xlo);
    k_splitw<<<dim3(1, 128), 256, 0, stream>>>(W_gat,    128, 128, btg_h, btg_l);
    k_splitw<<<dim3(1, 128), 256, 0, stream>>>(W_gcn,    128, 128, btc_h, btc_l);
    k_splitw<<<dim3(1, 128), 256, 0, stream>>>(W_sage_r, 128, 128, btr_h, btr_l);
    k_splitw<<<dim3(1, 128), 256, 0, stream>>>(W_sage_l, 128, 128, btl_h, btl_l);
    k_splitw<<<dim3(2, 256), 256, 0, stream>>>(W1,       384, 256, bt1_h, bt1_l);
    k_splitw<<<dim3(1, 128), 256, 0, stream>>>(W2,       256, 128, bt2_h, bt2_l);
    k_splitw<<<dim3(1,  48), 256, 0, stream>>>(W3,       128,  40, bt3_h, bt3_l);

    // ---- node-feature GEMMs (MFMA): h_gat, h_gcn, xwr ----
    dim3 gg((NN + 127) / 128, 1);
    k_mfma_gemm<8><<<gg, 256, 0, stream>>>(xhi, xlo, btg_h, btg_l, NN, 128, 0,
        nullptr, nullptr, nullptr, 0, hgat, 128, nullptr, nullptr, 0, 128);
    k_mfma_gemm<8><<<gg, 256, 0, stream>>>(xhi, xlo, btc_h, btc_l, NN, 128, 0,
        nullptr, nullptr, nullptr, 0, hgcn, 128, nullptr, nullptr, 0, 128);
    k_mfma_gemm<8><<<gg, 256, 0, stream>>>(xhi, xlo, btr_h, btr_l, NN, 128, 0,
        nullptr, nullptr, nullptr, 0, xwr, 128, nullptr, nullptr, 0, 128);

    // ---- memset #2: degA (X region free of xhi now) ----
    hipMemsetAsync(degA, 0, (size_t)NN * 4, stream);

    // ---- GAT attention logits ----
    k_att_dots<<<(NN + 3) / 4, 256, 0, stream>>>(hgat, att_src, att_dst, as_, ad_);

    // ---- edge passes + CSR build ----
    int eb = (EE + NN + 255) / 256;
    k_edge1<<<eb, 256, 0, stream>>>(e_src, e_dst, as_, ad_, ebuf, mu_, degA);
    k_scan<<<1, SCAN_T, 0, stream>>>(degA, offs, cursor);
    k_csr_fill<<<eb, 256, 0, stream>>>(e_dst, cursor, eids);
    k_edge2<<<eb, 256, 0, stream>>>(e_dst, ebuf, mu_, den);
    k_node_fin<<<(NN + 255) / 256, 256, 0, stream>>>(degA, den, dinv, rcnt);

    // ---- gather: GAT/GCN -> hch/hcl[:,0:256), SAGE sum -> agg hi/lo ----
    k_gather<<<(NN + 3) / 4, 256, 0, stream>>>(
        e_src, eids, offs, ebuf, den, dinv, hgat, hgcn, x, b_gat, b_gcn,
        hch, hcl, aggh, aggl);

    // ---- SAGE: rcnt[r]*(agg@W_l) + b_l + xwr -> hch/hcl[:,256:384) ----
    k_mfma_gemm<8><<<gg, 256, 0, stream>>>(aggh, aggl, btl_h, btl_l, NN, 128, 1,
        b_sage_l, rcnt, xwr, 128, nullptr, 0, hch + 256, hcl + 256, C3, 128);

    // ---- BatchNorm stats + fold; in-place BN+relu transform ----
    k_bn_stats<<<256, 128, 0, stream>>>(hch, hcl, sums, sumsq);
    k_bn_final<<<1, C3, 0, stream>>>(sums, sumsq, gamma, beta, scale, shift);
    k_bnrelu<<<NN, 192, 0, stream>>>(hch, hcl, scale, shift);

    // ---- MLP (MFMA, split activations end-to-end) ----
    dim3 g1((NN + 127) / 128, 2);
    k_mfma_gemm<8><<<g1, 256, 0, stream>>>(hch, hcl, bt1_h, bt1_l, NN, 384, 2,
        b1, nullptr, nullptr, 0, nullptr, 0, a1h, a1l, 256, 256);
    k_mfma_gemm<8><<<gg, 256, 0, stream>>>(a1h, a1l, bt2_h, bt2_l, NN, 256, 2,
        b2, nullptr, nullptr, 0, nullptr, 0, a2h, a2l, 128, 128);
    k_mfma_gemm<3><<<gg, 256, 0, stream>>>(a2h, a2l, bt3_h, bt3_l, NN, 128, 3,
        b3, nullptr, nullptr, 0, (float*)d_out, NOUT, nullptr, nullptr, 0, NOUT);
}

// Round 4
// 975.133 us; speedup vs baseline: 3.3120x; 1.0891x over previous
//
#include <hip/hip_runtime.h>
#include <cstdint>
#include <cstddef>

#define NN   50000
#define FIN  128
#define HD   128
#define EE   800000
#define C3   384   // 3*H
#define NOUT 40

typedef __attribute__((ext_vector_type(8))) short s8v;   // 8 x bf16 (4 VGPR)
typedef __attribute__((ext_vector_type(4))) float f4v;   // MFMA acc

// ---------- bf16 helpers ----------
static __device__ __forceinline__ float b2f(ushort u) {
    return __uint_as_float((unsigned)u << 16);
}
static __device__ __forceinline__ ushort f2b(float v) {
    unsigned u = __float_as_uint(v);
    unsigned r = u + 0x7fffu + ((u >> 16) & 1u);
    return (ushort)(r >> 16);
}
static __device__ __forceinline__ void bsplit(float v, ushort& h, ushort& l) {
    h = f2b(v);
    float hf = b2f(h);
    l = f2b(v - hf);
}

// ---------- float<->ordered-uint mapping for atomic fmax ----------
static __device__ __forceinline__ unsigned fkey(float f) {
    int i = __float_as_int(f);
    return (i >= 0) ? ((unsigned)i | 0x80000000u) : ~(unsigned)i;
}
static __device__ __forceinline__ float funkey(unsigned u) {
    int i = (u & 0x80000000u) ? (int)(u & 0x7fffffffu) : (int)~u;
    return __int_as_float(i);
}

// ---------- split x (fp32) -> xhi/xlo bf16 ----------
__global__ void k_split_x(const float* __restrict__ x,
                          ushort* __restrict__ xh, ushort* __restrict__ xl) {
    int gid = blockIdx.x * blockDim.x + threadIdx.x;
    if (gid >= NN * FIN / 2) return;
    float2 v = *(const float2*)(x + (size_t)gid * 2);
    ushort hx, lx, hy, ly;
    bsplit(v.x, hx, lx); bsplit(v.y, hy, ly);
    ushort2 h; h.x = hx; h.y = hy;
    ushort2 l; l.x = lx; l.y = ly;
    *(ushort2*)(xh + (size_t)gid * 2) = h;
    *(ushort2*)(xl + (size_t)gid * 2) = l;
}

// ---------- split+transpose weight: W[K][Nw] -> Bt[n][k] hi/lo ----------
__global__ void k_splitw(const float* __restrict__ W, int K, int Nw,
                         ushort* __restrict__ bh, ushort* __restrict__ bl) {
    int k = blockIdx.x * blockDim.x + threadIdx.x;
    int n = blockIdx.y;
    if (k >= K) return;
    float v = (n < Nw) ? W[(size_t)k * Nw + n] : 0.f;
    ushort h, l; bsplit(v, h, l);
    bh[(size_t)n * K + k] = h;
    bl[(size_t)n * K + k] = l;
}

// ---------- fold attention vectors: w_as = W_gat @ att_src (len 128) ----------
__global__ void k_att_w(const float* __restrict__ Wg,
                        const float* __restrict__ asv, const float* __restrict__ adv,
                        float* __restrict__ w_as, float* __restrict__ w_ad) {
    int f = threadIdx.x;  // 128
    float s1 = 0.f, s2 = 0.f;
    for (int j = 0; j < 128; ++j) {
        float w = Wg[f * 128 + j];
        s1 += w * asv[j];
        s2 += w * adv[j];
    }
    w_as[f] = s1; w_ad[f] = s2;
}

// ---------- MFMA split-bf16 GEMM ----------
// wave = 32 rows x NT*16 cols; block = 4 waves = 128 rows. No LDS.
// mode 0: Cf = acc (fp32, ldc)
// mode 1: Chi/Clo = split(acc*t1[r] + bias[c] + addC[r][c])
// mode 2: Chi/Clo = split(relu(acc + bias[c]))
// mode 3: Cf = acc + bias[c], store only c < colmax (fp32)
// mode 4: Chi/Clo = split(acc + bias[c])
template<int NT>
__global__ __launch_bounds__(256) void k_mfma_gemm(
    const ushort* __restrict__ Ahi, const ushort* __restrict__ Alo,
    const ushort* __restrict__ Bthi, const ushort* __restrict__ Btlo,
    int M, int K, int mode,
    const float* __restrict__ bias, const float* __restrict__ t1,
    const float* __restrict__ addC, int ldadd,
    float* __restrict__ Cf, int ldc,
    ushort* __restrict__ Chi, ushort* __restrict__ Clo, int ldch,
    int colmax)
{
    const int lane = threadIdx.x & 63;
    const int wave = threadIdx.x >> 6;
    const int quad = lane >> 4;
    const int ln15 = lane & 15;
    const int row0 = (blockIdx.x * 4 + wave) * 32;
    const int col0 = blockIdx.y * (NT * 16);
    if (row0 >= M) return;

    f4v acc[2][NT] = {};

    int r0 = row0 + ln15;        if (r0 > M - 1) r0 = M - 1;
    int r1 = row0 + 16 + ln15;   if (r1 > M - 1) r1 = M - 1;
    const size_t a0 = (size_t)r0 * K;
    const size_t a1 = (size_t)r1 * K;
    size_t bb[NT];
    #pragma unroll
    for (int t = 0; t < NT; ++t) bb[t] = (size_t)(col0 + t * 16 + ln15) * K;

    for (int k0 = 0; k0 < K; k0 += 32) {
        const int ko = k0 + quad * 8;
        s8v ah0 = *(const s8v*)(Ahi + a0 + ko);
        s8v al0 = *(const s8v*)(Alo + a0 + ko);
        s8v ah1 = *(const s8v*)(Ahi + a1 + ko);
        s8v al1 = *(const s8v*)(Alo + a1 + ko);
        s8v bh[NT], bl[NT];
        #pragma unroll
        for (int t = 0; t < NT; ++t) {
            bh[t] = *(const s8v*)(Bthi + bb[t] + ko);
            bl[t] = *(const s8v*)(Btlo + bb[t] + ko);
        }
        #pragma unroll
        for (int t = 0; t < NT; ++t) {
            acc[0][t] = __builtin_amdgcn_mfma_f32_16x16x32_bf16(ah0, bh[t], acc[0][t], 0, 0, 0);
            acc[1][t] = __builtin_amdgcn_mfma_f32_16x16x32_bf16(ah1, bh[t], acc[1][t], 0, 0, 0);
            acc[0][t] = __builtin_amdgcn_mfma_f32_16x16x32_bf16(ah0, bl[t], acc[0][t], 0, 0, 0);
            acc[1][t] = __builtin_amdgcn_mfma_f32_16x16x32_bf16(ah1, bl[t], acc[1][t], 0, 0, 0);
            acc[0][t] = __builtin_amdgcn_mfma_f32_16x16x32_bf16(al0, bh[t], acc[0][t], 0, 0, 0);
            acc[1][t] = __builtin_amdgcn_mfma_f32_16x16x32_bf16(al1, bh[t], acc[1][t], 0, 0, 0);
        }
    }

    #pragma unroll
    for (int mt = 0; mt < 2; ++mt) {
        #pragma unroll
        for (int t = 0; t < NT; ++t) {
            #pragma unroll
            for (int r = 0; r < 4; ++r) {
                int rr = row0 + mt * 16 + quad * 4 + r;
                if (rr >= M) continue;
                int cc = col0 + t * 16 + ln15;
                float v = acc[mt][t][r];
                if (mode == 0) {
                    Cf[(size_t)rr * ldc + cc] = v;
                } else if (mode == 1) {
                    v = v * t1[rr] + bias[cc] + addC[(size_t)rr * ldadd + cc];
                    ushort h, l; bsplit(v, h, l);
                    Chi[(size_t)rr * ldch + cc] = h;
                    Clo[(size_t)rr * ldch + cc] = l;
                } else if (mode == 2) {
                    v += bias[cc];
                    v = v > 0.f ? v : 0.f;
                    ushort h, l; bsplit(v, h, l);
                    Chi[(size_t)rr * ldch + cc] = h;
                    Clo[(size_t)rr * ldch + cc] = l;
                } else if (mode == 4) {
                    v += bias[cc];
                    ushort h, l; bsplit(v, h, l);
                    Chi[(size_t)rr * ldch + cc] = h;
                    Clo[(size_t)rr * ldch + cc] = l;
                } else {
                    if (cc < colmax) Cf[(size_t)rr * ldc + cc] = v + bias[cc];
                }
            }
        }
    }
}

// ---------- attention dots directly from x ----------
__global__ __launch_bounds__(256) void k_att_dots(
    const float* __restrict__ x, const float* __restrict__ w_as,
    const float* __restrict__ w_ad, float* __restrict__ a_s,
    float* __restrict__ a_d)
{
    int node = blockIdx.x * 4 + (threadIdx.x >> 6);
    if (node >= NN) return;
    int lane = threadIdx.x & 63;
    float2 v  = *(const float2*)(x + (size_t)node * 128 + lane * 2);
    float2 w1 = *(const float2*)(w_as + lane * 2);
    float2 w2 = *(const float2*)(w_ad + lane * 2);
    float s1 = v.x * w1.x + v.y * w1.y;
    float s2 = v.x * w2.x + v.y * w2.y;
    #pragma unroll
    for (int off = 32; off; off >>= 1) {
        s1 += __shfl_down(s1, off);
        s2 += __shfl_down(s2, off);
    }
    if (lane == 0) { a_s[node] = s1; a_d[node] = s2; }
}

// ---------- edge pass 1 ----------
__global__ void k_edge1(const int* __restrict__ src, const int* __restrict__ dst,
                        const float* __restrict__ a_s, const float* __restrict__ a_d,
                        float* __restrict__ ebuf, unsigned* __restrict__ mu,
                        int* __restrict__ degAll)
{
    int gid = blockIdx.x * blockDim.x + threadIdx.x;
    if (gid >= EE + NN) return;
    int s, d;
    if (gid < EE) { s = src[gid]; d = dst[gid]; } else { s = d = gid - EE; }
    float e = a_s[s] + a_d[d];
    e = (e > 0.f) ? e : 0.2f * e;
    ebuf[gid] = e;
    atomicMax(&mu[d], fkey(e));
    atomicAdd(&degAll[d], 1);
}

#define SCAN_T 256
__global__ __launch_bounds__(SCAN_T) void k_scan(
    const int* __restrict__ degAll, int* __restrict__ offs,
    int* __restrict__ cursor)
{
    __shared__ int part[SCAN_T];
    int t = threadIdx.x;
    const int chunk = (NN + SCAN_T - 1) / SCAN_T;
    int b = t * chunk;
    int e = b + chunk; if (e > NN) e = NN;
    int sum = 0;
    for (int i = b; i < e; ++i) sum += degAll[i];
    part[t] = sum;
    __syncthreads();
    for (int off = 1; off < SCAN_T; off <<= 1) {
        int v = (t >= off) ? part[t - off] : 0;
        __syncthreads();
        part[t] += v;
        __syncthreads();
    }
    int run = (t > 0) ? part[t - 1] : 0;
    for (int i = b; i < e; ++i) {
        offs[i] = run; cursor[i] = run;
        run += degAll[i];
    }
    if (t == SCAN_T - 1) offs[NN] = run;
}

__global__ void k_csr_fill(const int* __restrict__ dst, int* __restrict__ cursor,
                           int* __restrict__ eids)
{
    int gid = blockIdx.x * blockDim.x + threadIdx.x;
    if (gid >= EE + NN) return;
    int d = (gid < EE) ? dst[gid] : (gid - EE);
    int slot = atomicAdd(&cursor[d], 1);
    eids[slot] = gid;
}

__global__ void k_edge2(const int* __restrict__ dst,
                        float* __restrict__ ebuf, const unsigned* __restrict__ mu,
                        float* __restrict__ den)
{
    int gid = blockIdx.x * blockDim.x + threadIdx.x;
    if (gid >= EE + NN) return;
    int d = (gid < EE) ? dst[gid] : (gid - EE);
    float m = funkey(mu[d]);
    float ex = expf(ebuf[gid] - m);
    ebuf[gid] = ex;
    unsafeAtomicAdd(&den[d], ex);
}

__global__ void k_node_fin(const int* __restrict__ degAll, float* __restrict__ den,
                           float* __restrict__ dinv, float* __restrict__ rcnt)
{
    int i = blockIdx.x * blockDim.x + threadIdx.x;
    if (i >= NN) return;
    int da = degAll[i];
    dinv[i] = rsqrtf((float)da);
    den[i]  = 1.f / den[i];
    int cs = da - 1;
    rcnt[i] = 1.f / (float)(cs > 1 ? cs : 1);
}

// ---------- CSR gather: weighted x-sums only ----------
// t_gat = sum wg*x[s]; t_gcn = sum wc*x[s]; t_sage = sum x[s] (excl self) =
// (sum over all edges incl self) - x[d]. Outputs split bf16.
__global__ __launch_bounds__(256) void k_gather(
    const int* __restrict__ src,
    const int* __restrict__ eids, const int* __restrict__ offs,
    const float* __restrict__ ex, const float* __restrict__ rden,
    const float* __restrict__ dinv,
    const float* __restrict__ x,
    ushort* __restrict__ tgh, ushort* __restrict__ tgl,
    ushort* __restrict__ tch, ushort* __restrict__ tcl,
    ushort* __restrict__ tsh, ushort* __restrict__ tsl)
{
    int d = blockIdx.x * 4 + (threadIdx.x >> 6);
    if (d >= NN) return;
    int lane = threadIdx.x & 63;
    int beg = offs[d], end = offs[d + 1];
    float rd = rden[d], dd = dinv[d];
    float2 tg = {0.f, 0.f}, tc = {0.f, 0.f}, ts = {0.f, 0.f};
    int c = lane * 2;

    for (int base = beg; base < end; base += 64) {
        int idx = base + lane;
        int s = 0; float wg = 0.f, wc = 0.f;
        if (idx < end) {
            int eid = eids[idx];
            s = (eid < EE) ? src[eid] : (eid - EE);
            wg = ex[eid] * rd;
            wc = dinv[s] * dd;
        }
        int cnt = end - base; if (cnt > 64) cnt = 64;
        for (int j = 0; j < cnt; ++j) {
            int   sj  = __shfl(s,  j);
            float wgj = __shfl(wg, j);
            float wcj = __shfl(wc, j);
            const float2 xv = *(const float2*)(x + (size_t)sj * 128 + c);
            tg.x += wgj * xv.x; tg.y += wgj * xv.y;
            tc.x += wcj * xv.x; tc.y += wcj * xv.y;
            ts.x += xv.x;       ts.y += xv.y;
        }
    }
    // remove self-loop contribution from SAGE sum
    const float2 xd = *(const float2*)(x + (size_t)d * 128 + c);
    ts.x -= xd.x; ts.y -= xd.y;

    size_t row = (size_t)d * 128 + c;
    ushort h0, l0, h1, l1;
    bsplit(tg.x, h0, l0); bsplit(tg.y, h1, l1);
    { ushort2 u; u.x = h0; u.y = h1; *(ushort2*)(tgh + row) = u; }
    { ushort2 u; u.x = l0; u.y = l1; *(ushort2*)(tgl + row) = u; }
    bsplit(tc.x, h0, l0); bsplit(tc.y, h1, l1);
    { ushort2 u; u.x = h0; u.y = h1; *(ushort2*)(tch + row) = u; }
    { ushort2 u; u.x = l0; u.y = l1; *(ushort2*)(tcl + row) = u; }
    bsplit(ts.x, h0, l0); bsplit(ts.y, h1, l1);
    { ushort2 u; u.x = h0; u.y = h1; *(ushort2*)(tsh + row) = u; }
    { ushort2 u; u.x = l0; u.y = l1; *(ushort2*)(tsl + row) = u; }
}

// ---------- batchnorm stats over split hcat ----------
__global__ __launch_bounds__(128) void k_bn_stats(
    const ushort* __restrict__ hch, const ushort* __restrict__ hcl,
    float* __restrict__ sums, float* __restrict__ sumsq)
{
    int t = threadIdx.x;
    float s0 = 0, s1 = 0, s2 = 0, q0 = 0, q1 = 0, q2 = 0;
    for (int i = blockIdx.x; i < NN; i += gridDim.x) {
        const ushort* rh = hch + (size_t)i * C3;
        const ushort* rl = hcl + (size_t)i * C3;
        float v0 = b2f(rh[t])       + b2f(rl[t]);
        float v1 = b2f(rh[t + 128]) + b2f(rl[t + 128]);
        float v2 = b2f(rh[t + 256]) + b2f(rl[t + 256]);
        s0 += v0; q0 += v0 * v0;
        s1 += v1; q1 += v1 * v1;
        s2 += v2; q2 += v2 * v2;
    }
    unsafeAtomicAdd(&sums[t],        s0);
    unsafeAtomicAdd(&sums[t + 128],  s1);
    unsafeAtomicAdd(&sums[t + 256],  s2);
    unsafeAtomicAdd(&sumsq[t],       q0);
    unsafeAtomicAdd(&sumsq[t + 128], q1);
    unsafeAtomicAdd(&sumsq[t + 256], q2);
}

__global__ void k_bn_final(const float* __restrict__ sums, const float* __restrict__ sumsq,
                           const float* __restrict__ gamma, const float* __restrict__ beta,
                           float* __restrict__ scale, float* __restrict__ shift)
{
    int j = threadIdx.x;
    if (j >= C3) return;
    const float rn = 1.f / (float)NN;
    float mu  = sums[j] * rn;
    float var = sumsq[j] * rn - mu * mu;
    float sc  = gamma[j] * rsqrtf(var + 1e-5f);
    scale[j] = sc;
    shift[j] = beta[j] - mu * sc;
}

// ---------- in-place BN+relu transform of split hcat ----------
__global__ __launch_bounds__(192) void k_bnrelu(
    ushort* __restrict__ hch, ushort* __restrict__ hcl,
    const float* __restrict__ scale, const float* __restrict__ shift)
{
    int r = blockIdx.x;
    int c = threadIdx.x * 2;
    size_t o = (size_t)r * C3 + c;
    ushort2 h = *(ushort2*)(hch + o);
    ushort2 l = *(ushort2*)(hcl + o);
    float v0 = b2f(h.x) + b2f(l.x);
    float v1 = b2f(h.y) + b2f(l.y);
    v0 = v0 * scale[c] + shift[c];         v0 = v0 > 0.f ? v0 : 0.f;
    v1 = v1 * scale[c + 1] + shift[c + 1]; v1 = v1 > 0.f ? v1 : 0.f;
    ushort h0, l0, h1, l1;
    bsplit(v0, h0, l0); bsplit(v1, h1, l1);
    { ushort2 u; u.x = h0; u.y = h1; *(ushort2*)(hch + o) = u; }
    { ushort2 u; u.x = l0; u.y = l1; *(ushort2*)(hcl + o) = u; }
}

extern "C" void kernel_launch(void* const* d_in, const int* in_sizes, int n_in,
                              void* d_out, int out_size, void* d_ws, size_t ws_size,
                              hipStream_t stream) {
    const float* x        = (const float*)d_in[0];
    const int*   ei       = (const int*)d_in[1];
    const float* W_gat    = (const float*)d_in[2];
    const float* att_src  = (const float*)d_in[3];
    const float* att_dst  = (const float*)d_in[4];
    const float* b_gat    = (const float*)d_in[5];
    const float* W_gcn    = (const float*)d_in[6];
    const float* b_gcn    = (const float*)d_in[7];
    const float* W_sage_l = (const float*)d_in[8];
    const float* b_sage_l = (const float*)d_in[9];
    const float* W_sage_r = (const float*)d_in[10];
    const float* W1       = (const float*)d_in[11];
    const float* b1       = (const float*)d_in[12];
    const float* W2       = (const float*)d_in[13];
    const float* b2       = (const float*)d_in[14];
    const float* W3       = (const float*)d_in[15];
    const float* b3       = (const float*)d_in[16];
    const float* gamma    = (const float*)d_in[17];
    const float* beta     = (const float*)d_in[18];

    const int* e_src = ei;
    const int* e_dst = ei + EE;

    // ---- workspace layout ----
    char* base = (char*)d_ws;
    size_t o = 0;
    ushort* hch  = (ushort*)(base + o); o += (size_t)NN * C3 * 2;   // 38.4MB
    ushort* hcl  = (ushort*)(base + o); o += (size_t)NN * C3 * 2;   // 38.4MB
    float*  xwr  = (float*)(base + o);  o += (size_t)NN * 128 * 4;  // 25.6MB (reuse: a2h/a2l)
    char*   X    = base + o;            o += (size_t)NN * 128 * 4;  // 25.6MB multi-use
    ushort* tgh  = (ushort*)(base + o); o += (size_t)NN * 128 * 2;  // 12.8MB (reuse: a1h)
    ushort* tgl  = (ushort*)(base + o); o += (size_t)NN * 128 * 2;  // 12.8MB
    ushort* tch  = (ushort*)(base + o); o += (size_t)NN * 128 * 2;  // 12.8MB (reuse: a1l)
    ushort* tcl  = (ushort*)(base + o); o += (size_t)NN * 128 * 2;  // 12.8MB
    float*  ebuf = (float*)(base + o);  o += (size_t)(EE + NN) * 4;
    int*    eids = (int*)(base + o);    o += (size_t)(EE + NN) * 4;
    float*  dinv = (float*)(base + o);  o += (size_t)NN * 4;
    float*  rcnt = (float*)(base + o);  o += (size_t)NN * 4;
    int*    offs = (int*)(base + o);    o += (size_t)(NN + 16) * 4;
    unsigned* mu_ = (unsigned*)(base + o); o += (size_t)NN * 4;     // zeroed (memset#1)
    float*  den  = (float*)(base + o);  o += (size_t)NN * 4;        // zeroed (memset#1)
    float*  sums = (float*)(base + o);  o += C3 * 4;                // zeroed (memset#1)
    float*  sumsq= (float*)(base + o);  o += C3 * 4;                // zeroed (memset#1)
    float*  scale= (float*)(base + o);  o += C3 * 4;
    float*  shift= (float*)(base + o);  o += C3 * 4;
    float*  w_as = (float*)(base + o);  o += 128 * 4;
    float*  w_ad = (float*)(base + o);  o += 128 * 4;
    ushort* btg_h = (ushort*)(base + o); o += 128 * 128 * 2;
    ushort* btg_l = (ushort*)(base + o); o += 128 * 128 * 2;
    ushort* btc_h = (ushort*)(base + o); o += 128 * 128 * 2;
    ushort* btc_l = (ushort*)(base + o); o += 128 * 128 * 2;
    ushort* btr_h = (ushort*)(base + o); o += 128 * 128 * 2;
    ushort* btr_l = (ushort*)(base + o); o += 128 * 128 * 2;
    ushort* btl_h = (ushort*)(base + o); o += 128 * 128 * 2;
    ushort* btl_l = (ushort*)(base + o); o += 128 * 128 * 2;
    ushort* bt1_h = (ushort*)(base + o); o += 256 * 384 * 2;
    ushort* bt1_l = (ushort*)(base + o); o += 256 * 384 * 2;
    ushort* bt2_h = (ushort*)(base + o); o += 128 * 256 * 2;
    ushort* bt2_l = (ushort*)(base + o); o += 128 * 256 * 2;
    ushort* bt3_h = (ushort*)(base + o); o += 48 * 128 * 2;
    ushort* bt3_l = (ushort*)(base + o); o += 48 * 128 * 2;
    // X-region overlays (temporally disjoint):
    ushort* xhi = (ushort*)X;                               // split_x -> xwr GEMM
    ushort* xlo = (ushort*)(X + (size_t)NN * 128 * 2);
    float*  as_ = (float*)X;                                // att_dots -> edge1
    float*  ad_ = (float*)(X + 200000);
    int*    degA = (int*)(X + 400000);                      // edge1 -> node_fin (memset#2)
    int*    cursor = (int*)(X + 600000);                    // scan -> csr_fill
    ushort* tsh = (ushort*)X;                               // gather -> sage GEMM
    ushort* tsl = (ushort*)(X + (size_t)NN * 128 * 2);
    // post-gather reuses:
    ushort* a1h = tgh;   // NN*256 ushort == tgh+tgl region
    ushort* a1l = tch;   // NN*256 ushort == tch+tcl region
    ushort* a2h = (ushort*)xwr;
    ushort* a2l = (ushort*)xwr + (size_t)NN * 128;

    // ---- memset #1: mu_, den, sums, sumsq (contiguous) ----
    hipMemsetAsync(mu_, 0, (size_t)2 * NN * 4 + 2 * C3 * 4, stream);

    // ---- splits + attention weight fold ----
    k_split_x<<<(NN * FIN / 2 + 255) / 256, 256, 0, stream>>>(x, xhi, xlo);
    k_splitw<<<dim3(1, 128), 256, 0, stream>>>(W_gat,    128, 128, btg_h, btg_l);
    k_splitw<<<dim3(1, 128), 256, 0, stream>>>(W_gcn,    128, 128, btc_h, btc_l);
    k_splitw<<<dim3(1, 128), 256, 0, stream>>>(W_sage_r, 128, 128, btr_h, btr_l);
    k_splitw<<<dim3(1, 128), 256, 0, stream>>>(W_sage_l, 128, 128, btl_h, btl_l);
    k_splitw<<<dim3(2, 256), 256, 0, stream>>>(W1,       384, 256, bt1_h, bt1_l);
    k_splitw<<<dim3(1, 128), 256, 0, stream>>>(W2,       256, 128, bt2_h, bt2_l);
    k_splitw<<<dim3(1,  48), 256, 0, stream>>>(W3,       128,  40, bt3_h, bt3_l);
    k_att_w<<<1, 128, 0, stream>>>(W_gat, att_src, att_dst, w_as, w_ad);

    // ---- xwr = x @ W_sage_r (fp32 out; consumed as addC by SAGE GEMM) ----
    dim3 gg((NN + 127) / 128, 1);
    k_mfma_gemm<8><<<gg, 256, 0, stream>>>(xhi, xlo, btr_h, btr_l, NN, 128, 0,
        nullptr, nullptr, nullptr, 0, xwr, 128, nullptr, nullptr, 0, 128);

    // ---- memset #2: degA (X region free of xhi/xlo now) ----
    hipMemsetAsync(degA, 0, (size_t)NN * 4, stream);

    // ---- attention logits directly from x ----
    k_att_dots<<<(NN + 3) / 4, 256, 0, stream>>>(x, w_as, w_ad, as_, ad_);

    // ---- edge passes + CSR build ----
    int eb = (EE + NN + 255) / 256;
    k_edge1<<<eb, 256, 0, stream>>>(e_src, e_dst, as_, ad_, ebuf, mu_, degA);
    k_scan<<<1, SCAN_T, 0, stream>>>(degA, offs, cursor);
    k_csr_fill<<<eb, 256, 0, stream>>>(e_dst, cursor, eids);
    k_edge2<<<eb, 256, 0, stream>>>(e_dst, ebuf, mu_, den);
    k_node_fin<<<(NN + 255) / 256, 256, 0, stream>>>(degA, den, dinv, rcnt);

    // ---- gather: weighted x-sums (t_gat, t_gcn, t_sage) ----
    k_gather<<<(NN + 3) / 4, 256, 0, stream>>>(
        e_src, eids, offs, ebuf, den, dinv, x,
        tgh, tgl, tch, tcl, tsh, tsl);

    // ---- producer GEMMs into hcat ----
    k_mfma_gemm<8><<<gg, 256, 0, stream>>>(tgh, tgl, btg_h, btg_l, NN, 128, 4,
        b_gat, nullptr, nullptr, 0, nullptr, 0, hch, hcl, C3, 128);
    k_mfma_gemm<8><<<gg, 256, 0, stream>>>(tch, tcl, btc_h, btc_l, NN, 128, 4,
        b_gcn, nullptr, nullptr, 0, nullptr, 0, hch + 128, hcl + 128, C3, 128);
    k_mfma_gemm<8><<<gg, 256, 0, stream>>>(tsh, tsl, btl_h, btl_l, NN, 128, 1,
        b_sage_l, rcnt, xwr, 128, nullptr, 0, hch + 256, hcl + 256, C3, 128);

    // ---- BatchNorm stats + fold; in-place BN+relu ----
    k_bn_stats<<<256, 128, 0, stream>>>(hch, hcl, sums, sumsq);
    k_bn_final<<<1, C3, 0, stream>>>(sums, sumsq, gamma, beta, scale, shift);
    k_bnrelu<<<NN, 192, 0, stream>>>(hch, hcl, scale, shift);

    // ---- MLP ----
    dim3 g1((NN + 127) / 128, 2);
    k_mfma_gemm<8><<<g1, 256, 0, stream>>>(hch, hcl, bt1_h, bt1_l, NN, 384, 2,
        b1, nullptr, nullptr, 0, nullptr, 0, a1h, a1l, 256, 256);
    k_mfma_gemm<8><<<gg, 256, 0, stream>>>(a1h, a1l, bt2_h, bt2_l, NN, 256, 2,
        b2, nullptr, nullptr, 0, nullptr, 0, a2h, a2l, 128, 128);
    k_mfma_gemm<3><<<gg, 256, 0, stream>>>(a2h, a2l, bt3_h, bt3_l, NN, 128, 3,
        b3, nullptr, nullptr, 0, (float*)d_out, NOUT, nullptr, nullptr, 0, NOUT);
}

// Round 5
// 831.583 us; speedup vs baseline: 3.8838x; 1.1726x over previous
//
#include <hip/hip_runtime.h>
#include <cstdint>
#include <cstddef>

#define NN   50000
#define FIN  128
#define HD   128
#define EE   800000
#define C3   384   // 3*H
#define NOUT 40

typedef __attribute__((ext_vector_type(8))) short s8v;   // 8 x bf16 (4 VGPR)
typedef __attribute__((ext_vector_type(4))) float f4v;   // MFMA acc

typedef const __attribute__((address_space(1))) unsigned int* guintp;
typedef __attribute__((address_space(3))) unsigned int* luintp;

// async global->LDS 16B per lane: LDS dst = base + lane*16 (wave-uniform base)
static __device__ __forceinline__ void async_copy16(const void* g, void* l) {
    __builtin_amdgcn_global_load_lds((guintp)g, (luintp)l, 16, 0, 0);
}

// ---------- bf16 helpers ----------
static __device__ __forceinline__ float b2f(ushort u) {
    return __uint_as_float((unsigned)u << 16);
}
static __device__ __forceinline__ ushort f2b(float v) {
    unsigned u = __float_as_uint(v);
    unsigned r = u + 0x7fffu + ((u >> 16) & 1u);
    return (ushort)(r >> 16);
}
static __device__ __forceinline__ void bsplit(float v, ushort& h, ushort& l) {
    h = f2b(v);
    float hf = b2f(h);
    l = f2b(v - hf);
}

// ---------- merged: split x -> bf16 hi/lo AND attention dots ----------
__global__ __launch_bounds__(256) void k_split_x_att(
    const float* __restrict__ x,
    const float* __restrict__ w_as, const float* __restrict__ w_ad,
    ushort* __restrict__ xh, ushort* __restrict__ xl,
    float* __restrict__ a_s, float* __restrict__ a_d)
{
    int node = blockIdx.x * 4 + (threadIdx.x >> 6);
    if (node >= NN) return;
    int lane = threadIdx.x & 63;
    size_t o = (size_t)node * 128 + lane * 2;
    float2 v  = *(const float2*)(x + o);
    ushort hx, lx, hy, ly;
    bsplit(v.x, hx, lx); bsplit(v.y, hy, ly);
    { ushort2 u; u.x = hx; u.y = hy; *(ushort2*)(xh + o) = u; }
    { ushort2 u; u.x = lx; u.y = ly; *(ushort2*)(xl + o) = u; }
    float2 w1 = *(const float2*)(w_as + lane * 2);
    float2 w2 = *(const float2*)(w_ad + lane * 2);
    float s1 = v.x * w1.x + v.y * w1.y;
    float s2 = v.x * w2.x + v.y * w2.y;
    #pragma unroll
    for (int off = 32; off; off >>= 1) {
        s1 += __shfl_down(s1, off);
        s2 += __shfl_down(s2, off);
    }
    if (lane == 0) { a_s[node] = s1; a_d[node] = s2; }
}

// ---------- all weight splits+transposes in one launch ----------
// rows: [0,128) gat | [128,256) gcn | [256,384) sage concat [W_l;W_r] K=256
//       [384,640) W1 K=384 | [640,768) W2 K=256 | [768,816) W3 K=128 (pad 40->48)
__global__ void k_splitw_all(
    const float* __restrict__ Wg, const float* __restrict__ Wc,
    const float* __restrict__ Wl, const float* __restrict__ Wr,
    const float* __restrict__ W1, const float* __restrict__ W2,
    const float* __restrict__ W3,
    ushort* __restrict__ btg_h, ushort* __restrict__ btg_l,
    ushort* __restrict__ btc_h, ushort* __restrict__ btc_l,
    ushort* __restrict__ btsg_h, ushort* __restrict__ btsg_l,
    ushort* __restrict__ bt1_h, ushort* __restrict__ bt1_l,
    ushort* __restrict__ bt2_h, ushort* __restrict__ bt2_l,
    ushort* __restrict__ bt3_h, ushort* __restrict__ bt3_l)
{
    int ry = blockIdx.x;
    int t = threadIdx.x;
    const float* W = nullptr; ushort* dh; ushort* dl; int K, Nw, n;
    bool sage = false;
    if (ry < 128)      { n = ry;       K = 128; Nw = 128; W = Wg; dh = btg_h; dl = btg_l; }
    else if (ry < 256) { n = ry - 128; K = 128; Nw = 128; W = Wc; dh = btc_h; dl = btc_l; }
    else if (ry < 384) { n = ry - 256; K = 256; Nw = 128; sage = true; dh = btsg_h; dl = btsg_l; }
    else if (ry < 640) { n = ry - 384; K = 384; Nw = 256; W = W1; dh = bt1_h; dl = bt1_l; }
    else if (ry < 768) { n = ry - 640; K = 256; Nw = 128; W = W2; dh = bt2_h; dl = bt2_l; }
    else               { n = ry - 768; K = 128; Nw = 40;  W = W3; dh = bt3_h; dl = bt3_l; }
    for (int k = t; k < K; k += 256) {
        float v;
        if (sage) v = (k < 128) ? Wl[(size_t)k * 128 + n] : Wr[(size_t)(k - 128) * 128 + n];
        else      v = (n < Nw) ? W[(size_t)k * Nw + n] : 0.f;
        ushort h, l; bsplit(v, h, l);
        dh[(size_t)n * K + k] = h;
        dl[(size_t)n * K + k] = l;
    }
}

// ---------- fold attention vectors: w_as = W_gat @ att_src ----------
__global__ void k_att_w(const float* __restrict__ Wg,
                        const float* __restrict__ asv, const float* __restrict__ adv,
                        float* __restrict__ w_as, float* __restrict__ w_ad) {
    int f = threadIdx.x;  // 128
    float s1 = 0.f, s2 = 0.f;
    for (int j = 0; j < 128; ++j) {
        float w = Wg[f * 128 + j];
        s1 += w * asv[j];
        s2 += w * adv[j];
    }
    w_as[f] = s1; w_ad[f] = s2;
}

// ---------- MFMA split-bf16 GEMM, LDS-staged B, A register prefetch ----------
// wave = 32 rows x NT*16 cols; block = 4 waves = 128 rows x NT*16 cols.
// A = [A1 | A2] split by K1 (two-pointer concat); B = Bt[n][KTOT] hi/lo.
// mode 0: relu(acc+bias) -> split store   (MLP1/2)
// mode 1: acc+bias -> split store, + column stats atomics (producers)
// mode 2: acc+bias -> fp32 store, cols < colmax (MLP3)
template<int NT, int NCH>
__global__ __launch_bounds__(256) void k_gemm2(
    const ushort* __restrict__ A1h, const ushort* __restrict__ A1l, int K1,
    const ushort* __restrict__ A2h, const ushort* __restrict__ A2l, int K2,
    const ushort* __restrict__ Bth, const ushort* __restrict__ Btl,
    int M, int mode,
    const float* __restrict__ bias,
    float* __restrict__ sums, float* __restrict__ sumsq,
    float* __restrict__ Cf, int ldc,
    ushort* __restrict__ Chi, ushort* __restrict__ Clo, int ldch,
    int colmax)
{
    constexpr int COLS = NT * 16;
    constexpr int OPU  = 16 * COLS;    // 16B-units per operand per chunk
    constexpr int ISS  = COLS / 8;     // global_load_lds issues per wave per chunk
    constexpr int KTOT = NCH * 128;
    constexpr int NK   = NCH * 4;

    __shared__ __align__(16) ushort Bs[2 * OPU * 8];

    const int lane = threadIdx.x & 63;
    const int wave = threadIdx.x >> 6;
    const int quad = lane >> 4;
    const int ln15 = lane & 15;
    const int row0 = (blockIdx.x * 4 + wave) * 32;
    const int col0 = blockIdx.y * COLS;

    int r0 = row0 + ln15;        if (r0 > M - 1) r0 = M - 1;
    int r1 = row0 + 16 + ln15;   if (r1 > M - 1) r1 = M - 1;

    auto stage = [&](int c) {
        #pragma unroll
        for (int i = 0; i < ISS; ++i) {
            int u0 = (wave * ISS + i) * 64;
            int u  = u0 + lane;
            int op = u / OPU;                    // uniform per issue (OPU % 64 == 0)
            int rem = u - op * OPU;
            int kq  = rem / COLS;
            int col = rem - kq * COLS;
            int kk  = c * 128 + (kq >> 2) * 32 + (kq & 3) * 8;
            const ushort* spt = op ? Btl : Bth;
            const ushort* gp = spt + (size_t)(col0 + col) * KTOT + kk;
            async_copy16(gp, (char*)Bs + (size_t)u0 * 16);
        }
    };
    auto loadA = [&](int kk, s8v& h0, s8v& l0, s8v& h1, s8v& l1) {
        const ushort* ah; const ushort* al; size_t o0, o1;
        if (kk < K1) { ah = A1h; al = A1l; o0 = (size_t)r0 * K1 + kk; o1 = (size_t)r1 * K1 + kk; }
        else { ah = A2h; al = A2l; int k2 = kk - K1; o0 = (size_t)r0 * K2 + k2; o1 = (size_t)r1 * K2 + k2; }
        int q8 = quad * 8;
        h0 = *(const s8v*)(ah + o0 + q8);
        l0 = *(const s8v*)(al + o0 + q8);
        h1 = *(const s8v*)(ah + o1 + q8);
        l1 = *(const s8v*)(al + o1 + q8);
    };

    f4v acc[2][NT] = {};
    s8v cah0, cal0, cah1, cal1, nah0, nal0, nah1, nal1;

    stage(0);
    loadA(0, cah0, cal0, cah1, cal1);
    __syncthreads();

    #pragma unroll
    for (int c = 0; c < NCH; ++c) {
        #pragma unroll
        for (int j = 0; j < 4; ++j) {
            int kj = c * 4 + j;
            int nk = (kj + 1 < NK) ? (kj + 1) * 32 : 0;   // last iter: dummy reload
            loadA(nk, nah0, nal0, nah1, nal1);
            #pragma unroll
            for (int t = 0; t < NT; ++t) {
                int ub = (j * 4 + quad) * COLS + t * 16 + ln15;
                s8v bh = *(const s8v*)(Bs + (size_t)ub * 8);
                s8v bl = *(const s8v*)(Bs + (size_t)(OPU + ub) * 8);
                acc[0][t] = __builtin_amdgcn_mfma_f32_16x16x32_bf16(cah0, bh, acc[0][t], 0, 0, 0);
                acc[1][t] = __builtin_amdgcn_mfma_f32_16x16x32_bf16(cah1, bh, acc[1][t], 0, 0, 0);
                acc[0][t] = __builtin_amdgcn_mfma_f32_16x16x32_bf16(cah0, bl, acc[0][t], 0, 0, 0);
                acc[1][t] = __builtin_amdgcn_mfma_f32_16x16x32_bf16(cah1, bl, acc[1][t], 0, 0, 0);
                acc[0][t] = __builtin_amdgcn_mfma_f32_16x16x32_bf16(cal0, bh, acc[0][t], 0, 0, 0);
                acc[1][t] = __builtin_amdgcn_mfma_f32_16x16x32_bf16(cal1, bh, acc[1][t], 0, 0, 0);
            }
            cah0 = nah0; cal0 = nal0; cah1 = nah1; cal1 = nal1;
        }
        if (c + 1 < NCH) {
            __syncthreads();          // all waves done reading Bs
            stage(c + 1);
            __syncthreads();
        }
    }

    const bool dostats = (sums != nullptr);
    #pragma unroll
    for (int t = 0; t < NT; ++t) {
        int cc = col0 + t * 16 + ln15;
        float sp = 0.f, qp = 0.f;
        #pragma unroll
        for (int mt = 0; mt < 2; ++mt) {
            #pragma unroll
            for (int r = 0; r < 4; ++r) {
                int rr = row0 + mt * 16 + quad * 4 + r;
                bool ok = (rr < M);
                float v = acc[mt][t][r];
                if (mode == 0) {
                    v += bias[cc];
                    v = v > 0.f ? v : 0.f;
                    if (ok) {
                        ushort h, l; bsplit(v, h, l);
                        Chi[(size_t)rr * ldch + cc] = h;
                        Clo[(size_t)rr * ldch + cc] = l;
                    }
                } else if (mode == 1) {
                    v += bias[cc];
                    if (ok) {
                        ushort h, l; bsplit(v, h, l);
                        Chi[(size_t)rr * ldch + cc] = h;
                        Clo[(size_t)rr * ldch + cc] = l;
                        sp += v; qp += v * v;
                    }
                } else {
                    if (ok && cc < colmax) Cf[(size_t)rr * ldc + cc] = v + bias[cc];
                }
            }
        }
        if (dostats) {
            sp += __shfl_xor(sp, 16); sp += __shfl_xor(sp, 32);
            qp += __shfl_xor(qp, 16); qp += __shfl_xor(qp, 32);
            if (quad == 0) {
                unsafeAtomicAdd(&sums[cc], sp);
                unsafeAtomicAdd(&sumsq[cc], qp);
            }
        }
    }
}

// ---------- edge pass: dst-degree histogram (real edges only) ----------
__global__ void k_edge1(const int* __restrict__ dst, int* __restrict__ degA)
{
    int gid = blockIdx.x * blockDim.x + threadIdx.x;
    if (gid >= EE) return;
    atomicAdd(&degA[dst[gid]], 1);
}

// ---------- single-block exclusive scan (deg+1 per node, self-loop slot) ----------
#define SCAN_T 256
__global__ __launch_bounds__(SCAN_T) void k_scan(
    const int* __restrict__ degA, int* __restrict__ offs,
    int* __restrict__ cursor)
{
    __shared__ int part[SCAN_T];
    int t = threadIdx.x;
    const int chunk = (NN + SCAN_T - 1) / SCAN_T;
    int b = t * chunk;
    int e = b + chunk; if (e > NN) e = NN;
    int sum = 0;
    for (int i = b; i < e; ++i) sum += degA[i] + 1;
    part[t] = sum;
    __syncthreads();
    for (int off = 1; off < SCAN_T; off <<= 1) {
        int v = (t >= off) ? part[t - off] : 0;
        __syncthreads();
        part[t] += v;
        __syncthreads();
    }
    int run = (t > 0) ? part[t - 1] : 0;
    for (int i = b; i < e; ++i) {
        offs[i] = run; cursor[i] = run;
        run += degA[i] + 1;
    }
    if (t == SCAN_T - 1) offs[NN] = run;
}

__global__ void k_csr_fill(const int* __restrict__ dst, int* __restrict__ cursor,
                           int* __restrict__ eids)
{
    int gid = blockIdx.x * blockDim.x + threadIdx.x;
    if (gid >= EE + NN) return;
    int d = (gid < EE) ? dst[gid] : (gid - EE);
    int slot = atomicAdd(&cursor[d], 1);
    eids[slot] = gid;
}

__global__ void k_node_fin(const int* __restrict__ degA, float* __restrict__ dinv)
{
    int i = blockIdx.x * blockDim.x + threadIdx.x;
    if (i >= NN) return;
    dinv[i] = rsqrtf((float)(degA[i] + 1));   // GCN degree includes self-loop
}

// ---------- CSR gather with in-wave softmax (max + denom) ----------
// outputs: tg = sum alpha*x[s]; tc = sum norm*x[s]; ts = rcnt * sum_{nbr} x[s]
__global__ __launch_bounds__(256) void k_gather(
    const int* __restrict__ src,
    const int* __restrict__ eids, const int* __restrict__ offs,
    const float* __restrict__ a_s, const float* __restrict__ a_d,
    const float* __restrict__ dinv,
    const float* __restrict__ x,
    ushort* __restrict__ tgh, ushort* __restrict__ tgl,
    ushort* __restrict__ tch, ushort* __restrict__ tcl,
    ushort* __restrict__ tsh, ushort* __restrict__ tsl)
{
    int d = blockIdx.x * 4 + (threadIdx.x >> 6);
    if (d >= NN) return;
    int lane = threadIdx.x & 63;
    int beg = offs[d], end = offs[d + 1];
    float ad = a_d[d], dd = dinv[d];

    // chunk-0 cache (covers deg<=64, i.e. almost all nodes)
    int idx0 = beg + lane;
    bool v0 = idx0 < end;
    int s0 = d; float e0 = 0.f;
    if (v0) {
        int eid = eids[idx0];
        s0 = (eid < EE) ? src[eid] : d;
        float e = a_s[s0] + ad;
        e0 = (e > 0.f) ? e : 0.2f * e;
    }
    // pass A: segment max
    float m = v0 ? e0 : -3.0e38f;
    for (int base = beg + 64; base < end; base += 64) {
        int idx = base + lane;
        if (idx < end) {
            int eid = eids[idx];
            int s = (eid < EE) ? src[eid] : d;
            float e = a_s[s] + ad;
            e = (e > 0.f) ? e : 0.2f * e;
            m = fmaxf(m, e);
        }
    }
    #pragma unroll
    for (int off = 1; off < 64; off <<= 1) m = fmaxf(m, __shfl_xor(m, off));
    // pass B: denom
    float den = v0 ? expf(e0 - m) : 0.f;
    for (int base = beg + 64; base < end; base += 64) {
        int idx = base + lane;
        if (idx < end) {
            int eid = eids[idx];
            int s = (eid < EE) ? src[eid] : d;
            float e = a_s[s] + ad;
            e = (e > 0.f) ? e : 0.2f * e;
            den += expf(e - m);
        }
    }
    #pragma unroll
    for (int off = 1; off < 64; off <<= 1) den += __shfl_xor(den, off);
    float rden = 1.f / den;

    // pass C: weighted accumulation of x rows
    float2 tg = {0.f, 0.f}, tc = {0.f, 0.f}, ts = {0.f, 0.f};
    int c = lane * 2;
    {
        float wg = v0 ? expf(e0 - m) * rden : 0.f;
        float wc = v0 ? dinv[s0] * dd : 0.f;
        int cnt = end - beg; if (cnt > 64) cnt = 64;
        for (int j = 0; j < cnt; ++j) {
            int   sj  = __shfl(s0, j);
            float wgj = __shfl(wg, j);
            float wcj = __shfl(wc, j);
            const float2 xv = *(const float2*)(x + (size_t)sj * 128 + c);
            tg.x += wgj * xv.x; tg.y += wgj * xv.y;
            tc.x += wcj * xv.x; tc.y += wcj * xv.y;
            ts.x += xv.x;       ts.y += xv.y;
        }
    }
    for (int base = beg + 64; base < end; base += 64) {
        int idx = base + lane;
        int s = d; float wg = 0.f, wc = 0.f;
        if (idx < end) {
            int eid = eids[idx];
            s = (eid < EE) ? src[eid] : d;
            float e = a_s[s] + ad;
            e = (e > 0.f) ? e : 0.2f * e;
            wg = expf(e - m) * rden;
            wc = dinv[s] * dd;
        }
        int cnt = end - base; if (cnt > 64) cnt = 64;
        for (int j = 0; j < cnt; ++j) {
            int   sj  = __shfl(s, j);
            float wgj = __shfl(wg, j);
            float wcj = __shfl(wc, j);
            const float2 xv = *(const float2*)(x + (size_t)sj * 128 + c);
            tg.x += wgj * xv.x; tg.y += wgj * xv.y;
            tc.x += wcj * xv.x; tc.y += wcj * xv.y;
            ts.x += xv.x;       ts.y += xv.y;
        }
    }
    // SAGE: drop self-loop, apply 1/max(cnt,1)
    const float2 xd = *(const float2*)(x + (size_t)d * 128 + c);
    ts.x -= xd.x; ts.y -= xd.y;
    int cs = (end - beg) - 1;
    float rc = 1.f / (float)(cs > 1 ? cs : 1);
    ts.x *= rc; ts.y *= rc;

    size_t row = (size_t)d * 128 + c;
    ushort h0, l0, h1, l1;
    bsplit(tg.x, h0, l0); bsplit(tg.y, h1, l1);
    { ushort2 u; u.x = h0; u.y = h1; *(ushort2*)(tgh + row) = u; }
    { ushort2 u; u.x = l0; u.y = l1; *(ushort2*)(tgl + row) = u; }
    bsplit(tc.x, h0, l0); bsplit(tc.y, h1, l1);
    { ushort2 u; u.x = h0; u.y = h1; *(ushort2*)(tch + row) = u; }
    { ushort2 u; u.x = l0; u.y = l1; *(ushort2*)(tcl + row) = u; }
    bsplit(ts.x, h0, l0); bsplit(ts.y, h1, l1);
    { ushort2 u; u.x = h0; u.y = h1; *(ushort2*)(tsh + row) = u; }
    { ushort2 u; u.x = l0; u.y = l1; *(ushort2*)(tsl + row) = u; }
}

__global__ void k_bn_final(const float* __restrict__ sums, const float* __restrict__ sumsq,
                           const float* __restrict__ gamma, const float* __restrict__ beta,
                           float* __restrict__ scale, float* __restrict__ shift)
{
    int j = threadIdx.x;
    if (j >= C3) return;
    const float rn = 1.f / (float)NN;
    float mu  = sums[j] * rn;
    float var = sumsq[j] * rn - mu * mu;
    float sc  = gamma[j] * rsqrtf(var + 1e-5f);
    scale[j] = sc;
    shift[j] = beta[j] - mu * sc;
}

// ---------- in-place BN+relu of split hcat (flat over NN*192 pairs) ----------
__global__ __launch_bounds__(256) void k_bnrelu(
    ushort* __restrict__ hch, ushort* __restrict__ hcl,
    const float* __restrict__ scale, const float* __restrict__ shift)
{
    int p = blockIdx.x * blockDim.x + threadIdx.x;
    if (p >= NN * 192) return;
    int cpair = p % 192;
    int cidx = cpair * 2;
    size_t o = (size_t)p * 2;
    ushort2 h = *(ushort2*)(hch + o);
    ushort2 l = *(ushort2*)(hcl + o);
    float v0 = b2f(h.x) + b2f(l.x);
    float v1 = b2f(h.y) + b2f(l.y);
    v0 = v0 * scale[cidx] + shift[cidx];         v0 = v0 > 0.f ? v0 : 0.f;
    v1 = v1 * scale[cidx + 1] + shift[cidx + 1]; v1 = v1 > 0.f ? v1 : 0.f;
    ushort h0, l0, h1, l1;
    bsplit(v0, h0, l0); bsplit(v1, h1, l1);
    { ushort2 u; u.x = h0; u.y = h1; *(ushort2*)(hch + o) = u; }
    { ushort2 u; u.x = l0; u.y = l1; *(ushort2*)(hcl + o) = u; }
}

extern "C" void kernel_launch(void* const* d_in, const int* in_sizes, int n_in,
                              void* d_out, int out_size, void* d_ws, size_t ws_size,
                              hipStream_t stream) {
    const float* x        = (const float*)d_in[0];
    const int*   ei       = (const int*)d_in[1];
    const float* W_gat    = (const float*)d_in[2];
    const float* att_src  = (const float*)d_in[3];
    const float* att_dst  = (const float*)d_in[4];
    const float* b_gat    = (const float*)d_in[5];
    const float* W_gcn    = (const float*)d_in[6];
    const float* b_gcn    = (const float*)d_in[7];
    const float* W_sage_l = (const float*)d_in[8];
    const float* b_sage_l = (const float*)d_in[9];
    const float* W_sage_r = (const float*)d_in[10];
    const float* W1       = (const float*)d_in[11];
    const float* b1       = (const float*)d_in[12];
    const float* W2       = (const float*)d_in[13];
    const float* b2       = (const float*)d_in[14];
    const float* W3       = (const float*)d_in[15];
    const float* b3       = (const float*)d_in[16];
    const float* gamma    = (const float*)d_in[17];
    const float* beta     = (const float*)d_in[18];

    const int* e_src = ei;
    const int* e_dst = ei + EE;

    // ---- workspace layout (all offsets 16B-aligned) ----
    char* base = (char*)d_ws;
    size_t o = 0;
    ushort* hch  = (ushort*)(base + o); o += (size_t)NN * C3 * 2;
    ushort* hcl  = (ushort*)(base + o); o += (size_t)NN * C3 * 2;
    ushort* tgh  = (ushort*)(base + o); o += (size_t)NN * 128 * 2;   // a1h overlay (spans tgh+tgl)
    ushort* tgl  = (ushort*)(base + o); o += (size_t)NN * 128 * 2;
    ushort* tch  = (ushort*)(base + o); o += (size_t)NN * 128 * 2;   // a1l overlay (spans tch+tcl)
    ushort* tcl  = (ushort*)(base + o); o += (size_t)NN * 128 * 2;
    ushort* tsh  = (ushort*)(base + o); o += (size_t)NN * 128 * 2;   // a2h overlay
    ushort* tsl  = (ushort*)(base + o); o += (size_t)NN * 128 * 2;   // a2l overlay
    ushort* xhi  = (ushort*)(base + o); o += (size_t)NN * 128 * 2;
    ushort* xlo  = (ushort*)(base + o); o += (size_t)NN * 128 * 2;
    int*    eids = (int*)(base + o);    o += (size_t)(EE + NN) * 4;
    int*    offs = (int*)(base + o);    o += (size_t)(NN + 16) * 4;
    int*    cursor=(int*)(base + o);    o += (size_t)NN * 4;
    float*  as_  = (float*)(base + o);  o += (size_t)NN * 4;
    float*  ad_  = (float*)(base + o);  o += (size_t)NN * 4;
    float*  dinv = (float*)(base + o);  o += (size_t)NN * 4;
    // --- zero-init region: degA, sums, sumsq (contiguous) ---
    int*    degA = (int*)(base + o);    o += (size_t)NN * 4;
    float*  sums = (float*)(base + o);  o += C3 * 4;
    float*  sumsq= (float*)(base + o);  o += C3 * 4;
    // --- end zero region ---
    float*  scale= (float*)(base + o);  o += C3 * 4;
    float*  shift= (float*)(base + o);  o += C3 * 4;
    float*  w_as = (float*)(base + o);  o += 128 * 4;
    float*  w_ad = (float*)(base + o);  o += 128 * 4;
    ushort* btg_h = (ushort*)(base + o); o += 128 * 128 * 2;
    ushort* btg_l = (ushort*)(base + o); o += 128 * 128 * 2;
    ushort* btc_h = (ushort*)(base + o); o += 128 * 128 * 2;
    ushort* btc_l = (ushort*)(base + o); o += 128 * 128 * 2;
    ushort* btsg_h= (ushort*)(base + o); o += 128 * 256 * 2;
    ushort* btsg_l= (ushort*)(base + o); o += 128 * 256 * 2;
    ushort* bt1_h = (ushort*)(base + o); o += 256 * 384 * 2;
    ushort* bt1_l = (ushort*)(base + o); o += 256 * 384 * 2;
    ushort* bt2_h = (ushort*)(base + o); o += 128 * 256 * 2;
    ushort* bt2_l = (ushort*)(base + o); o += 128 * 256 * 2;
    ushort* bt3_h = (ushort*)(base + o); o += 48 * 128 * 2;
    ushort* bt3_l = (ushort*)(base + o); o += 48 * 128 * 2;
    // overlays (temporally disjoint with t*/x buffers)
    ushort* a1h = tgh;                       // NN*256 ushorts
    ushort* a1l = tch;                       // NN*256 ushorts
    ushort* a2h = tsh;                       // NN*128
    ushort* a2l = tsl;                       // NN*128

    hipMemsetAsync(degA, 0, (size_t)NN * 4 + 2 * C3 * 4, stream);

    // ---- weight prep ----
    k_att_w<<<1, 128, 0, stream>>>(W_gat, att_src, att_dst, w_as, w_ad);
    k_splitw_all<<<816, 256, 0, stream>>>(W_gat, W_gcn, W_sage_l, W_sage_r, W1, W2, W3,
        btg_h, btg_l, btc_h, btc_l, btsg_h, btsg_l, bt1_h, bt1_l, bt2_h, bt2_l, bt3_h, bt3_l);
    k_split_x_att<<<(NN + 3) / 4, 256, 0, stream>>>(x, w_as, w_ad, xhi, xlo, as_, ad_);

    // ---- CSR build ----
    k_edge1<<<(EE + 255) / 256, 256, 0, stream>>>(e_dst, degA);
    k_scan<<<1, SCAN_T, 0, stream>>>(degA, offs, cursor);
    k_csr_fill<<<(EE + NN + 255) / 256, 256, 0, stream>>>(e_dst, cursor, eids);
    k_node_fin<<<(NN + 255) / 256, 256, 0, stream>>>(degA, dinv);

    // ---- gather: softmax in-wave + weighted x sums ----
    k_gather<<<(NN + 3) / 4, 256, 0, stream>>>(
        e_src, eids, offs, as_, ad_, dinv, x, tgh, tgl, tch, tcl, tsh, tsl);

    // ---- producers (with fused BN stats) ----
    dim3 gg((NN + 127) / 128, 1);
    k_gemm2<8, 1><<<gg, 256, 0, stream>>>(tgh, tgl, 128, tgh, tgl, 128,
        btg_h, btg_l, NN, 1, b_gat, sums, sumsq,
        nullptr, 0, hch, hcl, C3, 128);
    k_gemm2<8, 1><<<gg, 256, 0, stream>>>(tch, tcl, 128, tch, tcl, 128,
        btc_h, btc_l, NN, 1, b_gcn, sums + 128, sumsq + 128,
        nullptr, 0, hch + 128, hcl + 128, C3, 128);
    k_gemm2<8, 2><<<gg, 256, 0, stream>>>(tsh, tsl, 128, xhi, xlo, 128,
        btsg_h, btsg_l, NN, 1, b_sage_l, sums + 256, sumsq + 256,
        nullptr, 0, hch + 256, hcl + 256, C3, 128);

    // ---- BN fold + in-place transform ----
    k_bn_final<<<1, C3, 0, stream>>>(sums, sumsq, gamma, beta, scale, shift);
    k_bnrelu<<<(NN * 192 + 255) / 256, 256, 0, stream>>>(hch, hcl, scale, shift);

    // ---- MLP ----
    dim3 g1((NN + 127) / 128, 2);
    k_gemm2<8, 3><<<g1, 256, 0, stream>>>(hch, hcl, 384, hch, hcl, 384,
        bt1_h, bt1_l, NN, 0, b1, nullptr, nullptr,
        nullptr, 0, a1h, a1l, 256, 256);
    k_gemm2<8, 2><<<gg, 256, 0, stream>>>(a1h, a1l, 256, a1h, a1l, 256,
        bt2_h, bt2_l, NN, 0, b2, nullptr, nullptr,
        nullptr, 0, a2h, a2l, 128, 128);
    k_gemm2<3, 1><<<gg, 256, 0, stream>>>(a2h, a2l, 128, a2h, a2l, 128,
        bt3_h, bt3_l, NN, 2, b3, nullptr, nullptr,
        (float*)d_out, NOUT, nullptr, nullptr, 0, NOUT);
}

// Round 7
// 745.408 us; speedup vs baseline: 4.3327x; 1.1156x over previous
//
#include <hip/hip_runtime.h>
#include <cstdint>
#include <cstddef>

#define NN   50000
#define FIN  128
#define HD   128
#define EE   800000
#define C3   384   // 3*H
#define NOUT 40

// hierarchical scan geometry
#define SC_ELEMS 512                       // elements per block (256 thr x 2)
#define SC_BLKS  ((NN + SC_ELEMS - 1) / SC_ELEMS)   // 98

typedef __attribute__((ext_vector_type(8))) short s8v;   // 8 x bf16 (4 VGPR)
typedef __attribute__((ext_vector_type(4))) float f4v;   // MFMA acc

typedef const __attribute__((address_space(1))) unsigned int* guintp;
typedef __attribute__((address_space(3))) unsigned int* luintp;

// async global->LDS 16B per lane: LDS dst = base + lane*16 (wave-uniform base)
static __device__ __forceinline__ void async_copy16(const void* g, void* l) {
    __builtin_amdgcn_global_load_lds((guintp)g, (luintp)l, 16, 0, 0);
}

// ---------- bf16 helpers ----------
static __device__ __forceinline__ float b2f(ushort u) {
    return __uint_as_float((unsigned)u << 16);
}
static __device__ __forceinline__ ushort f2b(float v) {
    unsigned u = __float_as_uint(v);
    unsigned r = u + 0x7fffu + ((u >> 16) & 1u);
    return (ushort)(r >> 16);
}
static __device__ __forceinline__ void bsplit(float v, ushort& h, ushort& l) {
    h = f2b(v);
    float hf = b2f(h);
    l = f2b(v - hf);
}

// ---------- merged: split x -> bf16 hi/lo AND attention dots ----------
__global__ __launch_bounds__(256) void k_split_x_att(
    const float* __restrict__ x,
    const float* __restrict__ w_as, const float* __restrict__ w_ad,
    ushort* __restrict__ xh, ushort* __restrict__ xl,
    float* __restrict__ a_s, float* __restrict__ a_d)
{
    int node = blockIdx.x * 4 + (threadIdx.x >> 6);
    if (node >= NN) return;
    int lane = threadIdx.x & 63;
    size_t o = (size_t)node * 128 + lane * 2;
    float2 v  = *(const float2*)(x + o);
    ushort hx, lx, hy, ly;
    bsplit(v.x, hx, lx); bsplit(v.y, hy, ly);
    { ushort2 u; u.x = hx; u.y = hy; *(ushort2*)(xh + o) = u; }
    { ushort2 u; u.x = lx; u.y = ly; *(ushort2*)(xl + o) = u; }
    float2 w1 = *(const float2*)(w_as + lane * 2);
    float2 w2 = *(const float2*)(w_ad + lane * 2);
    float s1 = v.x * w1.x + v.y * w1.y;
    float s2 = v.x * w2.x + v.y * w2.y;
    #pragma unroll
    for (int off = 32; off; off >>= 1) {
        s1 += __shfl_down(s1, off);
        s2 += __shfl_down(s2, off);
    }
    if (lane == 0) { a_s[node] = s1; a_d[node] = s2; }
}

// ---------- all weight splits+transposes in one launch ----------
__global__ void k_splitw_all(
    const float* __restrict__ Wg, const float* __restrict__ Wc,
    const float* __restrict__ Wl, const float* __restrict__ Wr,
    const float* __restrict__ W1, const float* __restrict__ W2,
    const float* __restrict__ W3,
    ushort* __restrict__ btg_h, ushort* __restrict__ btg_l,
    ushort* __restrict__ btc_h, ushort* __restrict__ btc_l,
    ushort* __restrict__ btsg_h, ushort* __restrict__ btsg_l,
    ushort* __restrict__ bt1_h, ushort* __restrict__ bt1_l,
    ushort* __restrict__ bt2_h, ushort* __restrict__ bt2_l,
    ushort* __restrict__ bt3_h, ushort* __restrict__ bt3_l)
{
    int ry = blockIdx.x;
    int t = threadIdx.x;
    const float* W = nullptr; ushort* dh; ushort* dl; int K, Nw, n;
    bool sage = false;
    if (ry < 128)      { n = ry;       K = 128; Nw = 128; W = Wg; dh = btg_h; dl = btg_l; }
    else if (ry < 256) { n = ry - 128; K = 128; Nw = 128; W = Wc; dh = btc_h; dl = btc_l; }
    else if (ry < 384) { n = ry - 256; K = 256; Nw = 128; sage = true; dh = btsg_h; dl = btsg_l; }
    else if (ry < 640) { n = ry - 384; K = 384; Nw = 256; W = W1; dh = bt1_h; dl = bt1_l; }
    else if (ry < 768) { n = ry - 640; K = 256; Nw = 128; W = W2; dh = bt2_h; dl = bt2_l; }
    else               { n = ry - 768; K = 128; Nw = 40;  W = W3; dh = bt3_h; dl = bt3_l; }
    for (int k = t; k < K; k += 256) {
        float v;
        if (sage) v = (k < 128) ? Wl[(size_t)k * 128 + n] : Wr[(size_t)(k - 128) * 128 + n];
        else      v = (n < Nw) ? W[(size_t)k * Nw + n] : 0.f;
        ushort h, l; bsplit(v, h, l);
        dh[(size_t)n * K + k] = h;
        dl[(size_t)n * K + k] = l;
    }
}

// ---------- fold attention vectors: w_as = W_gat @ att_src ----------
__global__ void k_att_w(const float* __restrict__ Wg,
                        const float* __restrict__ asv, const float* __restrict__ adv,
                        float* __restrict__ w_as, float* __restrict__ w_ad) {
    int f = threadIdx.x;  // 128
    float s1 = 0.f, s2 = 0.f;
    for (int j = 0; j < 128; ++j) {
        float w = Wg[f * 128 + j];
        s1 += w * asv[j];
        s2 += w * adv[j];
    }
    w_as[f] = s1; w_ad[f] = s2;
}

// ---------- MFMA split-bf16 GEMM, LDS-staged B, A register prefetch ----------
template<int NT, int NCH>
__global__ __launch_bounds__(256) void k_gemm2(
    const ushort* __restrict__ A1h, const ushort* __restrict__ A1l, int K1,
    const ushort* __restrict__ A2h, const ushort* __restrict__ A2l, int K2,
    const ushort* __restrict__ Bth, const ushort* __restrict__ Btl,
    int M, int mode,
    const float* __restrict__ bias,
    float* __restrict__ sums, float* __restrict__ sumsq,
    float* __restrict__ Cf, int ldc,
    ushort* __restrict__ Chi, ushort* __restrict__ Clo, int ldch,
    int colmax)
{
    constexpr int COLS = NT * 16;
    constexpr int OPU  = 16 * COLS;    // 16B-units per operand per chunk
    constexpr int ISS  = COLS / 8;     // global_load_lds issues per wave per chunk
    constexpr int KTOT = NCH * 128;
    constexpr int NK   = NCH * 4;

    __shared__ __align__(16) ushort Bs[2 * OPU * 8];

    const int lane = threadIdx.x & 63;
    const int wave = threadIdx.x >> 6;
    const int quad = lane >> 4;
    const int ln15 = lane & 15;
    const int row0 = (blockIdx.x * 4 + wave) * 32;
    const int col0 = blockIdx.y * COLS;

    int r0 = row0 + ln15;        if (r0 > M - 1) r0 = M - 1;
    int r1 = row0 + 16 + ln15;   if (r1 > M - 1) r1 = M - 1;

    auto stage = [&](int c) {
        #pragma unroll
        for (int i = 0; i < ISS; ++i) {
            int u0 = (wave * ISS + i) * 64;
            int u  = u0 + lane;
            int op = u / OPU;                    // uniform per issue (OPU % 64 == 0)
            int rem = u - op * OPU;
            int kq  = rem / COLS;
            int col = rem - kq * COLS;
            int kk  = c * 128 + (kq >> 2) * 32 + (kq & 3) * 8;
            const ushort* spt = op ? Btl : Bth;
            const ushort* gp = spt + (size_t)(col0 + col) * KTOT + kk;
            async_copy16(gp, (char*)Bs + (size_t)u0 * 16);
        }
    };
    auto loadA = [&](int kk, s8v& h0, s8v& l0, s8v& h1, s8v& l1) {
        const ushort* ah; const ushort* al; size_t o0, o1;
        if (kk < K1) { ah = A1h; al = A1l; o0 = (size_t)r0 * K1 + kk; o1 = (size_t)r1 * K1 + kk; }
        else { ah = A2h; al = A2l; int k2 = kk - K1; o0 = (size_t)r0 * K2 + k2; o1 = (size_t)r1 * K2 + k2; }
        int q8 = quad * 8;
        h0 = *(const s8v*)(ah + o0 + q8);
        l0 = *(const s8v*)(al + o0 + q8);
        h1 = *(const s8v*)(ah + o1 + q8);
        l1 = *(const s8v*)(al + o1 + q8);
    };

    f4v acc[2][NT] = {};
    s8v cah0, cal0, cah1, cal1, nah0, nal0, nah1, nal1;

    stage(0);
    loadA(0, cah0, cal0, cah1, cal1);
    __syncthreads();

    #pragma unroll
    for (int c = 0; c < NCH; ++c) {
        #pragma unroll
        for (int j = 0; j < 4; ++j) {
            int kj = c * 4 + j;
            int nk = (kj + 1 < NK) ? (kj + 1) * 32 : 0;   // last iter: dummy reload
            loadA(nk, nah0, nal0, nah1, nal1);
            #pragma unroll
            for (int t = 0; t < NT; ++t) {
                int ub = (j * 4 + quad) * COLS + t * 16 + ln15;
                s8v bh = *(const s8v*)(Bs + (size_t)ub * 8);
                s8v bl = *(const s8v*)(Bs + (size_t)(OPU + ub) * 8);
                acc[0][t] = __builtin_amdgcn_mfma_f32_16x16x32_bf16(cah0, bh, acc[0][t], 0, 0, 0);
                acc[1][t] = __builtin_amdgcn_mfma_f32_16x16x32_bf16(cah1, bh, acc[1][t], 0, 0, 0);
                acc[0][t] = __builtin_amdgcn_mfma_f32_16x16x32_bf16(cah0, bl, acc[0][t], 0, 0, 0);
                acc[1][t] = __builtin_amdgcn_mfma_f32_16x16x32_bf16(cah1, bl, acc[1][t], 0, 0, 0);
                acc[0][t] = __builtin_amdgcn_mfma_f32_16x16x32_bf16(cal0, bh, acc[0][t], 0, 0, 0);
                acc[1][t] = __builtin_amdgcn_mfma_f32_16x16x32_bf16(cal1, bh, acc[1][t], 0, 0, 0);
            }
            cah0 = nah0; cal0 = nal0; cah1 = nah1; cal1 = nal1;
        }
        if (c + 1 < NCH) {
            __syncthreads();          // all waves done reading Bs
            stage(c + 1);
            __syncthreads();
        }
    }

    const bool dostats = (sums != nullptr);
    #pragma unroll
    for (int t = 0; t < NT; ++t) {
        int cc = col0 + t * 16 + ln15;
        float sp = 0.f, qp = 0.f;
        #pragma unroll
        for (int mt = 0; mt < 2; ++mt) {
            #pragma unroll
            for (int r = 0; r < 4; ++r) {
                int rr = row0 + mt * 16 + quad * 4 + r;
                bool ok = (rr < M);
                float v = acc[mt][t][r];
                if (mode == 0) {
                    v += bias[cc];
                    v = v > 0.f ? v : 0.f;
                    if (ok) {
                        ushort h, l; bsplit(v, h, l);
                        Chi[(size_t)rr * ldch + cc] = h;
                        Clo[(size_t)rr * ldch + cc] = l;
                    }
                } else if (mode == 1) {
                    v += bias[cc];
                    if (ok) {
                        ushort h, l; bsplit(v, h, l);
                        Chi[(size_t)rr * ldch + cc] = h;
                        Clo[(size_t)rr * ldch + cc] = l;
                        sp += v; qp += v * v;
                    }
                } else {
                    if (ok && cc < colmax) Cf[(size_t)rr * ldc + cc] = v + bias[cc];
                }
            }
        }
        if (dostats) {
            sp += __shfl_xor(sp, 16); sp += __shfl_xor(sp, 32);
            qp += __shfl_xor(qp, 16); qp += __shfl_xor(qp, 32);
            if (quad == 0) {
                unsafeAtomicAdd(&sums[cc], sp);
                unsafeAtomicAdd(&sumsq[cc], qp);
            }
        }
    }
}

// ---------- edge pass: dst-degree histogram (real edges only) ----------
__global__ void k_edge1(const int* __restrict__ dst, int* __restrict__ degA)
{
    int gid = blockIdx.x * blockDim.x + threadIdx.x;
    if (gid >= EE) return;
    atomicAdd(&degA[dst[gid]], 1);
}

// ---------- hierarchical exclusive scan over (degA[i]+1) ----------
// phase 1: per-block totals (98 blocks x 512 elems)
__global__ __launch_bounds__(256) void k_scan_part(
    const int* __restrict__ degA, int* __restrict__ bsum)
{
    int t = threadIdx.x;
    int b0 = blockIdx.x * SC_ELEMS;
    int i0 = b0 + t * 2;
    int v0 = (i0 < NN)     ? degA[i0] + 1     : 0;
    int v1 = (i0 + 1 < NN) ? degA[i0 + 1] + 1 : 0;
    int s = v0 + v1;
    #pragma unroll
    for (int off = 32; off; off >>= 1) s += __shfl_down(s, off);
    __shared__ int ws[4];
    if ((t & 63) == 0) ws[t >> 6] = s;
    __syncthreads();
    if (t == 0) bsum[blockIdx.x] = ws[0] + ws[1] + ws[2] + ws[3];
}

// phase 2: exclusive scan of SC_BLKS partials (one small block)
__global__ __launch_bounds__(128) void k_scan_tops(
    const int* __restrict__ bsum, int* __restrict__ boffs)
{
    __shared__ int sh[128];
    int t = threadIdx.x;
    int v = (t < SC_BLKS) ? bsum[t] : 0;
    sh[t] = v;
    __syncthreads();
    for (int off = 1; off < 128; off <<= 1) {
        int u = (t >= off) ? sh[t - off] : 0;
        __syncthreads();
        sh[t] += u;
        __syncthreads();
    }
    if (t < SC_BLKS) boffs[t] = sh[t] - v;   // exclusive
    if (t == SC_BLKS - 1) boffs[SC_BLKS] = sh[t];
}

// phase 3: in-block exclusive scan + apply block offset; writes offs, cursor, dinv
// NOTE: OOB elements MUST contribute 0 (bug fixed vs R6: was d+1 -> +1 each,
// inflating offs[NN] by the padding count and corrupting node NN-1's edges).
__global__ __launch_bounds__(256) void k_scan_apply(
    const int* __restrict__ degA, const int* __restrict__ boffs,
    int* __restrict__ offs, int* __restrict__ cursor,
    float* __restrict__ dinv)
{
    __shared__ int sh[256];
    int t = threadIdx.x;
    int b0 = blockIdx.x * SC_ELEMS;
    int i0 = b0 + t * 2;
    int v0 = (i0 < NN)     ? degA[i0] + 1     : 0;
    int v1 = (i0 + 1 < NN) ? degA[i0 + 1] + 1 : 0;
    int pair = v0 + v1;
    sh[t] = pair;
    __syncthreads();
    for (int off = 1; off < 256; off <<= 1) {
        int u = (t >= off) ? sh[t - off] : 0;
        __syncthreads();
        sh[t] += u;
        __syncthreads();
    }
    int excl = sh[t] - pair + boffs[blockIdx.x];
    if (i0 < NN) {
        offs[i0] = excl; cursor[i0] = excl;
        dinv[i0] = rsqrtf((float)v0);
    }
    if (i0 + 1 < NN) {
        offs[i0 + 1] = excl + v0; cursor[i0 + 1] = excl + v0;
        dinv[i0 + 1] = rsqrtf((float)v1);
    }
    if (blockIdx.x == SC_BLKS - 1 && t == 255) offs[NN] = excl + pair;
}

__global__ void k_csr_fill(const int* __restrict__ dst, int* __restrict__ cursor,
                           int* __restrict__ eids)
{
    int gid = blockIdx.x * blockDim.x + threadIdx.x;
    if (gid >= EE + NN) return;
    int d = (gid < EE) ? dst[gid] : (gid - EE);
    int slot = atomicAdd(&cursor[d], 1);
    eids[slot] = gid;
}

// ---------- CSR gather with in-wave softmax (max + denom) ----------
__global__ __launch_bounds__(256) void k_gather(
    const int* __restrict__ src,
    const int* __restrict__ eids, const int* __restrict__ offs,
    const float* __restrict__ a_s, const float* __restrict__ a_d,
    const float* __restrict__ dinv,
    const float* __restrict__ x,
    ushort* __restrict__ tgh, ushort* __restrict__ tgl,
    ushort* __restrict__ tch, ushort* __restrict__ tcl,
    ushort* __restrict__ tsh, ushort* __restrict__ tsl)
{
    int d = blockIdx.x * 4 + (threadIdx.x >> 6);
    if (d >= NN) return;
    int lane = threadIdx.x & 63;
    int beg = offs[d], end = offs[d + 1];
    float ad = a_d[d], dd = dinv[d];

    int idx0 = beg + lane;
    bool v0 = idx0 < end;
    int s0 = d; float e0 = 0.f;
    if (v0) {
        int eid = eids[idx0];
        s0 = (eid < EE) ? src[eid] : d;
        float e = a_s[s0] + ad;
        e0 = (e > 0.f) ? e : 0.2f * e;
    }
    float m = v0 ? e0 : -3.0e38f;
    for (int base = beg + 64; base < end; base += 64) {
        int idx = base + lane;
        if (idx < end) {
            int eid = eids[idx];
            int s = (eid < EE) ? src[eid] : d;
            float e = a_s[s] + ad;
            e = (e > 0.f) ? e : 0.2f * e;
            m = fmaxf(m, e);
        }
    }
    #pragma unroll
    for (int off = 1; off < 64; off <<= 1) m = fmaxf(m, __shfl_xor(m, off));
    float den = v0 ? expf(e0 - m) : 0.f;
    for (int base = beg + 64; base < end; base += 64) {
        int idx = base + lane;
        if (idx < end) {
            int eid = eids[idx];
            int s = (eid < EE) ? src[eid] : d;
            float e = a_s[s] + ad;
            e = (e > 0.f) ? e : 0.2f * e;
            den += expf(e - m);
        }
    }
    #pragma unroll
    for (int off = 1; off < 64; off <<= 1) den += __shfl_xor(den, off);
    float rden = 1.f / den;

    float2 tg = {0.f, 0.f}, tc = {0.f, 0.f}, ts = {0.f, 0.f};
    int c = lane * 2;
    {
        float wg = v0 ? expf(e0 - m) * rden : 0.f;
        float wc = v0 ? dinv[s0] * dd : 0.f;
        int cnt = end - beg; if (cnt > 64) cnt = 64;
        for (int j = 0; j < cnt; ++j) {
            int   sj  = __shfl(s0, j);
            float wgj = __shfl(wg, j);
            float wcj = __shfl(wc, j);
            const float2 xv = *(const float2*)(x + (size_t)sj * 128 + c);
            tg.x += wgj * xv.x; tg.y += wgj * xv.y;
            tc.x += wcj * xv.x; tc.y += wcj * xv.y;
            ts.x += xv.x;       ts.y += xv.y;
        }
    }
    for (int base = beg + 64; base < end; base += 64) {
        int idx = base + lane;
        int s = d; float wg = 0.f, wc = 0.f;
        if (idx < end) {
            int eid = eids[idx];
            s = (eid < EE) ? src[eid] : d;
            float e = a_s[s] + ad;
            e = (e > 0.f) ? e : 0.2f * e;
            wg = expf(e - m) * rden;
            wc = dinv[s] * dd;
        }
        int cnt = end - base; if (cnt > 64) cnt = 64;
        for (int j = 0; j < cnt; ++j) {
            int   sj  = __shfl(s, j);
            float wgj = __shfl(wg, j);
            float wcj = __shfl(wc, j);
            const float2 xv = *(const float2*)(x + (size_t)sj * 128 + c);
            tg.x += wgj * xv.x; tg.y += wgj * xv.y;
            tc.x += wcj * xv.x; tc.y += wcj * xv.y;
            ts.x += xv.x;       ts.y += xv.y;
        }
    }
    const float2 xd = *(const float2*)(x + (size_t)d * 128 + c);
    ts.x -= xd.x; ts.y -= xd.y;
    int cs = (end - beg) - 1;
    float rc = 1.f / (float)(cs > 1 ? cs : 1);
    ts.x *= rc; ts.y *= rc;

    size_t row = (size_t)d * 128 + c;
    ushort h0, l0, h1, l1;
    bsplit(tg.x, h0, l0); bsplit(tg.y, h1, l1);
    { ushort2 u; u.x = h0; u.y = h1; *(ushort2*)(tgh + row) = u; }
    { ushort2 u; u.x = l0; u.y = l1; *(ushort2*)(tgl + row) = u; }
    bsplit(tc.x, h0, l0); bsplit(tc.y, h1, l1);
    { ushort2 u; u.x = h0; u.y = h1; *(ushort2*)(tch + row) = u; }
    { ushort2 u; u.x = l0; u.y = l1; *(ushort2*)(tcl + row) = u; }
    bsplit(ts.x, h0, l0); bsplit(ts.y, h1, l1);
    { ushort2 u; u.x = h0; u.y = h1; *(ushort2*)(tsh + row) = u; }
    { ushort2 u; u.x = l0; u.y = l1; *(ushort2*)(tsl + row) = u; }
}

__global__ void k_bn_final(const float* __restrict__ sums, const float* __restrict__ sumsq,
                           const float* __restrict__ gamma, const float* __restrict__ beta,
                           float* __restrict__ scale, float* __restrict__ shift)
{
    int j = threadIdx.x;
    if (j >= C3) return;
    const float rn = 1.f / (float)NN;
    float mu  = sums[j] * rn;
    float var = sumsq[j] * rn - mu * mu;
    float sc  = gamma[j] * rsqrtf(var + 1e-5f);
    scale[j] = sc;
    shift[j] = beta[j] - mu * sc;
}

// ---------- in-place BN+relu of split hcat (flat over NN*192 pairs) ----------
__global__ __launch_bounds__(256) void k_bnrelu(
    ushort* __restrict__ hch, ushort* __restrict__ hcl,
    const float* __restrict__ scale, const float* __restrict__ shift)
{
    int p = blockIdx.x * blockDim.x + threadIdx.x;
    if (p >= NN * 192) return;
    int cpair = p % 192;
    int cidx = cpair * 2;
    size_t o = (size_t)p * 2;
    ushort2 h = *(ushort2*)(hch + o);
    ushort2 l = *(ushort2*)(hcl + o);
    float v0 = b2f(h.x) + b2f(l.x);
    float v1 = b2f(h.y) + b2f(l.y);
    v0 = v0 * scale[cidx] + shift[cidx];         v0 = v0 > 0.f ? v0 : 0.f;
    v1 = v1 * scale[cidx + 1] + shift[cidx + 1]; v1 = v1 > 0.f ? v1 : 0.f;
    ushort h0, l0, h1, l1;
    bsplit(v0, h0, l0); bsplit(v1, h1, l1);
    { ushort2 u; u.x = h0; u.y = h1; *(ushort2*)(hch + o) = u; }
    { ushort2 u; u.x = l0; u.y = l1; *(ushort2*)(hcl + o) = u; }
}

extern "C" void kernel_launch(void* const* d_in, const int* in_sizes, int n_in,
                              void* d_out, int out_size, void* d_ws, size_t ws_size,
                              hipStream_t stream) {
    const float* x        = (const float*)d_in[0];
    const int*   ei       = (const int*)d_in[1];
    const float* W_gat    = (const float*)d_in[2];
    const float* att_src  = (const float*)d_in[3];
    const float* att_dst  = (const float*)d_in[4];
    const float* b_gat    = (const float*)d_in[5];
    const float* W_gcn    = (const float*)d_in[6];
    const float* b_gcn    = (const float*)d_in[7];
    const float* W_sage_l = (const float*)d_in[8];
    const float* b_sage_l = (const float*)d_in[9];
    const float* W_sage_r = (const float*)d_in[10];
    const float* W1       = (const float*)d_in[11];
    const float* b1       = (const float*)d_in[12];
    const float* W2       = (const float*)d_in[13];
    const float* b2       = (const float*)d_in[14];
    const float* W3       = (const float*)d_in[15];
    const float* b3       = (const float*)d_in[16];
    const float* gamma    = (const float*)d_in[17];
    const float* beta     = (const float*)d_in[18];

    const int* e_src = ei;
    const int* e_dst = ei + EE;

    // ---- workspace layout (all offsets 16B-aligned) ----
    char* base = (char*)d_ws;
    size_t o = 0;
    ushort* hch  = (ushort*)(base + o); o += (size_t)NN * C3 * 2;
    ushort* hcl  = (ushort*)(base + o); o += (size_t)NN * C3 * 2;
    ushort* tgh  = (ushort*)(base + o); o += (size_t)NN * 128 * 2;   // a1h overlay (spans tgh+tgl)
    ushort* tgl  = (ushort*)(base + o); o += (size_t)NN * 128 * 2;
    ushort* tch  = (ushort*)(base + o); o += (size_t)NN * 128 * 2;   // a1l overlay (spans tch+tcl)
    ushort* tcl  = (ushort*)(base + o); o += (size_t)NN * 128 * 2;
    ushort* tsh  = (ushort*)(base + o); o += (size_t)NN * 128 * 2;   // a2h overlay
    ushort* tsl  = (ushort*)(base + o); o += (size_t)NN * 128 * 2;   // a2l overlay
    ushort* xhi  = (ushort*)(base + o); o += (size_t)NN * 128 * 2;
    ushort* xlo  = (ushort*)(base + o); o += (size_t)NN * 128 * 2;
    int*    eids = (int*)(base + o);    o += (size_t)(EE + NN) * 4;
    int*    offs = (int*)(base + o);    o += (size_t)(NN + 16) * 4;
    int*    cursor=(int*)(base + o);    o += (size_t)NN * 4;
    float*  as_  = (float*)(base + o);  o += (size_t)NN * 4;
    float*  ad_  = (float*)(base + o);  o += (size_t)NN * 4;
    float*  dinv = (float*)(base + o);  o += (size_t)NN * 4;
    int*    bsum = (int*)(base + o);    o += 256 * 4;
    int*    boffs= (int*)(base + o);    o += 256 * 4;
    // --- zero-init region: degA, sums, sumsq (contiguous) ---
    int*    degA = (int*)(base + o);    o += (size_t)NN * 4;
    float*  sums = (float*)(base + o);  o += C3 * 4;
    float*  sumsq= (float*)(base + o);  o += C3 * 4;
    // --- end zero region ---
    float*  scale= (float*)(base + o);  o += C3 * 4;
    float*  shift= (float*)(base + o);  o += C3 * 4;
    float*  w_as = (float*)(base + o);  o += 128 * 4;
    float*  w_ad = (float*)(base + o);  o += 128 * 4;
    ushort* btg_h = (ushort*)(base + o); o += 128 * 128 * 2;
    ushort* btg_l = (ushort*)(base + o); o += 128 * 128 * 2;
    ushort* btc_h = (ushort*)(base + o); o += 128 * 128 * 2;
    ushort* btc_l = (ushort*)(base + o); o += 128 * 128 * 2;
    ushort* btsg_h= (ushort*)(base + o); o += 128 * 256 * 2;
    ushort* btsg_l= (ushort*)(base + o); o += 128 * 256 * 2;
    ushort* bt1_h = (ushort*)(base + o); o += 256 * 384 * 2;
    ushort* bt1_l = (ushort*)(base + o); o += 256 * 384 * 2;
    ushort* bt2_h = (ushort*)(base + o); o += 128 * 256 * 2;
    ushort* bt2_l = (ushort*)(base + o); o += 128 * 256 * 2;
    ushort* bt3_h = (ushort*)(base + o); o += 48 * 128 * 2;
    ushort* bt3_l = (ushort*)(base + o); o += 48 * 128 * 2;
    // overlays (temporally disjoint with t*/x buffers)
    ushort* a1h = tgh;                       // NN*256 ushorts
    ushort* a1l = tch;                       // NN*256 ushorts
    ushort* a2h = tsh;                       // NN*128
    ushort* a2l = tsl;                       // NN*128

    hipMemsetAsync(degA, 0, (size_t)NN * 4 + 2 * C3 * 4, stream);

    // ---- weight prep ----
    k_att_w<<<1, 128, 0, stream>>>(W_gat, att_src, att_dst, w_as, w_ad);
    k_splitw_all<<<816, 256, 0, stream>>>(W_gat, W_gcn, W_sage_l, W_sage_r, W1, W2, W3,
        btg_h, btg_l, btc_h, btc_l, btsg_h, btsg_l, bt1_h, bt1_l, bt2_h, bt2_l, bt3_h, bt3_l);
    k_split_x_att<<<(NN + 3) / 4, 256, 0, stream>>>(x, w_as, w_ad, xhi, xlo, as_, ad_);

    // ---- CSR build (hierarchical scan) ----
    k_edge1<<<(EE + 255) / 256, 256, 0, stream>>>(e_dst, degA);
    k_scan_part<<<SC_BLKS, 256, 0, stream>>>(degA, bsum);
    k_scan_tops<<<1, 128, 0, stream>>>(bsum, boffs);
    k_scan_apply<<<SC_BLKS, 256, 0, stream>>>(degA, boffs, offs, cursor, dinv);
    k_csr_fill<<<(EE + NN + 255) / 256, 256, 0, stream>>>(e_dst, cursor, eids);

    // ---- gather: softmax in-wave + weighted x sums ----
    k_gather<<<(NN + 3) / 4, 256, 0, stream>>>(
        e_src, eids, offs, as_, ad_, dinv, x, tgh, tgl, tch, tcl, tsh, tsl);

    // ---- producers (with fused BN stats) ----
    dim3 gg((NN + 127) / 128, 1);
    k_gemm2<8, 1><<<gg, 256, 0, stream>>>(tgh, tgl, 128, tgh, tgl, 128,
        btg_h, btg_l, NN, 1, b_gat, sums, sumsq,
        nullptr, 0, hch, hcl, C3, 128);
    k_gemm2<8, 1><<<gg, 256, 0, stream>>>(tch, tcl, 128, tch, tcl, 128,
        btc_h, btc_l, NN, 1, b_gcn, sums + 128, sumsq + 128,
        nullptr, 0, hch + 128, hcl + 128, C3, 128);
    k_gemm2<8, 2><<<gg, 256, 0, stream>>>(tsh, tsl, 128, xhi, xlo, 128,
        btsg_h, btsg_l, NN, 1, b_sage_l, sums + 256, sumsq + 256,
        nullptr, 0, hch + 256, hcl + 256, C3, 128);

    // ---- BN fold + in-place transform ----
    k_bn_final<<<1, C3, 0, stream>>>(sums, sumsq, gamma, beta, scale, shift);
    k_bnrelu<<<(NN * 192 + 255) / 256, 256, 0, stream>>>(hch, hcl, scale, shift);

    // ---- MLP ----
    dim3 g1((NN + 127) / 128, 2);
    k_gemm2<8, 3><<<g1, 256, 0, stream>>>(hch, hcl, 384, hch, hcl, 384,
        bt1_h, bt1_l, NN, 0, b1, nullptr, nullptr,
        nullptr, 0, a1h, a1l, 256, 256);
    k_gemm2<8, 2><<<gg, 256, 0, stream>>>(a1h, a1l, 256, a1h, a1l, 256,
        bt2_h, bt2_l, NN, 0, b2, nullptr, nullptr,
        nullptr, 0, a2h, a2l, 128, 128);
    k_gemm2<3, 1><<<gg, 256, 0, stream>>>(a2h, a2l, 128, a2h, a2l, 128,
        bt3_h, bt3_l, NN, 2, b3, nullptr, nullptr,
        (float*)d_out, NOUT, nullptr, nullptr, 0, NOUT);
}

// Round 8
// 718.859 us; speedup vs baseline: 4.4928x; 1.0369x over previous
//
#include <hip/hip_runtime.h>
#include <cstdint>
#include <cstddef>

#define NN   50000
#define FIN  128
#define HD   128
#define EE   800000
#define C3   384   // 3*H
#define NOUT 40

// hierarchical scan geometry
#define SC_ELEMS 512                       // elements per block (256 thr x 2)
#define SC_BLKS  ((NN + SC_ELEMS - 1) / SC_ELEMS)   // 98

typedef __attribute__((ext_vector_type(8))) short s8v;   // 8 x bf16 (4 VGPR)
typedef __attribute__((ext_vector_type(4))) float f4v;   // MFMA acc

typedef const __attribute__((address_space(1))) unsigned int* guintp;
typedef __attribute__((address_space(3))) unsigned int* luintp;

// async global->LDS 16B per lane: LDS dst = base + lane*16 (wave-uniform base)
static __device__ __forceinline__ void async_copy16(const void* g, void* l) {
    __builtin_amdgcn_global_load_lds((guintp)g, (luintp)l, 16, 0, 0);
}

// ---------- bf16 helpers ----------
static __device__ __forceinline__ float b2f(ushort u) {
    return __uint_as_float((unsigned)u << 16);
}
static __device__ __forceinline__ ushort f2b(float v) {
    unsigned u = __float_as_uint(v);
    unsigned r = u + 0x7fffu + ((u >> 16) & 1u);
    return (ushort)(r >> 16);
}
static __device__ __forceinline__ void bsplit(float v, ushort& h, ushort& l) {
    h = f2b(v);
    float hf = b2f(h);
    l = f2b(v - hf);
}

// ---------- merged: split x -> bf16 hi/lo AND attention dots ----------
__global__ __launch_bounds__(256) void k_split_x_att(
    const float* __restrict__ x,
    const float* __restrict__ w_as, const float* __restrict__ w_ad,
    ushort* __restrict__ xh, ushort* __restrict__ xl,
    float* __restrict__ a_s, float* __restrict__ a_d)
{
    int node = blockIdx.x * 4 + (threadIdx.x >> 6);
    if (node >= NN) return;
    int lane = threadIdx.x & 63;
    size_t o = (size_t)node * 128 + lane * 2;
    float2 v  = *(const float2*)(x + o);
    ushort hx, lx, hy, ly;
    bsplit(v.x, hx, lx); bsplit(v.y, hy, ly);
    { ushort2 u; u.x = hx; u.y = hy; *(ushort2*)(xh + o) = u; }
    { ushort2 u; u.x = lx; u.y = ly; *(ushort2*)(xl + o) = u; }
    float2 w1 = *(const float2*)(w_as + lane * 2);
    float2 w2 = *(const float2*)(w_ad + lane * 2);
    float s1 = v.x * w1.x + v.y * w1.y;
    float s2 = v.x * w2.x + v.y * w2.y;
    #pragma unroll
    for (int off = 32; off; off >>= 1) {
        s1 += __shfl_down(s1, off);
        s2 += __shfl_down(s2, off);
    }
    if (lane == 0) { a_s[node] = s1; a_d[node] = s2; }
}

// ---------- all weight splits+transposes in one launch ----------
__global__ void k_splitw_all(
    const float* __restrict__ Wg, const float* __restrict__ Wc,
    const float* __restrict__ Wl, const float* __restrict__ Wr,
    const float* __restrict__ W1, const float* __restrict__ W2,
    const float* __restrict__ W3,
    ushort* __restrict__ btg_h, ushort* __restrict__ btg_l,
    ushort* __restrict__ btc_h, ushort* __restrict__ btc_l,
    ushort* __restrict__ btsg_h, ushort* __restrict__ btsg_l,
    ushort* __restrict__ bt1_h, ushort* __restrict__ bt1_l,
    ushort* __restrict__ bt2_h, ushort* __restrict__ bt2_l,
    ushort* __restrict__ bt3_h, ushort* __restrict__ bt3_l)
{
    int ry = blockIdx.x;
    int t = threadIdx.x;
    const float* W = nullptr; ushort* dh; ushort* dl; int K, Nw, n;
    bool sage = false;
    if (ry < 128)      { n = ry;       K = 128; Nw = 128; W = Wg; dh = btg_h; dl = btg_l; }
    else if (ry < 256) { n = ry - 128; K = 128; Nw = 128; W = Wc; dh = btc_h; dl = btc_l; }
    else if (ry < 384) { n = ry - 256; K = 256; Nw = 128; sage = true; dh = btsg_h; dl = btsg_l; }
    else if (ry < 640) { n = ry - 384; K = 384; Nw = 256; W = W1; dh = bt1_h; dl = bt1_l; }
    else if (ry < 768) { n = ry - 640; K = 256; Nw = 128; W = W2; dh = bt2_h; dl = bt2_l; }
    else               { n = ry - 768; K = 128; Nw = 40;  W = W3; dh = bt3_h; dl = bt3_l; }
    for (int k = t; k < K; k += 256) {
        float v;
        if (sage) v = (k < 128) ? Wl[(size_t)k * 128 + n] : Wr[(size_t)(k - 128) * 128 + n];
        else      v = (n < Nw) ? W[(size_t)k * Nw + n] : 0.f;
        ushort h, l; bsplit(v, h, l);
        dh[(size_t)n * K + k] = h;
        dl[(size_t)n * K + k] = l;
    }
}

// ---------- fold attention vectors: w_as = W_gat @ att_src ----------
__global__ void k_att_w(const float* __restrict__ Wg,
                        const float* __restrict__ asv, const float* __restrict__ adv,
                        float* __restrict__ w_as, float* __restrict__ w_ad) {
    int f = threadIdx.x;  // 128
    float s1 = 0.f, s2 = 0.f;
    for (int j = 0; j < 128; ++j) {
        float w = Wg[f * 128 + j];
        s1 += w * asv[j];
        s2 += w * adv[j];
    }
    w_as[f] = s1; w_ad[f] = s2;
}

// ---------- MFMA split-bf16 GEMM, 32KB half-chunk LDS staging ----------
// wave = 32 rows x NT*16 cols; block = 4 waves = 128 rows x NT*16 cols.
// B staged in 64-k halves (32 KB LDS) -> 4 blocks/CU (vs 2 at 64 KB).
template<int NT, int NCH>
__global__ __launch_bounds__(256, 4) void k_gemm2(
    const ushort* __restrict__ A1h, const ushort* __restrict__ A1l, int K1,
    const ushort* __restrict__ A2h, const ushort* __restrict__ A2l, int K2,
    const ushort* __restrict__ Bth, const ushort* __restrict__ Btl,
    int M, int mode,
    const float* __restrict__ bias,
    float* __restrict__ sums, float* __restrict__ sumsq,
    float* __restrict__ Cf, int ldc,
    ushort* __restrict__ Chi, ushort* __restrict__ Clo, int ldch,
    int colmax)
{
    constexpr int COLS = NT * 16;
    constexpr int HOPU = 8 * COLS;       // 16B-units per operand per HALF (64 k)
    constexpr int ISS  = (2 * HOPU) / 256;   // issues per wave per half
    constexpr int KTOT = NCH * 128;
    constexpr int NK   = NCH * 4;        // 32-k steps total

    __shared__ __align__(16) ushort Bs[2 * HOPU * 8];   // 32 KB @ NT=8

    const int lane = threadIdx.x & 63;
    const int wave = threadIdx.x >> 6;
    const int quad = lane >> 4;
    const int ln15 = lane & 15;
    const int row0 = (blockIdx.x * 4 + wave) * 32;
    const int col0 = blockIdx.y * COLS;

    int r0 = row0 + ln15;        if (r0 > M - 1) r0 = M - 1;
    int r1 = row0 + 16 + ln15;   if (r1 > M - 1) r1 = M - 1;

    // stage half h (64 k) of chunk c: LDS unit u -> op|kq|col
    auto stage = [&](int c, int h) {
        #pragma unroll
        for (int i = 0; i < ISS; ++i) {
            int u0 = (wave * ISS + i) * 64;
            int u  = u0 + lane;
            int op = u / HOPU;               // HOPU % 64 == 0 -> uniform/issue
            int rem = u - op * HOPU;
            int kq  = rem / COLS;            // 0..7 (8 k each)
            int col = rem - kq * COLS;
            int kk  = c * 128 + h * 64 + kq * 8;
            const ushort* spt = op ? Btl : Bth;
            const ushort* gp = spt + (size_t)(col0 + col) * KTOT + kk;
            async_copy16(gp, (char*)Bs + (size_t)u0 * 16);
        }
    };
    auto loadA = [&](int kk, s8v& h0, s8v& l0, s8v& h1, s8v& l1) {
        const ushort* ah; const ushort* al; size_t o0, o1;
        if (kk < K1) { ah = A1h; al = A1l; o0 = (size_t)r0 * K1 + kk; o1 = (size_t)r1 * K1 + kk; }
        else { ah = A2h; al = A2l; int k2 = kk - K1; o0 = (size_t)r0 * K2 + k2; o1 = (size_t)r1 * K2 + k2; }
        int q8 = quad * 8;
        h0 = *(const s8v*)(ah + o0 + q8);
        l0 = *(const s8v*)(al + o0 + q8);
        h1 = *(const s8v*)(ah + o1 + q8);
        l1 = *(const s8v*)(al + o1 + q8);
    };

    f4v acc[2][NT] = {};
    s8v cah0, cal0, cah1, cal1, nah0, nal0, nah1, nal1;

    stage(0, 0);
    loadA(0, cah0, cal0, cah1, cal1);
    __syncthreads();

    #pragma unroll
    for (int c = 0; c < NCH; ++c) {
        #pragma unroll
        for (int h = 0; h < 2; ++h) {
            #pragma unroll
            for (int jj = 0; jj < 2; ++jj) {
                int kj = c * 4 + h * 2 + jj;
                int nk = (kj + 1 < NK) ? (kj + 1) * 32 : 0;   // last: dummy
                loadA(nk, nah0, nal0, nah1, nal1);
                #pragma unroll
                for (int t = 0; t < NT; ++t) {
                    int ub = (jj * 4 + quad) * COLS + t * 16 + ln15;
                    s8v bh = *(const s8v*)(Bs + (size_t)ub * 8);
                    s8v bl = *(const s8v*)(Bs + (size_t)(HOPU + ub) * 8);
                    acc[0][t] = __builtin_amdgcn_mfma_f32_16x16x32_bf16(cah0, bh, acc[0][t], 0, 0, 0);
                    acc[1][t] = __builtin_amdgcn_mfma_f32_16x16x32_bf16(cah1, bh, acc[1][t], 0, 0, 0);
                    acc[0][t] = __builtin_amdgcn_mfma_f32_16x16x32_bf16(cah0, bl, acc[0][t], 0, 0, 0);
                    acc[1][t] = __builtin_amdgcn_mfma_f32_16x16x32_bf16(cah1, bl, acc[1][t], 0, 0, 0);
                    acc[0][t] = __builtin_amdgcn_mfma_f32_16x16x32_bf16(cal0, bh, acc[0][t], 0, 0, 0);
                    acc[1][t] = __builtin_amdgcn_mfma_f32_16x16x32_bf16(cal1, bh, acc[1][t], 0, 0, 0);
                }
                cah0 = nah0; cal0 = nal0; cah1 = nah1; cal1 = nal1;
            }
            if (!(c == NCH - 1 && h == 1)) {
                __syncthreads();          // all waves done reading Bs
                int nc = c, nh = h + 1;
                if (nh == 2) { nh = 0; ++nc; }
                stage(nc, nh);
                __syncthreads();
            }
        }
    }

    const bool dostats = (sums != nullptr);
    #pragma unroll
    for (int t = 0; t < NT; ++t) {
        int cc = col0 + t * 16 + ln15;
        float sp = 0.f, qp = 0.f;
        #pragma unroll
        for (int mt = 0; mt < 2; ++mt) {
            #pragma unroll
            for (int r = 0; r < 4; ++r) {
                int rr = row0 + mt * 16 + quad * 4 + r;
                bool ok = (rr < M);
                float v = acc[mt][t][r];
                if (mode == 0) {
                    v += bias[cc];
                    v = v > 0.f ? v : 0.f;
                    if (ok) {
                        ushort h, l; bsplit(v, h, l);
                        Chi[(size_t)rr * ldch + cc] = h;
                        Clo[(size_t)rr * ldch + cc] = l;
                    }
                } else if (mode == 1) {
                    v += bias[cc];
                    if (ok) {
                        ushort h, l; bsplit(v, h, l);
                        Chi[(size_t)rr * ldch + cc] = h;
                        Clo[(size_t)rr * ldch + cc] = l;
                        sp += v; qp += v * v;
                    }
                } else {
                    if (ok && cc < colmax) Cf[(size_t)rr * ldc + cc] = v + bias[cc];
                }
            }
        }
        if (dostats) {
            sp += __shfl_xor(sp, 16); sp += __shfl_xor(sp, 32);
            qp += __shfl_xor(qp, 16); qp += __shfl_xor(qp, 32);
            if (quad == 0) {
                unsafeAtomicAdd(&sums[cc], sp);
                unsafeAtomicAdd(&sumsq[cc], qp);
            }
        }
    }
}

// ---------- edge pass: dst-degree histogram (real edges only) ----------
__global__ void k_edge1(const int* __restrict__ dst, int* __restrict__ degA)
{
    int gid = blockIdx.x * blockDim.x + threadIdx.x;
    if (gid >= EE) return;
    atomicAdd(&degA[dst[gid]], 1);
}

// ---------- hierarchical exclusive scan over (degA[i]+1) ----------
__global__ __launch_bounds__(256) void k_scan_part(
    const int* __restrict__ degA, int* __restrict__ bsum)
{
    int t = threadIdx.x;
    int b0 = blockIdx.x * SC_ELEMS;
    int i0 = b0 + t * 2;
    int v0 = (i0 < NN)     ? degA[i0] + 1     : 0;
    int v1 = (i0 + 1 < NN) ? degA[i0 + 1] + 1 : 0;
    int s = v0 + v1;
    #pragma unroll
    for (int off = 32; off; off >>= 1) s += __shfl_down(s, off);
    __shared__ int ws[4];
    if ((t & 63) == 0) ws[t >> 6] = s;
    __syncthreads();
    if (t == 0) bsum[blockIdx.x] = ws[0] + ws[1] + ws[2] + ws[3];
}

__global__ __launch_bounds__(128) void k_scan_tops(
    const int* __restrict__ bsum, int* __restrict__ boffs)
{
    __shared__ int sh[128];
    int t = threadIdx.x;
    int v = (t < SC_BLKS) ? bsum[t] : 0;
    sh[t] = v;
    __syncthreads();
    for (int off = 1; off < 128; off <<= 1) {
        int u = (t >= off) ? sh[t - off] : 0;
        __syncthreads();
        sh[t] += u;
        __syncthreads();
    }
    if (t < SC_BLKS) boffs[t] = sh[t] - v;   // exclusive
    if (t == SC_BLKS - 1) boffs[SC_BLKS] = sh[t];
}

// phase 3: OOB elements contribute 0 (R6 bug fixed in R7, kept)
__global__ __launch_bounds__(256) void k_scan_apply(
    const int* __restrict__ degA, const int* __restrict__ boffs,
    int* __restrict__ offs, int* __restrict__ cursor,
    float* __restrict__ dinv)
{
    __shared__ int sh[256];
    int t = threadIdx.x;
    int b0 = blockIdx.x * SC_ELEMS;
    int i0 = b0 + t * 2;
    int v0 = (i0 < NN)     ? degA[i0] + 1     : 0;
    int v1 = (i0 + 1 < NN) ? degA[i0 + 1] + 1 : 0;
    int pair = v0 + v1;
    sh[t] = pair;
    __syncthreads();
    for (int off = 1; off < 256; off <<= 1) {
        int u = (t >= off) ? sh[t - off] : 0;
        __syncthreads();
        sh[t] += u;
        __syncthreads();
    }
    int excl = sh[t] - pair + boffs[blockIdx.x];
    if (i0 < NN) {
        offs[i0] = excl; cursor[i0] = excl;
        dinv[i0] = rsqrtf((float)v0);
    }
    if (i0 + 1 < NN) {
        offs[i0 + 1] = excl + v0; cursor[i0 + 1] = excl + v0;
        dinv[i0 + 1] = rsqrtf((float)v1);
    }
    if (blockIdx.x == SC_BLKS - 1 && t == 255) offs[NN] = excl + pair;
}

__global__ void k_csr_fill(const int* __restrict__ dst, int* __restrict__ cursor,
                           int* __restrict__ eids)
{
    int gid = blockIdx.x * blockDim.x + threadIdx.x;
    if (gid >= EE + NN) return;
    int d = (gid < EE) ? dst[gid] : (gid - EE);
    int slot = atomicAdd(&cursor[d], 1);
    eids[slot] = gid;
}

// ---------- CSR gather with in-wave softmax (max + denom) ----------
__global__ __launch_bounds__(256) void k_gather(
    const int* __restrict__ src,
    const int* __restrict__ eids, const int* __restrict__ offs,
    const float* __restrict__ a_s, const float* __restrict__ a_d,
    const float* __restrict__ dinv,
    const float* __restrict__ x,
    ushort* __restrict__ tgh, ushort* __restrict__ tgl,
    ushort* __restrict__ tch, ushort* __restrict__ tcl,
    ushort* __restrict__ tsh, ushort* __restrict__ tsl)
{
    int d = blockIdx.x * 4 + (threadIdx.x >> 6);
    if (d >= NN) return;
    int lane = threadIdx.x & 63;
    int beg = offs[d], end = offs[d + 1];
    float ad = a_d[d], dd = dinv[d];

    int idx0 = beg + lane;
    bool v0 = idx0 < end;
    int s0 = d; float e0 = 0.f;
    if (v0) {
        int eid = eids[idx0];
        s0 = (eid < EE) ? src[eid] : d;
        float e = a_s[s0] + ad;
        e0 = (e > 0.f) ? e : 0.2f * e;
    }
    float m = v0 ? e0 : -3.0e38f;
    for (int base = beg + 64; base < end; base += 64) {
        int idx = base + lane;
        if (idx < end) {
            int eid = eids[idx];
            int s = (eid < EE) ? src[eid] : d;
            float e = a_s[s] + ad;
            e = (e > 0.f) ? e : 0.2f * e;
            m = fmaxf(m, e);
        }
    }
    #pragma unroll
    for (int off = 1; off < 64; off <<= 1) m = fmaxf(m, __shfl_xor(m, off));
    float den = v0 ? expf(e0 - m) : 0.f;
    for (int base = beg + 64; base < end; base += 64) {
        int idx = base + lane;
        if (idx < end) {
            int eid = eids[idx];
            int s = (eid < EE) ? src[eid] : d;
            float e = a_s[s] + ad;
            e = (e > 0.f) ? e : 0.2f * e;
            den += expf(e - m);
        }
    }
    #pragma unroll
    for (int off = 1; off < 64; off <<= 1) den += __shfl_xor(den, off);
    float rden = 1.f / den;

    float2 tg = {0.f, 0.f}, tc = {0.f, 0.f}, ts = {0.f, 0.f};
    int c = lane * 2;
    {
        float wg = v0 ? expf(e0 - m) * rden : 0.f;
        float wc = v0 ? dinv[s0] * dd : 0.f;
        int cnt = end - beg; if (cnt > 64) cnt = 64;
        for (int j = 0; j < cnt; ++j) {
            int   sj  = __shfl(s0, j);
            float wgj = __shfl(wg, j);
            float wcj = __shfl(wc, j);
            const float2 xv = *(const float2*)(x + (size_t)sj * 128 + c);
            tg.x += wgj * xv.x; tg.y += wgj * xv.y;
            tc.x += wcj * xv.x; tc.y += wcj * xv.y;
            ts.x += xv.x;       ts.y += xv.y;
        }
    }
    for (int base = beg + 64; base < end; base += 64) {
        int idx = base + lane;
        int s = d; float wg = 0.f, wc = 0.f;
        if (idx < end) {
            int eid = eids[idx];
            s = (eid < EE) ? src[eid] : d;
            float e = a_s[s] + ad;
            e = (e > 0.f) ? e : 0.2f * e;
            wg = expf(e - m) * rden;
            wc = dinv[s] * dd;
        }
        int cnt = end - base; if (cnt > 64) cnt = 64;
        for (int j = 0; j < cnt; ++j) {
            int   sj  = __shfl(s, j);
            float wgj = __shfl(wg, j);
            float wcj = __shfl(wc, j);
            const float2 xv = *(const float2*)(x + (size_t)sj * 128 + c);
            tg.x += wgj * xv.x; tg.y += wgj * xv.y;
            tc.x += wcj * xv.x; tc.y += wcj * xv.y;
            ts.x += xv.x;       ts.y += xv.y;
        }
    }
    const float2 xd = *(const float2*)(x + (size_t)d * 128 + c);
    ts.x -= xd.x; ts.y -= xd.y;
    int cs = (end - beg) - 1;
    float rc = 1.f / (float)(cs > 1 ? cs : 1);
    ts.x *= rc; ts.y *= rc;

    size_t row = (size_t)d * 128 + c;
    ushort h0, l0, h1, l1;
    bsplit(tg.x, h0, l0); bsplit(tg.y, h1, l1);
    { ushort2 u; u.x = h0; u.y = h1; *(ushort2*)(tgh + row) = u; }
    { ushort2 u; u.x = l0; u.y = l1; *(ushort2*)(tgl + row) = u; }
    bsplit(tc.x, h0, l0); bsplit(tc.y, h1, l1);
    { ushort2 u; u.x = h0; u.y = h1; *(ushort2*)(tch + row) = u; }
    { ushort2 u; u.x = l0; u.y = l1; *(ushort2*)(tcl + row) = u; }
    bsplit(ts.x, h0, l0); bsplit(ts.y, h1, l1);
    { ushort2 u; u.x = h0; u.y = h1; *(ushort2*)(tsh + row) = u; }
    { ushort2 u; u.x = l0; u.y = l1; *(ushort2*)(tsl + row) = u; }
}

__global__ void k_bn_final(const float* __restrict__ sums, const float* __restrict__ sumsq,
                           const float* __restrict__ gamma, const float* __restrict__ beta,
                           float* __restrict__ scale, float* __restrict__ shift)
{
    int j = threadIdx.x;
    if (j >= C3) return;
    const float rn = 1.f / (float)NN;
    float mu  = sums[j] * rn;
    float var = sumsq[j] * rn - mu * mu;
    float sc  = gamma[j] * rsqrtf(var + 1e-5f);
    scale[j] = sc;
    shift[j] = beta[j] - mu * sc;
}

// ---------- in-place BN+relu of split hcat (flat over NN*192 pairs) ----------
__global__ __launch_bounds__(256) void k_bnrelu(
    ushort* __restrict__ hch, ushort* __restrict__ hcl,
    const float* __restrict__ scale, const float* __restrict__ shift)
{
    int p = blockIdx.x * blockDim.x + threadIdx.x;
    if (p >= NN * 192) return;
    int cpair = p % 192;
    int cidx = cpair * 2;
    size_t o = (size_t)p * 2;
    ushort2 h = *(ushort2*)(hch + o);
    ushort2 l = *(ushort2*)(hcl + o);
    float v0 = b2f(h.x) + b2f(l.x);
    float v1 = b2f(h.y) + b2f(l.y);
    v0 = v0 * scale[cidx] + shift[cidx];         v0 = v0 > 0.f ? v0 : 0.f;
    v1 = v1 * scale[cidx + 1] + shift[cidx + 1]; v1 = v1 > 0.f ? v1 : 0.f;
    ushort h0, l0, h1, l1;
    bsplit(v0, h0, l0); bsplit(v1, h1, l1);
    { ushort2 u; u.x = h0; u.y = h1; *(ushort2*)(hch + o) = u; }
    { ushort2 u; u.x = l0; u.y = l1; *(ushort2*)(hcl + o) = u; }
}

extern "C" void kernel_launch(void* const* d_in, const int* in_sizes, int n_in,
                              void* d_out, int out_size, void* d_ws, size_t ws_size,
                              hipStream_t stream) {
    const float* x        = (const float*)d_in[0];
    const int*   ei       = (const int*)d_in[1];
    const float* W_gat    = (const float*)d_in[2];
    const float* att_src  = (const float*)d_in[3];
    const float* att_dst  = (const float*)d_in[4];
    const float* b_gat    = (const float*)d_in[5];
    const float* W_gcn    = (const float*)d_in[6];
    const float* b_gcn    = (const float*)d_in[7];
    const float* W_sage_l = (const float*)d_in[8];
    const float* b_sage_l = (const float*)d_in[9];
    const float* W_sage_r = (const float*)d_in[10];
    const float* W1       = (const float*)d_in[11];
    const float* b1       = (const float*)d_in[12];
    const float* W2       = (const float*)d_in[13];
    const float* b2       = (const float*)d_in[14];
    const float* W3       = (const float*)d_in[15];
    const float* b3       = (const float*)d_in[16];
    const float* gamma    = (const float*)d_in[17];
    const float* beta     = (const float*)d_in[18];

    const int* e_src = ei;
    const int* e_dst = ei + EE;

    // ---- workspace layout (all offsets 16B-aligned) ----
    char* base = (char*)d_ws;
    size_t o = 0;
    ushort* hch  = (ushort*)(base + o); o += (size_t)NN * C3 * 2;
    ushort* hcl  = (ushort*)(base + o); o += (size_t)NN * C3 * 2;
    ushort* tgh  = (ushort*)(base + o); o += (size_t)NN * 128 * 2;   // a1h overlay (spans tgh+tgl)
    ushort* tgl  = (ushort*)(base + o); o += (size_t)NN * 128 * 2;
    ushort* tch  = (ushort*)(base + o); o += (size_t)NN * 128 * 2;   // a1l overlay (spans tch+tcl)
    ushort* tcl  = (ushort*)(base + o); o += (size_t)NN * 128 * 2;
    ushort* tsh  = (ushort*)(base + o); o += (size_t)NN * 128 * 2;   // a2h overlay
    ushort* tsl  = (ushort*)(base + o); o += (size_t)NN * 128 * 2;   // a2l overlay
    ushort* xhi  = (ushort*)(base + o); o += (size_t)NN * 128 * 2;
    ushort* xlo  = (ushort*)(base + o); o += (size_t)NN * 128 * 2;
    int*    eids = (int*)(base + o);    o += (size_t)(EE + NN) * 4;
    int*    offs = (int*)(base + o);    o += (size_t)(NN + 16) * 4;
    int*    cursor=(int*)(base + o);    o += (size_t)NN * 4;
    float*  as_  = (float*)(base + o);  o += (size_t)NN * 4;
    float*  ad_  = (float*)(base + o);  o += (size_t)NN * 4;
    float*  dinv = (float*)(base + o);  o += (size_t)NN * 4;
    int*    bsum = (int*)(base + o);    o += 256 * 4;
    int*    boffs= (int*)(base + o);    o += 256 * 4;
    // --- zero-init region: degA, sums, sumsq (contiguous) ---
    int*    degA = (int*)(base + o);    o += (size_t)NN * 4;
    float*  sums = (float*)(base + o);  o += C3 * 4;
    float*  sumsq= (float*)(base + o);  o += C3 * 4;
    // --- end zero region ---
    float*  scale= (float*)(base + o);  o += C3 * 4;
    float*  shift= (float*)(base + o);  o += C3 * 4;
    float*  w_as = (float*)(base + o);  o += 128 * 4;
    float*  w_ad = (float*)(base + o);  o += 128 * 4;
    ushort* btg_h = (ushort*)(base + o); o += 128 * 128 * 2;
    ushort* btg_l = (ushort*)(base + o); o += 128 * 128 * 2;
    ushort* btc_h = (ushort*)(base + o); o += 128 * 128 * 2;
    ushort* btc_l = (ushort*)(base + o); o += 128 * 128 * 2;
    ushort* btsg_h= (ushort*)(base + o); o += 128 * 256 * 2;
    ushort* btsg_l= (ushort*)(base + o); o += 128 * 256 * 2;
    ushort* bt1_h = (ushort*)(base + o); o += 256 * 384 * 2;
    ushort* bt1_l = (ushort*)(base + o); o += 256 * 384 * 2;
    ushort* bt2_h = (ushort*)(base + o); o += 128 * 256 * 2;
    ushort* bt2_l = (ushort*)(base + o); o += 128 * 256 * 2;
    ushort* bt3_h = (ushort*)(base + o); o += 48 * 128 * 2;
    ushort* bt3_l = (ushort*)(base + o); o += 48 * 128 * 2;
    // overlays (temporally disjoint with t*/x buffers)
    ushort* a1h = tgh;                       // NN*256 ushorts
    ushort* a1l = tch;                       // NN*256 ushorts
    ushort* a2h = tsh;                       // NN*128
    ushort* a2l = tsl;                       // NN*128

    hipMemsetAsync(degA, 0, (size_t)NN * 4 + 2 * C3 * 4, stream);

    // ---- weight prep ----
    k_att_w<<<1, 128, 0, stream>>>(W_gat, att_src, att_dst, w_as, w_ad);
    k_splitw_all<<<816, 256, 0, stream>>>(W_gat, W_gcn, W_sage_l, W_sage_r, W1, W2, W3,
        btg_h, btg_l, btc_h, btc_l, btsg_h, btsg_l, bt1_h, bt1_l, bt2_h, bt2_l, bt3_h, bt3_l);
    k_split_x_att<<<(NN + 3) / 4, 256, 0, stream>>>(x, w_as, w_ad, xhi, xlo, as_, ad_);

    // ---- CSR build (hierarchical scan) ----
    k_edge1<<<(EE + 255) / 256, 256, 0, stream>>>(e_dst, degA);
    k_scan_part<<<SC_BLKS, 256, 0, stream>>>(degA, bsum);
    k_scan_tops<<<1, 128, 0, stream>>>(bsum, boffs);
    k_scan_apply<<<SC_BLKS, 256, 0, stream>>>(degA, boffs, offs, cursor, dinv);
    k_csr_fill<<<(EE + NN + 255) / 256, 256, 0, stream>>>(e_dst, cursor, eids);

    // ---- gather: softmax in-wave + weighted x sums ----
    k_gather<<<(NN + 3) / 4, 256, 0, stream>>>(
        e_src, eids, offs, as_, ad_, dinv, x, tgh, tgl, tch, tcl, tsh, tsl);

    // ---- producers (with fused BN stats) ----
    dim3 gg((NN + 127) / 128, 1);
    k_gemm2<8, 1><<<gg, 256, 0, stream>>>(tgh, tgl, 128, tgh, tgl, 128,
        btg_h, btg_l, NN, 1, b_gat, sums, sumsq,
        nullptr, 0, hch, hcl, C3, 128);
    k_gemm2<8, 1><<<gg, 256, 0, stream>>>(tch, tcl, 128, tch, tcl, 128,
        btc_h, btc_l, NN, 1, b_gcn, sums + 128, sumsq + 128,
        nullptr, 0, hch + 128, hcl + 128, C3, 128);
    k_gemm2<8, 2><<<gg, 256, 0, stream>>>(tsh, tsl, 128, xhi, xlo, 128,
        btsg_h, btsg_l, NN, 1, b_sage_l, sums + 256, sumsq + 256,
        nullptr, 0, hch + 256, hcl + 256, C3, 128);

    // ---- BN fold + in-place transform ----
    k_bn_final<<<1, C3, 0, stream>>>(sums, sumsq, gamma, beta, scale, shift);
    k_bnrelu<<<(NN * 192 + 255) / 256, 256, 0, stream>>>(hch, hcl, scale, shift);

    // ---- MLP ----
    dim3 g1((NN + 127) / 128, 2);
    k_gemm2<8, 3><<<g1, 256, 0, stream>>>(hch, hcl, 384, hch, hcl, 384,
        bt1_h, bt1_l, NN, 0, b1, nullptr, nullptr,
        nullptr, 0, a1h, a1l, 256, 256);
    k_gemm2<8, 2><<<gg, 256, 0, stream>>>(a1h, a1l, 256, a1h, a1l, 256,
        bt2_h, bt2_l, NN, 0, b2, nullptr, nullptr,
        nullptr, 0, a2h, a2l, 128, 128);
    k_gemm2<3, 1><<<gg, 256, 0, stream>>>(a2h, a2l, 128, a2h, a2l, 128,
        bt3_h, bt3_l, NN, 2, b3, nullptr, nullptr,
        (float*)d_out, NOUT, nullptr, nullptr, 0, NOUT);
}

// Round 9
// 638.766 us; speedup vs baseline: 5.0561x; 1.1254x over previous
//
#include <hip/hip_runtime.h>
#include <cstdint>
#include <cstddef>

#define NN   50000
#define FIN  128
#define HD   128
#define EE   800000
#define C3   384   // 3*H
#define NOUT 40

// hierarchical scan geometry
#define SC_ELEMS 512
#define SC_BLKS  ((NN + SC_ELEMS - 1) / SC_ELEMS)   // 98

typedef __attribute__((ext_vector_type(8))) short s8v;   // 8 x bf16 (4 VGPR)
typedef __attribute__((ext_vector_type(4))) float f4v;   // MFMA acc

typedef const __attribute__((address_space(1))) unsigned int* guintp;
typedef __attribute__((address_space(3))) unsigned int* luintp;

static __device__ __forceinline__ void async_copy16(const void* g, void* l) {
    __builtin_amdgcn_global_load_lds((guintp)g, (luintp)l, 16, 0, 0);
}

// ---------- bf16 helpers ----------
static __device__ __forceinline__ float b2f(ushort u) {
    return __uint_as_float((unsigned)u << 16);
}
static __device__ __forceinline__ ushort f2b(float v) {
    unsigned u = __float_as_uint(v);
    unsigned r = u + 0x7fffu + ((u >> 16) & 1u);
    return (ushort)(r >> 16);
}
static __device__ __forceinline__ void bsplit(float v, ushort& h, ushort& l) {
    h = f2b(v);
    float hf = b2f(h);
    l = f2b(v - hf);
}

// ---------- merged: split x -> bf16 hi/lo AND attention dots ----------
__global__ __launch_bounds__(256) void k_split_x_att(
    const float* __restrict__ x,
    const float* __restrict__ w_as, const float* __restrict__ w_ad,
    ushort* __restrict__ xh, ushort* __restrict__ xl,
    float* __restrict__ a_s, float* __restrict__ a_d)
{
    int node = blockIdx.x * 4 + (threadIdx.x >> 6);
    if (node >= NN) return;
    int lane = threadIdx.x & 63;
    size_t o = (size_t)node * 128 + lane * 2;
    float2 v  = *(const float2*)(x + o);
    ushort hx, lx, hy, ly;
    bsplit(v.x, hx, lx); bsplit(v.y, hy, ly);
    { ushort2 u; u.x = hx; u.y = hy; *(ushort2*)(xh + o) = u; }
    { ushort2 u; u.x = lx; u.y = ly; *(ushort2*)(xl + o) = u; }
    float2 w1 = *(const float2*)(w_as + lane * 2);
    float2 w2 = *(const float2*)(w_ad + lane * 2);
    float s1 = v.x * w1.x + v.y * w1.y;
    float s2 = v.x * w2.x + v.y * w2.y;
    #pragma unroll
    for (int off = 32; off; off >>= 1) {
        s1 += __shfl_down(s1, off);
        s2 += __shfl_down(s2, off);
    }
    if (lane == 0) { a_s[node] = s1; a_d[node] = s2; }
}

// ---------- all weight splits+transposes + att fold in one launch ----------
// blocks [0,816): weight split rows; block 816: w_as/w_ad fold
__global__ void k_splitw_all(
    const float* __restrict__ Wg, const float* __restrict__ Wc,
    const float* __restrict__ Wl, const float* __restrict__ Wr,
    const float* __restrict__ W1, const float* __restrict__ W2,
    const float* __restrict__ W3,
    const float* __restrict__ asv, const float* __restrict__ adv,
    float* __restrict__ w_as, float* __restrict__ w_ad,
    ushort* __restrict__ btg_h, ushort* __restrict__ btg_l,
    ushort* __restrict__ btc_h, ushort* __restrict__ btc_l,
    ushort* __restrict__ btsg_h, ushort* __restrict__ btsg_l,
    ushort* __restrict__ bt1_h, ushort* __restrict__ bt1_l,
    ushort* __restrict__ bt2_h, ushort* __restrict__ bt2_l,
    ushort* __restrict__ bt3_h, ushort* __restrict__ bt3_l)
{
    int ry = blockIdx.x;
    int t = threadIdx.x;
    if (ry == 816) {
        if (t < 128) {
            float s1 = 0.f, s2 = 0.f;
            for (int j = 0; j < 128; ++j) {
                float w = Wg[t * 128 + j];
                s1 += w * asv[j];
                s2 += w * adv[j];
            }
            w_as[t] = s1; w_ad[t] = s2;
        }
        return;
    }
    const float* W = nullptr; ushort* dh; ushort* dl; int K, Nw, n;
    bool sage = false;
    if (ry < 128)      { n = ry;       K = 128; Nw = 128; W = Wg; dh = btg_h; dl = btg_l; }
    else if (ry < 256) { n = ry - 128; K = 128; Nw = 128; W = Wc; dh = btc_h; dl = btc_l; }
    else if (ry < 384) { n = ry - 256; K = 256; Nw = 128; sage = true; dh = btsg_h; dl = btsg_l; }
    else if (ry < 640) { n = ry - 384; K = 384; Nw = 256; W = W1; dh = bt1_h; dl = bt1_l; }
    else if (ry < 768) { n = ry - 640; K = 256; Nw = 128; W = W2; dh = bt2_h; dl = bt2_l; }
    else               { n = ry - 768; K = 128; Nw = 40;  W = W3; dh = bt3_h; dl = bt3_l; }
    for (int k = t; k < K; k += 256) {
        float v;
        if (sage) v = (k < 128) ? Wl[(size_t)k * 128 + n] : Wr[(size_t)(k - 128) * 128 + n];
        else      v = (n < Nw) ? W[(size_t)k * Nw + n] : 0.f;
        ushort h, l; bsplit(v, h, l);
        dh[(size_t)n * K + k] = h;
        dl[(size_t)n * K + k] = l;
    }
}

// ---------- MFMA split-bf16 GEMM, 32KB half-chunk LDS staging ----------
// AX=0: blockIdx.x=rows, blockIdx.y=cols. AX=1: swapped (col-blocks dispatch-
// adjacent -> 2nd col-block L2-hits the same A rows).
// mode 0: relu(acc+bias) -> split store; mode 2: acc+bias -> fp32, cols<colmax
template<int NT, int NCH, int AX>
__global__ __launch_bounds__(256, 4) void k_gemm2(
    const ushort* __restrict__ A1h, const ushort* __restrict__ A1l, int K1,
    const ushort* __restrict__ A2h, const ushort* __restrict__ A2l, int K2,
    const ushort* __restrict__ Bth, const ushort* __restrict__ Btl,
    int M, int mode,
    const float* __restrict__ bias,
    float* __restrict__ Cf, int ldc,
    ushort* __restrict__ Chi, ushort* __restrict__ Clo, int ldch,
    int colmax)
{
    constexpr int COLS = NT * 16;
    constexpr int HOPU = 8 * COLS;       // 16B-units per operand per 64-k half
    constexpr int ISS  = (2 * HOPU) / 256;
    constexpr int KTOT = NCH * 128;
    constexpr int NK   = NCH * 4;

    __shared__ __align__(16) ushort Bs[2 * HOPU * 8];   // 32 KB @ NT=8

    const int lane = threadIdx.x & 63;
    const int wave = threadIdx.x >> 6;
    const int quad = lane >> 4;
    const int ln15 = lane & 15;
    const int brow = AX ? blockIdx.y : blockIdx.x;
    const int bcol = AX ? blockIdx.x : blockIdx.y;
    const int row0 = (brow * 4 + wave) * 32;
    const int col0 = bcol * COLS;

    int r0 = row0 + ln15;        if (r0 > M - 1) r0 = M - 1;
    int r1 = row0 + 16 + ln15;   if (r1 > M - 1) r1 = M - 1;

    auto stage = [&](int c, int h) {
        #pragma unroll
        for (int i = 0; i < ISS; ++i) {
            int u0 = (wave * ISS + i) * 64;
            int u  = u0 + lane;
            int op = u / HOPU;
            int rem = u - op * HOPU;
            int kq  = rem / COLS;
            int col = rem - kq * COLS;
            int kk  = c * 128 + h * 64 + kq * 8;
            const ushort* spt = op ? Btl : Bth;
            const ushort* gp = spt + (size_t)(col0 + col) * KTOT + kk;
            async_copy16(gp, (char*)Bs + (size_t)u0 * 16);
        }
    };
    auto loadA = [&](int kk, s8v& h0, s8v& l0, s8v& h1, s8v& l1) {
        const ushort* ah; const ushort* al; size_t o0, o1;
        if (kk < K1) { ah = A1h; al = A1l; o0 = (size_t)r0 * K1 + kk; o1 = (size_t)r1 * K1 + kk; }
        else { ah = A2h; al = A2l; int k2 = kk - K1; o0 = (size_t)r0 * K2 + k2; o1 = (size_t)r1 * K2 + k2; }
        int q8 = quad * 8;
        h0 = *(const s8v*)(ah + o0 + q8);
        l0 = *(const s8v*)(al + o0 + q8);
        h1 = *(const s8v*)(ah + o1 + q8);
        l1 = *(const s8v*)(al + o1 + q8);
    };

    f4v acc[2][NT] = {};
    s8v cah0, cal0, cah1, cal1, nah0, nal0, nah1, nal1;

    stage(0, 0);
    loadA(0, cah0, cal0, cah1, cal1);
    __syncthreads();

    #pragma unroll
    for (int c = 0; c < NCH; ++c) {
        #pragma unroll
        for (int h = 0; h < 2; ++h) {
            #pragma unroll
            for (int jj = 0; jj < 2; ++jj) {
                int kj = c * 4 + h * 2 + jj;
                int nk = (kj + 1 < NK) ? (kj + 1) * 32 : 0;   // last: dummy
                loadA(nk, nah0, nal0, nah1, nal1);
                #pragma unroll
                for (int t = 0; t < NT; ++t) {
                    int ub = (jj * 4 + quad) * COLS + t * 16 + ln15;
                    s8v bh = *(const s8v*)(Bs + (size_t)ub * 8);
                    s8v bl = *(const s8v*)(Bs + (size_t)(HOPU + ub) * 8);
                    acc[0][t] = __builtin_amdgcn_mfma_f32_16x16x32_bf16(cah0, bh, acc[0][t], 0, 0, 0);
                    acc[1][t] = __builtin_amdgcn_mfma_f32_16x16x32_bf16(cah1, bh, acc[1][t], 0, 0, 0);
                    acc[0][t] = __builtin_amdgcn_mfma_f32_16x16x32_bf16(cah0, bl, acc[0][t], 0, 0, 0);
                    acc[1][t] = __builtin_amdgcn_mfma_f32_16x16x32_bf16(cah1, bl, acc[1][t], 0, 0, 0);
                    acc[0][t] = __builtin_amdgcn_mfma_f32_16x16x32_bf16(cal0, bh, acc[0][t], 0, 0, 0);
                    acc[1][t] = __builtin_amdgcn_mfma_f32_16x16x32_bf16(cal1, bh, acc[1][t], 0, 0, 0);
                }
                cah0 = nah0; cal0 = nal0; cah1 = nah1; cal1 = nal1;
            }
            if (!(c == NCH - 1 && h == 1)) {
                __syncthreads();
                int nc = c, nh = h + 1;
                if (nh == 2) { nh = 0; ++nc; }
                stage(nc, nh);
                __syncthreads();
            }
        }
    }

    #pragma unroll
    for (int t = 0; t < NT; ++t) {
        int cc = col0 + t * 16 + ln15;
        #pragma unroll
        for (int mt = 0; mt < 2; ++mt) {
            #pragma unroll
            for (int r = 0; r < 4; ++r) {
                int rr = row0 + mt * 16 + quad * 4 + r;
                bool ok = (rr < M);
                float v = acc[mt][t][r];
                if (mode == 0) {
                    v += bias[cc];
                    v = v > 0.f ? v : 0.f;
                    if (ok) {
                        ushort h, l; bsplit(v, h, l);
                        Chi[(size_t)rr * ldch + cc] = h;
                        Clo[(size_t)rr * ldch + cc] = l;
                    }
                } else {
                    if (ok && cc < colmax) Cf[(size_t)rr * ldc + cc] = v + bias[cc];
                }
            }
        }
    }
}

// ---------- merged producer GEMMs: z=0 GAT, z=1 GCN, z=2 SAGE ----------
// All: 128 cols, split store into hcat cols [z*128, z*128+128), fused BN stats.
__global__ __launch_bounds__(256, 4) void k_gemm_prod(
    const ushort* __restrict__ tgh, const ushort* __restrict__ tgl,
    const ushort* __restrict__ tch, const ushort* __restrict__ tcl,
    const ushort* __restrict__ tsh, const ushort* __restrict__ tsl,
    const ushort* __restrict__ xhi, const ushort* __restrict__ xlo,
    const ushort* __restrict__ btg_h, const ushort* __restrict__ btg_l,
    const ushort* __restrict__ btc_h, const ushort* __restrict__ btc_l,
    const ushort* __restrict__ btsg_h, const ushort* __restrict__ btsg_l,
    const float* __restrict__ bg, const float* __restrict__ bc,
    const float* __restrict__ bsl,
    float* __restrict__ sums, float* __restrict__ sumsq,
    ushort* __restrict__ hch, ushort* __restrict__ hcl)
{
    constexpr int COLS = 128;
    constexpr int HOPU = 8 * COLS;      // 1024 units/op per 64-k half
    constexpr int ISS  = (2 * HOPU) / 256;
    __shared__ __align__(16) ushort Bs[2 * HOPU * 8];   // 32 KB

    const int z = blockIdx.z;
    const ushort* A1h = (z == 0) ? tgh : (z == 1) ? tch : tsh;
    const ushort* A1l = (z == 0) ? tgl : (z == 1) ? tcl : tsl;
    const ushort* Bth = (z == 0) ? btg_h : (z == 1) ? btc_h : btsg_h;
    const ushort* Btl = (z == 0) ? btg_l : (z == 1) ? btc_l : btsg_l;
    const float*  bias = (z == 0) ? bg : (z == 1) ? bc : bsl;
    const int nch = (z == 2) ? 2 : 1;
    const int ktot = nch * 128;
    const int nk = nch * 4;

    const int lane = threadIdx.x & 63;
    const int wave = threadIdx.x >> 6;
    const int quad = lane >> 4;
    const int ln15 = lane & 15;
    const int row0 = (blockIdx.x * 4 + wave) * 32;

    int r0 = row0 + ln15;        if (r0 > NN - 1) r0 = NN - 1;
    int r1 = row0 + 16 + ln15;   if (r1 > NN - 1) r1 = NN - 1;

    auto stage = [&](int c, int h) {
        #pragma unroll
        for (int i = 0; i < ISS; ++i) {
            int u0 = (wave * ISS + i) * 64;
            int u  = u0 + lane;
            int op = u / HOPU;
            int rem = u - op * HOPU;
            int kq  = rem / COLS;
            int col = rem - kq * COLS;
            int kk  = c * 128 + h * 64 + kq * 8;
            const ushort* spt = op ? Btl : Bth;
            const ushort* gp = spt + (size_t)col * ktot + kk;
            async_copy16(gp, (char*)Bs + (size_t)u0 * 16);
        }
    };
    auto loadA = [&](int kk, s8v& h0, s8v& l0, s8v& h1, s8v& l1) {
        const ushort* ah; const ushort* al; size_t o0, o1;
        if (kk < 128) { ah = A1h; al = A1l; o0 = (size_t)r0 * 128 + kk; o1 = (size_t)r1 * 128 + kk; }
        else { ah = xhi; al = xlo; int k2 = kk - 128; o0 = (size_t)r0 * 128 + k2; o1 = (size_t)r1 * 128 + k2; }
        int q8 = quad * 8;
        h0 = *(const s8v*)(ah + o0 + q8);
        l0 = *(const s8v*)(al + o0 + q8);
        h1 = *(const s8v*)(ah + o1 + q8);
        l1 = *(const s8v*)(al + o1 + q8);
    };

    f4v acc[2][8] = {};
    s8v cah0, cal0, cah1, cal1, nah0, nal0, nah1, nal1;

    stage(0, 0);
    loadA(0, cah0, cal0, cah1, cal1);
    __syncthreads();

    for (int c = 0; c < nch; ++c) {
        for (int h = 0; h < 2; ++h) {
            for (int jj = 0; jj < 2; ++jj) {
                int kj = c * 4 + h * 2 + jj;
                int nkk = (kj + 1 < nk) ? (kj + 1) * 32 : 0;
                loadA(nkk, nah0, nal0, nah1, nal1);
                #pragma unroll
                for (int t = 0; t < 8; ++t) {
                    int ub = (jj * 4 + quad) * COLS + t * 16 + ln15;
                    s8v bh = *(const s8v*)(Bs + (size_t)ub * 8);
                    s8v bl = *(const s8v*)(Bs + (size_t)(HOPU + ub) * 8);
                    acc[0][t] = __builtin_amdgcn_mfma_f32_16x16x32_bf16(cah0, bh, acc[0][t], 0, 0, 0);
                    acc[1][t] = __builtin_amdgcn_mfma_f32_16x16x32_bf16(cah1, bh, acc[1][t], 0, 0, 0);
                    acc[0][t] = __builtin_amdgcn_mfma_f32_16x16x32_bf16(cah0, bl, acc[0][t], 0, 0, 0);
                    acc[1][t] = __builtin_amdgcn_mfma_f32_16x16x32_bf16(cah1, bl, acc[1][t], 0, 0, 0);
                    acc[0][t] = __builtin_amdgcn_mfma_f32_16x16x32_bf16(cal0, bh, acc[0][t], 0, 0, 0);
                    acc[1][t] = __builtin_amdgcn_mfma_f32_16x16x32_bf16(cal1, bh, acc[1][t], 0, 0, 0);
                }
                cah0 = nah0; cal0 = nal0; cah1 = nah1; cal1 = nal1;
            }
            if (!(c == nch - 1 && h == 1)) {
                __syncthreads();
                int nc = c, nh = h + 1;
                if (nh == 2) { nh = 0; ++nc; }
                stage(nc, nh);
                __syncthreads();
            }
        }
    }

    #pragma unroll
    for (int t = 0; t < 8; ++t) {
        int cc = t * 16 + ln15;            // local col in [0,128)
        int gc = z * 128 + cc;             // hcat column
        float sp = 0.f, qp = 0.f;
        #pragma unroll
        for (int mt = 0; mt < 2; ++mt) {
            #pragma unroll
            for (int r = 0; r < 4; ++r) {
                int rr = row0 + mt * 16 + quad * 4 + r;
                if (rr >= NN) continue;
                float v = acc[mt][t][r] + bias[cc];
                ushort h, l; bsplit(v, h, l);
                hch[(size_t)rr * C3 + gc] = h;
                hcl[(size_t)rr * C3 + gc] = l;
                sp += v; qp += v * v;
            }
        }
        sp += __shfl_xor(sp, 16); sp += __shfl_xor(sp, 32);
        qp += __shfl_xor(qp, 16); qp += __shfl_xor(qp, 32);
        if (quad == 0) {
            unsafeAtomicAdd(&sums[gc], sp);
            unsafeAtomicAdd(&sumsq[gc], qp);
        }
    }
}

// ---------- edge pass: dst-degree histogram (real edges only) ----------
__global__ void k_edge1(const int* __restrict__ dst, int* __restrict__ degA)
{
    int gid = blockIdx.x * blockDim.x + threadIdx.x;
    if (gid >= EE) return;
    atomicAdd(&degA[dst[gid]], 1);
}

// ---------- hierarchical exclusive scan over (degA[i]+1) ----------
__global__ __launch_bounds__(256) void k_scan_part(
    const int* __restrict__ degA, int* __restrict__ bsum)
{
    int t = threadIdx.x;
    int b0 = blockIdx.x * SC_ELEMS;
    int i0 = b0 + t * 2;
    int v0 = (i0 < NN)     ? degA[i0] + 1     : 0;
    int v1 = (i0 + 1 < NN) ? degA[i0 + 1] + 1 : 0;
    int s = v0 + v1;
    #pragma unroll
    for (int off = 32; off; off >>= 1) s += __shfl_down(s, off);
    __shared__ int ws[4];
    if ((t & 63) == 0) ws[t >> 6] = s;
    __syncthreads();
    if (t == 0) bsum[blockIdx.x] = ws[0] + ws[1] + ws[2] + ws[3];
}

__global__ __launch_bounds__(128) void k_scan_tops(
    const int* __restrict__ bsum, int* __restrict__ boffs)
{
    __shared__ int sh[128];
    int t = threadIdx.x;
    int v = (t < SC_BLKS) ? bsum[t] : 0;
    sh[t] = v;
    __syncthreads();
    for (int off = 1; off < 128; off <<= 1) {
        int u = (t >= off) ? sh[t - off] : 0;
        __syncthreads();
        sh[t] += u;
        __syncthreads();
    }
    if (t < SC_BLKS) boffs[t] = sh[t] - v;   // exclusive
    if (t == SC_BLKS - 1) boffs[SC_BLKS] = sh[t];
}

// phase 3: OOB elements contribute 0 (R6 bug fixed in R7, kept)
__global__ __launch_bounds__(256) void k_scan_apply(
    const int* __restrict__ degA, const int* __restrict__ boffs,
    int* __restrict__ offs, int* __restrict__ cursor,
    float* __restrict__ dinv)
{
    __shared__ int sh[256];
    int t = threadIdx.x;
    int b0 = blockIdx.x * SC_ELEMS;
    int i0 = b0 + t * 2;
    int v0 = (i0 < NN)     ? degA[i0] + 1     : 0;
    int v1 = (i0 + 1 < NN) ? degA[i0 + 1] + 1 : 0;
    int pair = v0 + v1;
    sh[t] = pair;
    __syncthreads();
    for (int off = 1; off < 256; off <<= 1) {
        int u = (t >= off) ? sh[t - off] : 0;
        __syncthreads();
        sh[t] += u;
        __syncthreads();
    }
    int excl = sh[t] - pair + boffs[blockIdx.x];
    if (i0 < NN) {
        offs[i0] = excl; cursor[i0] = excl;
        dinv[i0] = rsqrtf((float)v0);
    }
    if (i0 + 1 < NN) {
        offs[i0 + 1] = excl + v0; cursor[i0 + 1] = excl + v0;
        dinv[i0 + 1] = rsqrtf((float)v1);
    }
    if (blockIdx.x == SC_BLKS - 1 && t == 255) offs[NN] = excl + pair;
}

__global__ void k_csr_fill(const int* __restrict__ dst, int* __restrict__ cursor,
                           int* __restrict__ eids)
{
    int gid = blockIdx.x * blockDim.x + threadIdx.x;
    if (gid >= EE + NN) return;
    int d = (gid < EE) ? dst[gid] : (gid - EE);
    int slot = atomicAdd(&cursor[d], 1);
    eids[slot] = gid;
}

// ---------- CSR gather with in-wave softmax (max + denom) ----------
__global__ __launch_bounds__(256) void k_gather(
    const int* __restrict__ src,
    const int* __restrict__ eids, const int* __restrict__ offs,
    const float* __restrict__ a_s, const float* __restrict__ a_d,
    const float* __restrict__ dinv,
    const float* __restrict__ x,
    ushort* __restrict__ tgh, ushort* __restrict__ tgl,
    ushort* __restrict__ tch, ushort* __restrict__ tcl,
    ushort* __restrict__ tsh, ushort* __restrict__ tsl)
{
    int d = blockIdx.x * 4 + (threadIdx.x >> 6);
    if (d >= NN) return;
    int lane = threadIdx.x & 63;
    int beg = offs[d], end = offs[d + 1];
    float ad = a_d[d], dd = dinv[d];

    int idx0 = beg + lane;
    bool v0 = idx0 < end;
    int s0 = d; float e0 = 0.f;
    if (v0) {
        int eid = eids[idx0];
        s0 = (eid < EE) ? src[eid] : d;
        float e = a_s[s0] + ad;
        e0 = (e > 0.f) ? e : 0.2f * e;
    }
    float m = v0 ? e0 : -3.0e38f;
    for (int base = beg + 64; base < end; base += 64) {
        int idx = base + lane;
        if (idx < end) {
            int eid = eids[idx];
            int s = (eid < EE) ? src[eid] : d;
            float e = a_s[s] + ad;
            e = (e > 0.f) ? e : 0.2f * e;
            m = fmaxf(m, e);
        }
    }
    #pragma unroll
    for (int off = 1; off < 64; off <<= 1) m = fmaxf(m, __shfl_xor(m, off));
    float den = v0 ? expf(e0 - m) : 0.f;
    for (int base = beg + 64; base < end; base += 64) {
        int idx = base + lane;
        if (idx < end) {
            int eid = eids[idx];
            int s = (eid < EE) ? src[eid] : d;
            float e = a_s[s] + ad;
            e = (e > 0.f) ? e : 0.2f * e;
            den += expf(e - m);
        }
    }
    #pragma unroll
    for (int off = 1; off < 64; off <<= 1) den += __shfl_xor(den, off);
    float rden = 1.f / den;

    float2 tg = {0.f, 0.f}, tc = {0.f, 0.f}, ts = {0.f, 0.f};
    int c = lane * 2;
    {
        float wg = v0 ? expf(e0 - m) * rden : 0.f;
        float wc = v0 ? dinv[s0] * dd : 0.f;
        int cnt = end - beg; if (cnt > 64) cnt = 64;
        for (int j = 0; j < cnt; ++j) {
            int   sj  = __shfl(s0, j);
            float wgj = __shfl(wg, j);
            float wcj = __shfl(wc, j);
            const float2 xv = *(const float2*)(x + (size_t)sj * 128 + c);
            tg.x += wgj * xv.x; tg.y += wgj * xv.y;
            tc.x += wcj * xv.x; tc.y += wcj * xv.y;
            ts.x += xv.x;       ts.y += xv.y;
        }
    }
    for (int base = beg + 64; base < end; base += 64) {
        int idx = base + lane;
        int s = d; float wg = 0.f, wc = 0.f;
        if (idx < end) {
            int eid = eids[idx];
            s = (eid < EE) ? src[eid] : d;
            float e = a_s[s] + ad;
            e = (e > 0.f) ? e : 0.2f * e;
            wg = expf(e - m) * rden;
            wc = dinv[s] * dd;
        }
        int cnt = end - base; if (cnt > 64) cnt = 64;
        for (int j = 0; j < cnt; ++j) {
            int   sj  = __shfl(s, j);
            float wgj = __shfl(wg, j);
            float wcj = __shfl(wc, j);
            const float2 xv = *(const float2*)(x + (size_t)sj * 128 + c);
            tg.x += wgj * xv.x; tg.y += wgj * xv.y;
            tc.x += wcj * xv.x; tc.y += wcj * xv.y;
            ts.x += xv.x;       ts.y += xv.y;
        }
    }
    const float2 xd = *(const float2*)(x + (size_t)d * 128 + c);
    ts.x -= xd.x; ts.y -= xd.y;
    int cs = (end - beg) - 1;
    float rc = 1.f / (float)(cs > 1 ? cs : 1);
    ts.x *= rc; ts.y *= rc;

    size_t row = (size_t)d * 128 + c;
    ushort h0, l0, h1, l1;
    bsplit(tg.x, h0, l0); bsplit(tg.y, h1, l1);
    { ushort2 u; u.x = h0; u.y = h1; *(ushort2*)(tgh + row) = u; }
    { ushort2 u; u.x = l0; u.y = l1; *(ushort2*)(tgl + row) = u; }
    bsplit(tc.x, h0, l0); bsplit(tc.y, h1, l1);
    { ushort2 u; u.x = h0; u.y = h1; *(ushort2*)(tch + row) = u; }
    { ushort2 u; u.x = l0; u.y = l1; *(ushort2*)(tcl + row) = u; }
    bsplit(ts.x, h0, l0); bsplit(ts.y, h1, l1);
    { ushort2 u; u.x = h0; u.y = h1; *(ushort2*)(tsh + row) = u; }
    { ushort2 u; u.x = l0; u.y = l1; *(ushort2*)(tsl + row) = u; }
}

__global__ void k_bn_final(const float* __restrict__ sums, const float* __restrict__ sumsq,
                           const float* __restrict__ gamma, const float* __restrict__ beta,
                           float* __restrict__ scale, float* __restrict__ shift)
{
    int j = threadIdx.x;
    if (j >= C3) return;
    const float rn = 1.f / (float)NN;
    float mu  = sums[j] * rn;
    float var = sumsq[j] * rn - mu * mu;
    float sc  = gamma[j] * rsqrtf(var + 1e-5f);
    scale[j] = sc;
    shift[j] = beta[j] - mu * sc;
}

// ---------- in-place BN+relu of split hcat (flat over NN*192 pairs) ----------
__global__ __launch_bounds__(256) void k_bnrelu(
    ushort* __restrict__ hch, ushort* __restrict__ hcl,
    const float* __restrict__ scale, const float* __restrict__ shift)
{
    int p = blockIdx.x * blockDim.x + threadIdx.x;
    if (p >= NN * 192) return;
    int cpair = p % 192;
    int cidx = cpair * 2;
    size_t o = (size_t)p * 2;
    ushort2 h = *(ushort2*)(hch + o);
    ushort2 l = *(ushort2*)(hcl + o);
    float v0 = b2f(h.x) + b2f(l.x);
    float v1 = b2f(h.y) + b2f(l.y);
    v0 = v0 * scale[cidx] + shift[cidx];         v0 = v0 > 0.f ? v0 : 0.f;
    v1 = v1 * scale[cidx + 1] + shift[cidx + 1]; v1 = v1 > 0.f ? v1 : 0.f;
    ushort h0, l0, h1, l1;
    bsplit(v0, h0, l0); bsplit(v1, h1, l1);
    { ushort2 u; u.x = h0; u.y = h1; *(ushort2*)(hch + o) = u; }
    { ushort2 u; u.x = l0; u.y = l1; *(ushort2*)(hcl + o) = u; }
}

extern "C" void kernel_launch(void* const* d_in, const int* in_sizes, int n_in,
                              void* d_out, int out_size, void* d_ws, size_t ws_size,
                              hipStream_t stream) {
    const float* x        = (const float*)d_in[0];
    const int*   ei       = (const int*)d_in[1];
    const float* W_gat    = (const float*)d_in[2];
    const float* att_src  = (const float*)d_in[3];
    const float* att_dst  = (const float*)d_in[4];
    const float* b_gat    = (const float*)d_in[5];
    const float* W_gcn    = (const float*)d_in[6];
    const float* b_gcn    = (const float*)d_in[7];
    const float* W_sage_l = (const float*)d_in[8];
    const float* b_sage_l = (const float*)d_in[9];
    const float* W_sage_r = (const float*)d_in[10];
    const float* W1       = (const float*)d_in[11];
    const float* b1       = (const float*)d_in[12];
    const float* W2       = (const float*)d_in[13];
    const float* b2       = (const float*)d_in[14];
    const float* W3       = (const float*)d_in[15];
    const float* b3       = (const float*)d_in[16];
    const float* gamma    = (const float*)d_in[17];
    const float* beta     = (const float*)d_in[18];

    const int* e_src = ei;
    const int* e_dst = ei + EE;

    // ---- workspace layout (all offsets 16B-aligned) ----
    char* base = (char*)d_ws;
    size_t o = 0;
    ushort* hch  = (ushort*)(base + o); o += (size_t)NN * C3 * 2;
    ushort* hcl  = (ushort*)(base + o); o += (size_t)NN * C3 * 2;
    ushort* tgh  = (ushort*)(base + o); o += (size_t)NN * 128 * 2;   // a1h overlay
    ushort* tgl  = (ushort*)(base + o); o += (size_t)NN * 128 * 2;
    ushort* tch  = (ushort*)(base + o); o += (size_t)NN * 128 * 2;   // a1l overlay
    ushort* tcl  = (ushort*)(base + o); o += (size_t)NN * 128 * 2;
    ushort* tsh  = (ushort*)(base + o); o += (size_t)NN * 128 * 2;   // a2h overlay
    ushort* tsl  = (ushort*)(base + o); o += (size_t)NN * 128 * 2;   // a2l overlay
    ushort* xhi  = (ushort*)(base + o); o += (size_t)NN * 128 * 2;
    ushort* xlo  = (ushort*)(base + o); o += (size_t)NN * 128 * 2;
    int*    eids = (int*)(base + o);    o += (size_t)(EE + NN) * 4;
    int*    offs = (int*)(base + o);    o += (size_t)(NN + 16) * 4;
    int*    cursor=(int*)(base + o);    o += (size_t)NN * 4;
    float*  as_  = (float*)(base + o);  o += (size_t)NN * 4;
    float*  ad_  = (float*)(base + o);  o += (size_t)NN * 4;
    float*  dinv = (float*)(base + o);  o += (size_t)NN * 4;
    int*    bsum = (int*)(base + o);    o += 256 * 4;
    int*    boffs= (int*)(base + o);    o += 256 * 4;
    // --- zero-init region: degA, sums, sumsq (contiguous) ---
    int*    degA = (int*)(base + o);    o += (size_t)NN * 4;
    float*  sums = (float*)(base + o);  o += C3 * 4;
    float*  sumsq= (float*)(base + o);  o += C3 * 4;
    // --- end zero region ---
    float*  scale= (float*)(base + o);  o += C3 * 4;
    float*  shift= (float*)(base + o);  o += C3 * 4;
    float*  w_as = (float*)(base + o);  o += 128 * 4;
    float*  w_ad = (float*)(base + o);  o += 128 * 4;
    ushort* btg_h = (ushort*)(base + o); o += 128 * 128 * 2;
    ushort* btg_l = (ushort*)(base + o); o += 128 * 128 * 2;
    ushort* btc_h = (ushort*)(base + o); o += 128 * 128 * 2;
    ushort* btc_l = (ushort*)(base + o); o += 128 * 128 * 2;
    ushort* btsg_h= (ushort*)(base + o); o += 128 * 256 * 2;
    ushort* btsg_l= (ushort*)(base + o); o += 128 * 256 * 2;
    ushort* bt1_h = (ushort*)(base + o); o += 256 * 384 * 2;
    ushort* bt1_l = (ushort*)(base + o); o += 256 * 384 * 2;
    ushort* bt2_h = (ushort*)(base + o); o += 128 * 256 * 2;
    ushort* bt2_l = (ushort*)(base + o); o += 128 * 256 * 2;
    ushort* bt3_h = (ushort*)(base + o); o += 48 * 128 * 2;
    ushort* bt3_l = (ushort*)(base + o); o += 48 * 128 * 2;
    // overlays (temporally disjoint with t*/x buffers)
    ushort* a1h = tgh;                       // NN*256 ushorts
    ushort* a1l = tch;                       // NN*256 ushorts
    ushort* a2h = tsh;                       // NN*128
    ushort* a2l = tsl;                       // NN*128

    hipMemsetAsync(degA, 0, (size_t)NN * 4 + 2 * C3 * 4, stream);

    // ---- weight prep (att fold fused as block 816) ----
    k_splitw_all<<<817, 256, 0, stream>>>(W_gat, W_gcn, W_sage_l, W_sage_r, W1, W2, W3,
        att_src, att_dst, w_as, w_ad,
        btg_h, btg_l, btc_h, btc_l, btsg_h, btsg_l, bt1_h, bt1_l, bt2_h, bt2_l, bt3_h, bt3_l);
    k_split_x_att<<<(NN + 3) / 4, 256, 0, stream>>>(x, w_as, w_ad, xhi, xlo, as_, ad_);

    // ---- CSR build (hierarchical scan) ----
    k_edge1<<<(EE + 255) / 256, 256, 0, stream>>>(e_dst, degA);
    k_scan_part<<<SC_BLKS, 256, 0, stream>>>(degA, bsum);
    k_scan_tops<<<1, 128, 0, stream>>>(bsum, boffs);
    k_scan_apply<<<SC_BLKS, 256, 0, stream>>>(degA, boffs, offs, cursor, dinv);
    k_csr_fill<<<(EE + NN + 255) / 256, 256, 0, stream>>>(e_dst, cursor, eids);

    // ---- gather: softmax in-wave + weighted x sums ----
    k_gather<<<(NN + 3) / 4, 256, 0, stream>>>(
        e_src, eids, offs, as_, ad_, dinv, x, tgh, tgl, tch, tcl, tsh, tsl);

    // ---- producers: ONE launch, z in {GAT, GCN, SAGE}, fused BN stats ----
    k_gemm_prod<<<dim3((NN + 127) / 128, 1, 3), 256, 0, stream>>>(
        tgh, tgl, tch, tcl, tsh, tsl, xhi, xlo,
        btg_h, btg_l, btc_h, btc_l, btsg_h, btsg_l,
        b_gat, b_gcn, b_sage_l, sums, sumsq, hch, hcl);

    // ---- BN fold + in-place transform ----
    k_bn_final<<<1, C3, 0, stream>>>(sums, sumsq, gamma, beta, scale, shift);
    k_bnrelu<<<(NN * 192 + 255) / 256, 256, 0, stream>>>(hch, hcl, scale, shift);

    // ---- MLP ----
    // MLP1: col-blocks dispatch-adjacent (AX=1) so A rows are fetched once
    k_gemm2<8, 3, 1><<<dim3(2, (NN + 127) / 128), 256, 0, stream>>>(
        hch, hcl, 384, hch, hcl, 384, bt1_h, bt1_l, NN, 0, b1,
        nullptr, 0, a1h, a1l, 256, 256);
    k_gemm2<8, 2, 0><<<dim3((NN + 127) / 128, 1), 256, 0, stream>>>(
        a1h, a1l, 256, a1h, a1l, 256, bt2_h, bt2_l, NN, 0, b2,
        nullptr, 0, a2h, a2l, 128, 128);
    k_gemm2<3, 1, 0><<<dim3((NN + 127) / 128, 1), 256, 0, stream>>>(
        a2h, a2l, 128, a2h, a2l, 128, bt3_h, bt3_l, NN, 2, b3,
        (float*)d_out, NOUT, nullptr, nullptr, 0, NOUT);
}

// Round 10
// 573.750 us; speedup vs baseline: 5.6290x; 1.1133x over previous
//
#include <hip/hip_runtime.h>
#include <cstdint>
#include <cstddef>

#define NN   50000
#define FIN  128
#define HD   128
#define EE   800000
#define C3   384   // 3*H
#define NOUT 40

// hierarchical scan geometry
#define SC_ELEMS 512
#define SC_BLKS  ((NN + SC_ELEMS - 1) / SC_ELEMS)   // 98

typedef __attribute__((ext_vector_type(8))) short s8v;   // 8 x bf16 (4 VGPR)
typedef __attribute__((ext_vector_type(4))) float f4v;   // MFMA acc
typedef __attribute__((ext_vector_type(4))) unsigned int u4v;

typedef const __attribute__((address_space(1))) unsigned int* guintp;
typedef __attribute__((address_space(3))) unsigned int* luintp;

static __device__ __forceinline__ void async_copy16(const void* g, void* l) {
    __builtin_amdgcn_global_load_lds((guintp)g, (luintp)l, 16, 0, 0);
}

// ---------- bf16 helpers ----------
static __device__ __forceinline__ float b2f(ushort u) {
    return __uint_as_float((unsigned)u << 16);
}
static __device__ __forceinline__ ushort f2b(float v) {
    unsigned u = __float_as_uint(v);
    unsigned r = u + 0x7fffu + ((u >> 16) & 1u);
    return (ushort)(r >> 16);
}
static __device__ __forceinline__ void bsplit(float v, ushort& h, ushort& l) {
    h = f2b(v);
    float hf = b2f(h);
    l = f2b(v - hf);
}

// ---------- merged: split x -> bf16 hi/lo AND attention dots ----------
__global__ __launch_bounds__(256) void k_split_x_att(
    const float* __restrict__ x,
    const float* __restrict__ w_as, const float* __restrict__ w_ad,
    ushort* __restrict__ xh, ushort* __restrict__ xl,
    float* __restrict__ a_s, float* __restrict__ a_d)
{
    int node = blockIdx.x * 4 + (threadIdx.x >> 6);
    if (node >= NN) return;
    int lane = threadIdx.x & 63;
    size_t o = (size_t)node * 128 + lane * 2;
    float2 v  = *(const float2*)(x + o);
    ushort hx, lx, hy, ly;
    bsplit(v.x, hx, lx); bsplit(v.y, hy, ly);
    { ushort2 u; u.x = hx; u.y = hy; *(ushort2*)(xh + o) = u; }
    { ushort2 u; u.x = lx; u.y = ly; *(ushort2*)(xl + o) = u; }
    float2 w1 = *(const float2*)(w_as + lane * 2);
    float2 w2 = *(const float2*)(w_ad + lane * 2);
    float s1 = v.x * w1.x + v.y * w1.y;
    float s2 = v.x * w2.x + v.y * w2.y;
    #pragma unroll
    for (int off = 32; off; off >>= 1) {
        s1 += __shfl_down(s1, off);
        s2 += __shfl_down(s2, off);
    }
    if (lane == 0) { a_s[node] = s1; a_d[node] = s2; }
}

// ---------- all weight splits+transposes + att fold in one launch ----------
__global__ void k_splitw_all(
    const float* __restrict__ Wg, const float* __restrict__ Wc,
    const float* __restrict__ Wl, const float* __restrict__ Wr,
    const float* __restrict__ W1, const float* __restrict__ W2,
    const float* __restrict__ W3,
    const float* __restrict__ asv, const float* __restrict__ adv,
    float* __restrict__ w_as, float* __restrict__ w_ad,
    ushort* __restrict__ btg_h, ushort* __restrict__ btg_l,
    ushort* __restrict__ btc_h, ushort* __restrict__ btc_l,
    ushort* __restrict__ btsg_h, ushort* __restrict__ btsg_l,
    ushort* __restrict__ bt1_h, ushort* __restrict__ bt1_l,
    ushort* __restrict__ bt2_h, ushort* __restrict__ bt2_l,
    ushort* __restrict__ bt3_h, ushort* __restrict__ bt3_l)
{
    int ry = blockIdx.x;
    int t = threadIdx.x;
    if (ry == 816) {
        if (t < 128) {
            float s1 = 0.f, s2 = 0.f;
            for (int j = 0; j < 128; ++j) {
                float w = Wg[t * 128 + j];
                s1 += w * asv[j];
                s2 += w * adv[j];
            }
            w_as[t] = s1; w_ad[t] = s2;
        }
        return;
    }
    const float* W = nullptr; ushort* dh; ushort* dl; int K, Nw, n;
    bool sage = false;
    if (ry < 128)      { n = ry;       K = 128; Nw = 128; W = Wg; dh = btg_h; dl = btg_l; }
    else if (ry < 256) { n = ry - 128; K = 128; Nw = 128; W = Wc; dh = btc_h; dl = btc_l; }
    else if (ry < 384) { n = ry - 256; K = 256; Nw = 128; sage = true; dh = btsg_h; dl = btsg_l; }
    else if (ry < 640) { n = ry - 384; K = 384; Nw = 256; W = W1; dh = bt1_h; dl = bt1_l; }
    else if (ry < 768) { n = ry - 640; K = 256; Nw = 128; W = W2; dh = bt2_h; dl = bt2_l; }
    else               { n = ry - 768; K = 128; Nw = 40;  W = W3; dh = bt3_h; dl = bt3_l; }
    for (int k = t; k < K; k += 256) {
        float v;
        if (sage) v = (k < 128) ? Wl[(size_t)k * 128 + n] : Wr[(size_t)(k - 128) * 128 + n];
        else      v = (n < Nw) ? W[(size_t)k * Nw + n] : 0.f;
        ushort h, l; bsplit(v, h, l);
        dh[(size_t)n * K + k] = h;
        dl[(size_t)n * K + k] = l;
    }
}

// ---------- MFMA split-bf16 GEMM, 32KB half-chunk LDS staging ----------
// AX=1: grid axes swapped so col-blocks over same rows are dispatch-adjacent.
// mode 0: relu(acc+bias) -> split store (vectorized LDS-transpose epilogue)
// mode 2: acc+bias -> fp32, cols<colmax (scalar store)
template<int NT, int NCH, int AX>
__global__ __launch_bounds__(256, 4) void k_gemm2(
    const ushort* __restrict__ A1h, const ushort* __restrict__ A1l, int K1,
    const ushort* __restrict__ A2h, const ushort* __restrict__ A2l, int K2,
    const ushort* __restrict__ Bth, const ushort* __restrict__ Btl,
    int M, int mode,
    const float* __restrict__ bias,
    float* __restrict__ Cf, int ldc,
    ushort* __restrict__ Chi, ushort* __restrict__ Clo, int ldch,
    int colmax)
{
    constexpr int COLS = NT * 16;
    constexpr int HOPU = 8 * COLS;       // 16B-units per operand per 64-k half
    constexpr int ISS  = (2 * HOPU) / 256;
    constexpr int KTOT = NCH * 128;
    constexpr int NK   = NCH * 4;

    __shared__ __align__(16) ushort Bs[2 * HOPU * 8];   // 32 KB @ NT=8

    const int lane = threadIdx.x & 63;
    const int wave = threadIdx.x >> 6;
    const int quad = lane >> 4;
    const int ln15 = lane & 15;
    const int brow = AX ? blockIdx.y : blockIdx.x;
    const int bcol = AX ? blockIdx.x : blockIdx.y;
    const int row0 = (brow * 4 + wave) * 32;
    const int col0 = bcol * COLS;

    int r0 = row0 + ln15;        if (r0 > M - 1) r0 = M - 1;
    int r1 = row0 + 16 + ln15;   if (r1 > M - 1) r1 = M - 1;

    auto stage = [&](int c, int h) {
        #pragma unroll
        for (int i = 0; i < ISS; ++i) {
            int u0 = (wave * ISS + i) * 64;
            int u  = u0 + lane;
            int op = u / HOPU;
            int rem = u - op * HOPU;
            int kq  = rem / COLS;
            int col = rem - kq * COLS;
            int kk  = c * 128 + h * 64 + kq * 8;
            const ushort* spt = op ? Btl : Bth;
            const ushort* gp = spt + (size_t)(col0 + col) * KTOT + kk;
            async_copy16(gp, (char*)Bs + (size_t)u0 * 16);
        }
    };
    auto loadA = [&](int kk, s8v& h0, s8v& l0, s8v& h1, s8v& l1) {
        const ushort* ah; const ushort* al; size_t o0, o1;
        if (kk < K1) { ah = A1h; al = A1l; o0 = (size_t)r0 * K1 + kk; o1 = (size_t)r1 * K1 + kk; }
        else { ah = A2h; al = A2l; int k2 = kk - K1; o0 = (size_t)r0 * K2 + k2; o1 = (size_t)r1 * K2 + k2; }
        int q8 = quad * 8;
        h0 = *(const s8v*)(ah + o0 + q8);
        l0 = *(const s8v*)(al + o0 + q8);
        h1 = *(const s8v*)(ah + o1 + q8);
        l1 = *(const s8v*)(al + o1 + q8);
    };

    f4v acc[2][NT] = {};
    s8v cah0, cal0, cah1, cal1, nah0, nal0, nah1, nal1;

    stage(0, 0);
    loadA(0, cah0, cal0, cah1, cal1);
    __syncthreads();

    #pragma unroll
    for (int c = 0; c < NCH; ++c) {
        #pragma unroll
        for (int h = 0; h < 2; ++h) {
            #pragma unroll
            for (int jj = 0; jj < 2; ++jj) {
                int kj = c * 4 + h * 2 + jj;
                int nk = (kj + 1 < NK) ? (kj + 1) * 32 : 0;   // last: dummy
                loadA(nk, nah0, nal0, nah1, nal1);
                #pragma unroll
                for (int t = 0; t < NT; ++t) {
                    int ub = (jj * 4 + quad) * COLS + t * 16 + ln15;
                    s8v bh = *(const s8v*)(Bs + (size_t)ub * 8);
                    s8v bl = *(const s8v*)(Bs + (size_t)(HOPU + ub) * 8);
                    acc[0][t] = __builtin_amdgcn_mfma_f32_16x16x32_bf16(cah0, bh, acc[0][t], 0, 0, 0);
                    acc[1][t] = __builtin_amdgcn_mfma_f32_16x16x32_bf16(cah1, bh, acc[1][t], 0, 0, 0);
                    acc[0][t] = __builtin_amdgcn_mfma_f32_16x16x32_bf16(cah0, bl, acc[0][t], 0, 0, 0);
                    acc[1][t] = __builtin_amdgcn_mfma_f32_16x16x32_bf16(cah1, bl, acc[1][t], 0, 0, 0);
                    acc[0][t] = __builtin_amdgcn_mfma_f32_16x16x32_bf16(cal0, bh, acc[0][t], 0, 0, 0);
                    acc[1][t] = __builtin_amdgcn_mfma_f32_16x16x32_bf16(cal1, bh, acc[1][t], 0, 0, 0);
                }
                cah0 = nah0; cal0 = nal0; cah1 = nah1; cal1 = nal1;
            }
            if (!(c == NCH - 1 && h == 1)) {
                __syncthreads();
                int nc = c, nh = h + 1;
                if (nh == 2) { nh = 0; ++nc; }
                stage(nc, nh);
                __syncthreads();
            }
        }
    }

    if (NT == 8 && mode == 0) {
        // vectorized LDS-transpose epilogue (COLS==128): pack (hi|lo) uints
        // into per-wave 8KB LDS quarter, read back row-major, 8B stores.
        __syncthreads();                      // Bs done as staging
        uint* Lp = (uint*)Bs + wave * 2048;   // 16 rows x 128 cols
        #pragma unroll
        for (int mt = 0; mt < 2; ++mt) {
            #pragma unroll
            for (int t = 0; t < NT; ++t) {
                int cc = col0 + t * 16 + ln15;
                #pragma unroll
                for (int r = 0; r < 4; ++r) {
                    float v = acc[mt][t][r] + bias[cc];
                    v = v > 0.f ? v : 0.f;
                    ushort h, l; bsplit(v, h, l);
                    Lp[(quad * 4 + r) * 128 + t * 16 + ln15] = (uint)h | ((uint)l << 16);
                }
            }
            // same-wave LDS RAW: DS pipe is in-order per wave
            int cb = (lane & 31) * 4;
            #pragma unroll
            for (int it = 0; it < 8; ++it) {
                int row2 = it * 2 + (lane >> 5);
                int rr = row0 + mt * 16 + row2;
                u4v v = *(u4v*)(Lp + row2 * 128 + cb);
                if (rr < M) {
                    uint2 hw, lw;
                    hw.x = (v[0] & 0xffffu) | (v[1] << 16);
                    hw.y = (v[2] & 0xffffu) | (v[3] << 16);
                    lw.x = (v[0] >> 16) | (v[1] & 0xffff0000u);
                    lw.y = (v[2] >> 16) | (v[3] & 0xffff0000u);
                    *(uint2*)(Chi + (size_t)rr * ldch + col0 + cb) = hw;
                    *(uint2*)(Clo + (size_t)rr * ldch + col0 + cb) = lw;
                }
            }
        }
    } else {
        #pragma unroll
        for (int t = 0; t < NT; ++t) {
            int cc = col0 + t * 16 + ln15;
            #pragma unroll
            for (int mt = 0; mt < 2; ++mt) {
                #pragma unroll
                for (int r = 0; r < 4; ++r) {
                    int rr = row0 + mt * 16 + quad * 4 + r;
                    if (rr < M && cc < colmax)
                        Cf[(size_t)rr * ldc + cc] = acc[mt][t][r] + bias[cc];
                }
            }
        }
    }
}

// ---------- merged producer GEMMs: z=0 GAT, z=1 GCN, z=2 SAGE ----------
__global__ __launch_bounds__(256, 4) void k_gemm_prod(
    const ushort* __restrict__ tgh, const ushort* __restrict__ tgl,
    const ushort* __restrict__ tch, const ushort* __restrict__ tcl,
    const ushort* __restrict__ tsh, const ushort* __restrict__ tsl,
    const ushort* __restrict__ xhi, const ushort* __restrict__ xlo,
    const ushort* __restrict__ btg_h, const ushort* __restrict__ btg_l,
    const ushort* __restrict__ btc_h, const ushort* __restrict__ btc_l,
    const ushort* __restrict__ btsg_h, const ushort* __restrict__ btsg_l,
    const float* __restrict__ bg, const float* __restrict__ bc,
    const float* __restrict__ bsl,
    float* __restrict__ sums, float* __restrict__ sumsq,
    ushort* __restrict__ hch, ushort* __restrict__ hcl)
{
    constexpr int COLS = 128;
    constexpr int HOPU = 8 * COLS;
    constexpr int ISS  = (2 * HOPU) / 256;
    __shared__ __align__(16) ushort Bs[2 * HOPU * 8];   // 32 KB

    const int z = blockIdx.z;
    const ushort* A1h = (z == 0) ? tgh : (z == 1) ? tch : tsh;
    const ushort* A1l = (z == 0) ? tgl : (z == 1) ? tcl : tsl;
    const ushort* Bth = (z == 0) ? btg_h : (z == 1) ? btc_h : btsg_h;
    const ushort* Btl = (z == 0) ? btg_l : (z == 1) ? btc_l : btsg_l;
    const float*  bias = (z == 0) ? bg : (z == 1) ? bc : bsl;
    const int nch = (z == 2) ? 2 : 1;
    const int ktot = nch * 128;
    const int nk = nch * 4;

    const int lane = threadIdx.x & 63;
    const int wave = threadIdx.x >> 6;
    const int quad = lane >> 4;
    const int ln15 = lane & 15;
    const int row0 = (blockIdx.x * 4 + wave) * 32;

    int r0 = row0 + ln15;        if (r0 > NN - 1) r0 = NN - 1;
    int r1 = row0 + 16 + ln15;   if (r1 > NN - 1) r1 = NN - 1;

    auto stage = [&](int c, int h) {
        #pragma unroll
        for (int i = 0; i < ISS; ++i) {
            int u0 = (wave * ISS + i) * 64;
            int u  = u0 + lane;
            int op = u / HOPU;
            int rem = u - op * HOPU;
            int kq  = rem / COLS;
            int col = rem - kq * COLS;
            int kk  = c * 128 + h * 64 + kq * 8;
            const ushort* spt = op ? Btl : Bth;
            const ushort* gp = spt + (size_t)col * ktot + kk;
            async_copy16(gp, (char*)Bs + (size_t)u0 * 16);
        }
    };
    auto loadA = [&](int kk, s8v& h0, s8v& l0, s8v& h1, s8v& l1) {
        const ushort* ah; const ushort* al; size_t o0, o1;
        if (kk < 128) { ah = A1h; al = A1l; o0 = (size_t)r0 * 128 + kk; o1 = (size_t)r1 * 128 + kk; }
        else { ah = xhi; al = xlo; int k2 = kk - 128; o0 = (size_t)r0 * 128 + k2; o1 = (size_t)r1 * 128 + k2; }
        int q8 = quad * 8;
        h0 = *(const s8v*)(ah + o0 + q8);
        l0 = *(const s8v*)(al + o0 + q8);
        h1 = *(const s8v*)(ah + o1 + q8);
        l1 = *(const s8v*)(al + o1 + q8);
    };

    f4v acc[2][8] = {};
    s8v cah0, cal0, cah1, cal1, nah0, nal0, nah1, nal1;

    stage(0, 0);
    loadA(0, cah0, cal0, cah1, cal1);
    __syncthreads();

    for (int c = 0; c < nch; ++c) {
        for (int h = 0; h < 2; ++h) {
            for (int jj = 0; jj < 2; ++jj) {
                int kj = c * 4 + h * 2 + jj;
                int nkk = (kj + 1 < nk) ? (kj + 1) * 32 : 0;
                loadA(nkk, nah0, nal0, nah1, nal1);
                #pragma unroll
                for (int t = 0; t < 8; ++t) {
                    int ub = (jj * 4 + quad) * COLS + t * 16 + ln15;
                    s8v bh = *(const s8v*)(Bs + (size_t)ub * 8);
                    s8v bl = *(const s8v*)(Bs + (size_t)(HOPU + ub) * 8);
                    acc[0][t] = __builtin_amdgcn_mfma_f32_16x16x32_bf16(cah0, bh, acc[0][t], 0, 0, 0);
                    acc[1][t] = __builtin_amdgcn_mfma_f32_16x16x32_bf16(cah1, bh, acc[1][t], 0, 0, 0);
                    acc[0][t] = __builtin_amdgcn_mfma_f32_16x16x32_bf16(cah0, bl, acc[0][t], 0, 0, 0);
                    acc[1][t] = __builtin_amdgcn_mfma_f32_16x16x32_bf16(cah1, bl, acc[1][t], 0, 0, 0);
                    acc[0][t] = __builtin_amdgcn_mfma_f32_16x16x32_bf16(cal0, bh, acc[0][t], 0, 0, 0);
                    acc[1][t] = __builtin_amdgcn_mfma_f32_16x16x32_bf16(cal1, bh, acc[1][t], 0, 0, 0);
                }
                cah0 = nah0; cal0 = nal0; cah1 = nah1; cal1 = nal1;
            }
            if (!(c == nch - 1 && h == 1)) {
                __syncthreads();
                int nc = c, nh = h + 1;
                if (nh == 2) { nh = 0; ++nc; }
                stage(nc, nh);
                __syncthreads();
            }
        }
    }

    // vectorized LDS-transpose epilogue + fused BN stats
    __syncthreads();
    uint* Lp = (uint*)Bs + wave * 2048;
    float sp[8] = {}, qp[8] = {};
    #pragma unroll
    for (int mt = 0; mt < 2; ++mt) {
        #pragma unroll
        for (int t = 0; t < 8; ++t) {
            #pragma unroll
            for (int r = 0; r < 4; ++r) {
                int rr = row0 + mt * 16 + quad * 4 + r;
                float v = acc[mt][t][r] + bias[t * 16 + ln15];
                ushort h, l; bsplit(v, h, l);
                Lp[(quad * 4 + r) * 128 + t * 16 + ln15] = (uint)h | ((uint)l << 16);
                if (rr < NN) { sp[t] += v; qp[t] += v * v; }
            }
        }
        int cb = (lane & 31) * 4;
        #pragma unroll
        for (int it = 0; it < 8; ++it) {
            int row2 = it * 2 + (lane >> 5);
            int rr = row0 + mt * 16 + row2;
            u4v v = *(u4v*)(Lp + row2 * 128 + cb);
            if (rr < NN) {
                uint2 hw, lw;
                hw.x = (v[0] & 0xffffu) | (v[1] << 16);
                hw.y = (v[2] & 0xffffu) | (v[3] << 16);
                lw.x = (v[0] >> 16) | (v[1] & 0xffff0000u);
                lw.y = (v[2] >> 16) | (v[3] & 0xffff0000u);
                *(uint2*)(hch + (size_t)rr * C3 + z * 128 + cb) = hw;
                *(uint2*)(hcl + (size_t)rr * C3 + z * 128 + cb) = lw;
            }
        }
    }
    #pragma unroll
    for (int t = 0; t < 8; ++t) {
        float s = sp[t], q = qp[t];
        s += __shfl_xor(s, 16); s += __shfl_xor(s, 32);
        q += __shfl_xor(q, 16); q += __shfl_xor(q, 32);
        if (quad == 0) {
            int gc = z * 128 + t * 16 + ln15;
            unsafeAtomicAdd(&sums[gc], s);
            unsafeAtomicAdd(&sumsq[gc], q);
        }
    }
}

// ---------- edge pass: dst-degree histogram (real edges only) ----------
__global__ void k_edge1(const int* __restrict__ dst, int* __restrict__ degA)
{
    int gid = blockIdx.x * blockDim.x + threadIdx.x;
    if (gid >= EE) return;
    atomicAdd(&degA[dst[gid]], 1);
}

// ---------- hierarchical exclusive scan over (degA[i]+1) ----------
__global__ __launch_bounds__(256) void k_scan_part(
    const int* __restrict__ degA, int* __restrict__ bsum)
{
    int t = threadIdx.x;
    int b0 = blockIdx.x * SC_ELEMS;
    int i0 = b0 + t * 2;
    int v0 = (i0 < NN)     ? degA[i0] + 1     : 0;
    int v1 = (i0 + 1 < NN) ? degA[i0 + 1] + 1 : 0;
    int s = v0 + v1;
    #pragma unroll
    for (int off = 32; off; off >>= 1) s += __shfl_down(s, off);
    __shared__ int ws[4];
    if ((t & 63) == 0) ws[t >> 6] = s;
    __syncthreads();
    if (t == 0) bsum[blockIdx.x] = ws[0] + ws[1] + ws[2] + ws[3];
}

__global__ __launch_bounds__(128) void k_scan_tops(
    const int* __restrict__ bsum, int* __restrict__ boffs)
{
    __shared__ int sh[128];
    int t = threadIdx.x;
    int v = (t < SC_BLKS) ? bsum[t] : 0;
    sh[t] = v;
    __syncthreads();
    for (int off = 1; off < 128; off <<= 1) {
        int u = (t >= off) ? sh[t - off] : 0;
        __syncthreads();
        sh[t] += u;
        __syncthreads();
    }
    if (t < SC_BLKS) boffs[t] = sh[t] - v;   // exclusive
    if (t == SC_BLKS - 1) boffs[SC_BLKS] = sh[t];
}

// phase 3: OOB elements contribute 0
__global__ __launch_bounds__(256) void k_scan_apply(
    const int* __restrict__ degA, const int* __restrict__ boffs,
    int* __restrict__ offs, int* __restrict__ cursor,
    float* __restrict__ dinv)
{
    __shared__ int sh[256];
    int t = threadIdx.x;
    int b0 = blockIdx.x * SC_ELEMS;
    int i0 = b0 + t * 2;
    int v0 = (i0 < NN)     ? degA[i0] + 1     : 0;
    int v1 = (i0 + 1 < NN) ? degA[i0 + 1] + 1 : 0;
    int pair = v0 + v1;
    sh[t] = pair;
    __syncthreads();
    for (int off = 1; off < 256; off <<= 1) {
        int u = (t >= off) ? sh[t - off] : 0;
        __syncthreads();
        sh[t] += u;
        __syncthreads();
    }
    int excl = sh[t] - pair + boffs[blockIdx.x];
    if (i0 < NN) {
        offs[i0] = excl; cursor[i0] = excl;
        dinv[i0] = rsqrtf((float)v0);
    }
    if (i0 + 1 < NN) {
        offs[i0 + 1] = excl + v0; cursor[i0 + 1] = excl + v0;
        dinv[i0 + 1] = rsqrtf((float)v1);
    }
    if (blockIdx.x == SC_BLKS - 1 && t == 255) offs[NN] = excl + pair;
}

__global__ void k_csr_fill(const int* __restrict__ dst, int* __restrict__ cursor,
                           int* __restrict__ eids)
{
    int gid = blockIdx.x * blockDim.x + threadIdx.x;
    if (gid >= EE + NN) return;
    int d = (gid < EE) ? dst[gid] : (gid - EE);
    int slot = atomicAdd(&cursor[d], 1);
    eids[slot] = gid;
}

// ---------- CSR gather with in-wave softmax (max + denom) ----------
__global__ __launch_bounds__(256) void k_gather(
    const int* __restrict__ src,
    const int* __restrict__ eids, const int* __restrict__ offs,
    const float* __restrict__ a_s, const float* __restrict__ a_d,
    const float* __restrict__ dinv,
    const float* __restrict__ x,
    ushort* __restrict__ tgh, ushort* __restrict__ tgl,
    ushort* __restrict__ tch, ushort* __restrict__ tcl,
    ushort* __restrict__ tsh, ushort* __restrict__ tsl)
{
    int d = blockIdx.x * 4 + (threadIdx.x >> 6);
    if (d >= NN) return;
    int lane = threadIdx.x & 63;
    int beg = offs[d], end = offs[d + 1];
    float ad = a_d[d], dd = dinv[d];

    int idx0 = beg + lane;
    bool v0 = idx0 < end;
    int s0 = d; float e0 = 0.f;
    if (v0) {
        int eid = eids[idx0];
        s0 = (eid < EE) ? src[eid] : d;
        float e = a_s[s0] + ad;
        e0 = (e > 0.f) ? e : 0.2f * e;
    }
    float m = v0 ? e0 : -3.0e38f;
    for (int base = beg + 64; base < end; base += 64) {
        int idx = base + lane;
        if (idx < end) {
            int eid = eids[idx];
            int s = (eid < EE) ? src[eid] : d;
            float e = a_s[s] + ad;
            e = (e > 0.f) ? e : 0.2f * e;
            m = fmaxf(m, e);
        }
    }
    #pragma unroll
    for (int off = 1; off < 64; off <<= 1) m = fmaxf(m, __shfl_xor(m, off));
    float den = v0 ? expf(e0 - m) : 0.f;
    for (int base = beg + 64; base < end; base += 64) {
        int idx = base + lane;
        if (idx < end) {
            int eid = eids[idx];
            int s = (eid < EE) ? src[eid] : d;
            float e = a_s[s] + ad;
            e = (e > 0.f) ? e : 0.2f * e;
            den += expf(e - m);
        }
    }
    #pragma unroll
    for (int off = 1; off < 64; off <<= 1) den += __shfl_xor(den, off);
    float rden = 1.f / den;

    float2 tg = {0.f, 0.f}, tc = {0.f, 0.f}, ts = {0.f, 0.f};
    int c = lane * 2;
    {
        float wg = v0 ? expf(e0 - m) * rden : 0.f;
        float wc = v0 ? dinv[s0] * dd : 0.f;
        int cnt = end - beg; if (cnt > 64) cnt = 64;
        for (int j = 0; j < cnt; ++j) {
            int   sj  = __shfl(s0, j);
            float wgj = __shfl(wg, j);
            float wcj = __shfl(wc, j);
            const float2 xv = *(const float2*)(x + (size_t)sj * 128 + c);
            tg.x += wgj * xv.x; tg.y += wgj * xv.y;
            tc.x += wcj * xv.x; tc.y += wcj * xv.y;
            ts.x += xv.x;       ts.y += xv.y;
        }
    }
    for (int base = beg + 64; base < end; base += 64) {
        int idx = base + lane;
        int s = d; float wg = 0.f, wc = 0.f;
        if (idx < end) {
            int eid = eids[idx];
            s = (eid < EE) ? src[eid] : d;
            float e = a_s[s] + ad;
            e = (e > 0.f) ? e : 0.2f * e;
            wg = expf(e - m) * rden;
            wc = dinv[s] * dd;
        }
        int cnt = end - base; if (cnt > 64) cnt = 64;
        for (int j = 0; j < cnt; ++j) {
            int   sj  = __shfl(s, j);
            float wgj = __shfl(wg, j);
            float wcj = __shfl(wc, j);
            const float2 xv = *(const float2*)(x + (size_t)sj * 128 + c);
            tg.x += wgj * xv.x; tg.y += wgj * xv.y;
            tc.x += wcj * xv.x; tc.y += wcj * xv.y;
            ts.x += xv.x;       ts.y += xv.y;
        }
    }
    const float2 xd = *(const float2*)(x + (size_t)d * 128 + c);
    ts.x -= xd.x; ts.y -= xd.y;
    int cs = (end - beg) - 1;
    float rc = 1.f / (float)(cs > 1 ? cs : 1);
    ts.x *= rc; ts.y *= rc;

    size_t row = (size_t)d * 128 + c;
    ushort h0, l0, h1, l1;
    bsplit(tg.x, h0, l0); bsplit(tg.y, h1, l1);
    { ushort2 u; u.x = h0; u.y = h1; *(ushort2*)(tgh + row) = u; }
    { ushort2 u; u.x = l0; u.y = l1; *(ushort2*)(tgl + row) = u; }
    bsplit(tc.x, h0, l0); bsplit(tc.y, h1, l1);
    { ushort2 u; u.x = h0; u.y = h1; *(ushort2*)(tch + row) = u; }
    { ushort2 u; u.x = l0; u.y = l1; *(ushort2*)(tcl + row) = u; }
    bsplit(ts.x, h0, l0); bsplit(ts.y, h1, l1);
    { ushort2 u; u.x = h0; u.y = h1; *(ushort2*)(tsh + row) = u; }
    { ushort2 u; u.x = l0; u.y = l1; *(ushort2*)(tsl + row) = u; }
}

__global__ void k_bn_final(const float* __restrict__ sums, const float* __restrict__ sumsq,
                           const float* __restrict__ gamma, const float* __restrict__ beta,
                           float* __restrict__ scale, float* __restrict__ shift)
{
    int j = threadIdx.x;
    if (j >= C3) return;
    const float rn = 1.f / (float)NN;
    float mu  = sums[j] * rn;
    float var = sumsq[j] * rn - mu * mu;
    float sc  = gamma[j] * rsqrtf(var + 1e-5f);
    scale[j] = sc;
    shift[j] = beta[j] - mu * sc;
}

// ---------- in-place BN+relu of split hcat (flat over NN*192 pairs) ----------
__global__ __launch_bounds__(256) void k_bnrelu(
    ushort* __restrict__ hch, ushort* __restrict__ hcl,
    const float* __restrict__ scale, const float* __restrict__ shift)
{
    int p = blockIdx.x * blockDim.x + threadIdx.x;
    if (p >= NN * 192) return;
    int cpair = p % 192;
    int cidx = cpair * 2;
    size_t o = (size_t)p * 2;
    ushort2 h = *(ushort2*)(hch + o);
    ushort2 l = *(ushort2*)(hcl + o);
    float v0 = b2f(h.x) + b2f(l.x);
    float v1 = b2f(h.y) + b2f(l.y);
    v0 = v0 * scale[cidx] + shift[cidx];         v0 = v0 > 0.f ? v0 : 0.f;
    v1 = v1 * scale[cidx + 1] + shift[cidx + 1]; v1 = v1 > 0.f ? v1 : 0.f;
    ushort h0, l0, h1, l1;
    bsplit(v0, h0, l0); bsplit(v1, h1, l1);
    { ushort2 u; u.x = h0; u.y = h1; *(ushort2*)(hch + o) = u; }
    { ushort2 u; u.x = l0; u.y = l1; *(ushort2*)(hcl + o) = u; }
}

extern "C" void kernel_launch(void* const* d_in, const int* in_sizes, int n_in,
                              void* d_out, int out_size, void* d_ws, size_t ws_size,
                              hipStream_t stream) {
    const float* x        = (const float*)d_in[0];
    const int*   ei       = (const int*)d_in[1];
    const float* W_gat    = (const float*)d_in[2];
    const float* att_src  = (const float*)d_in[3];
    const float* att_dst  = (const float*)d_in[4];
    const float* b_gat    = (const float*)d_in[5];
    const float* W_gcn    = (const float*)d_in[6];
    const float* b_gcn    = (const float*)d_in[7];
    const float* W_sage_l = (const float*)d_in[8];
    const float* b_sage_l = (const float*)d_in[9];
    const float* W_sage_r = (const float*)d_in[10];
    const float* W1       = (const float*)d_in[11];
    const float* b1       = (const float*)d_in[12];
    const float* W2       = (const float*)d_in[13];
    const float* b2       = (const float*)d_in[14];
    const float* W3       = (const float*)d_in[15];
    const float* b3       = (const float*)d_in[16];
    const float* gamma    = (const float*)d_in[17];
    const float* beta     = (const float*)d_in[18];

    const int* e_src = ei;
    const int* e_dst = ei + EE;

    // ---- workspace layout (all offsets 16B-aligned) ----
    char* base = (char*)d_ws;
    size_t o = 0;
    ushort* hch  = (ushort*)(base + o); o += (size_t)NN * C3 * 2;
    ushort* hcl  = (ushort*)(base + o); o += (size_t)NN * C3 * 2;
    ushort* tgh  = (ushort*)(base + o); o += (size_t)NN * 128 * 2;   // a1h overlay
    ushort* tgl  = (ushort*)(base + o); o += (size_t)NN * 128 * 2;
    ushort* tch  = (ushort*)(base + o); o += (size_t)NN * 128 * 2;   // a1l overlay
    ushort* tcl  = (ushort*)(base + o); o += (size_t)NN * 128 * 2;
    ushort* tsh  = (ushort*)(base + o); o += (size_t)NN * 128 * 2;   // a2h overlay
    ushort* tsl  = (ushort*)(base + o); o += (size_t)NN * 128 * 2;   // a2l overlay
    ushort* xhi  = (ushort*)(base + o); o += (size_t)NN * 128 * 2;
    ushort* xlo  = (ushort*)(base + o); o += (size_t)NN * 128 * 2;
    int*    eids = (int*)(base + o);    o += (size_t)(EE + NN) * 4;
    int*    offs = (int*)(base + o);    o += (size_t)(NN + 16) * 4;
    int*    cursor=(int*)(base + o);    o += (size_t)NN * 4;
    float*  as_  = (float*)(base + o);  o += (size_t)NN * 4;
    float*  ad_  = (float*)(base + o);  o += (size_t)NN * 4;
    float*  dinv = (float*)(base + o);  o += (size_t)NN * 4;
    int*    bsum = (int*)(base + o);    o += 256 * 4;
    int*    boffs= (int*)(base + o);    o += 256 * 4;
    // --- zero-init region: degA, sums, sumsq (contiguous) ---
    int*    degA = (int*)(base + o);    o += (size_t)NN * 4;
    float*  sums = (float*)(base + o);  o += C3 * 4;
    float*  sumsq= (float*)(base + o);  o += C3 * 4;
    // --- end zero region ---
    float*  scale= (float*)(base + o);  o += C3 * 4;
    float*  shift= (float*)(base + o);  o += C3 * 4;
    float*  w_as = (float*)(base + o);  o += 128 * 4;
    float*  w_ad = (float*)(base + o);  o += 128 * 4;
    ushort* btg_h = (ushort*)(base + o); o += 128 * 128 * 2;
    ushort* btg_l = (ushort*)(base + o); o += 128 * 128 * 2;
    ushort* btc_h = (ushort*)(base + o); o += 128 * 128 * 2;
    ushort* btc_l = (ushort*)(base + o); o += 128 * 128 * 2;
    ushort* btsg_h= (ushort*)(base + o); o += 128 * 256 * 2;
    ushort* btsg_l= (ushort*)(base + o); o += 128 * 256 * 2;
    ushort* bt1_h = (ushort*)(base + o); o += 256 * 384 * 2;
    ushort* bt1_l = (ushort*)(base + o); o += 256 * 384 * 2;
    ushort* bt2_h = (ushort*)(base + o); o += 128 * 256 * 2;
    ushort* bt2_l = (ushort*)(base + o); o += 128 * 256 * 2;
    ushort* bt3_h = (ushort*)(base + o); o += 48 * 128 * 2;
    ushort* bt3_l = (ushort*)(base + o); o += 48 * 128 * 2;
    // overlays (temporally disjoint with t*/x buffers)
    ushort* a1h = tgh;                       // NN*256 ushorts
    ushort* a1l = tch;                       // NN*256 ushorts
    ushort* a2h = tsh;                       // NN*128
    ushort* a2l = tsl;                       // NN*128

    hipMemsetAsync(degA, 0, (size_t)NN * 4 + 2 * C3 * 4, stream);

    // ---- weight prep (att fold fused as block 816) ----
    k_splitw_all<<<817, 256, 0, stream>>>(W_gat, W_gcn, W_sage_l, W_sage_r, W1, W2, W3,
        att_src, att_dst, w_as, w_ad,
        btg_h, btg_l, btc_h, btc_l, btsg_h, btsg_l, bt1_h, bt1_l, bt2_h, bt2_l, bt3_h, bt3_l);
    k_split_x_att<<<(NN + 3) / 4, 256, 0, stream>>>(x, w_as, w_ad, xhi, xlo, as_, ad_);

    // ---- CSR build (hierarchical scan) ----
    k_edge1<<<(EE + 255) / 256, 256, 0, stream>>>(e_dst, degA);
    k_scan_part<<<SC_BLKS, 256, 0, stream>>>(degA, bsum);
    k_scan_tops<<<1, 128, 0, stream>>>(bsum, boffs);
    k_scan_apply<<<SC_BLKS, 256, 0, stream>>>(degA, boffs, offs, cursor, dinv);
    k_csr_fill<<<(EE + NN + 255) / 256, 256, 0, stream>>>(e_dst, cursor, eids);

    // ---- gather: softmax in-wave + weighted x sums ----
    k_gather<<<(NN + 3) / 4, 256, 0, stream>>>(
        e_src, eids, offs, as_, ad_, dinv, x, tgh, tgl, tch, tcl, tsh, tsl);

    // ---- producers: ONE launch, z in {GAT, GCN, SAGE}, fused BN stats ----
    k_gemm_prod<<<dim3((NN + 127) / 128, 1, 3), 256, 0, stream>>>(
        tgh, tgl, tch, tcl, tsh, tsl, xhi, xlo,
        btg_h, btg_l, btc_h, btc_l, btsg_h, btsg_l,
        b_gat, b_gcn, b_sage_l, sums, sumsq, hch, hcl);

    // ---- BN fold + in-place transform ----
    k_bn_final<<<1, C3, 0, stream>>>(sums, sumsq, gamma, beta, scale, shift);
    k_bnrelu<<<(NN * 192 + 255) / 256, 256, 0, stream>>>(hch, hcl, scale, shift);

    // ---- MLP ----
    k_gemm2<8, 3, 1><<<dim3(2, (NN + 127) / 128), 256, 0, stream>>>(
        hch, hcl, 384, hch, hcl, 384, bt1_h, bt1_l, NN, 0, b1,
        nullptr, 0, a1h, a1l, 256, 256);
    k_gemm2<8, 2, 0><<<dim3((NN + 127) / 128, 1), 256, 0, stream>>>(
        a1h, a1l, 256, a1h, a1l, 256, bt2_h, bt2_l, NN, 0, b2,
        nullptr, 0, a2h, a2l, 128, 128);
    k_gemm2<3, 1, 0><<<dim3((NN + 127) / 128, 1), 256, 0, stream>>>(
        a2h, a2l, 128, a2h, a2l, 128, bt3_h, bt3_l, NN, 2, b3,
        (float*)d_out, NOUT, nullptr, nullptr, 0, NOUT);
}